// Round 7
// baseline (283.804 us; speedup 1.0000x reference)
//
#include <hip/hip_runtime.h>
#include <hip/hip_bf16.h>

typedef __hip_bfloat16 bf16;
typedef unsigned short ushort8_v __attribute__((ext_vector_type(8)));

#define N_B     64
#define C_IN    9
#define T0      4096
#define C1      16
#define T1      2048
#define C2      32
#define T2      1024
#define N_NODES 65536
#define N_EDGES 524288
#define HID     128
#define OUT_C   10

__device__ __forceinline__ float us2f(unsigned short u) {
  union { unsigned int i; float f; } c; c.i = ((unsigned int)u) << 16; return c.f;
}
__device__ __forceinline__ unsigned short f2us(float f) {
  bf16 h = __float2bfloat16(f);
  unsigned short u;
  __builtin_memcpy(&u, &h, 2);
  return u;
}

// ---------------- CSR build ----------------

__global__ __launch_bounds__(256) void init_kernel(int* __restrict__ deg, float* __restrict__ pooled)
{
  int i = blockIdx.x * 256 + threadIdx.x;
  if (i < N_NODES) deg[i] = 0;
  if (i < N_B * HID) pooled[i] = 0.f;
}

__global__ __launch_bounds__(256) void count_kernel(const int* __restrict__ ei, int* __restrict__ deg)
{
  int e = blockIdx.x * 256 + threadIdx.x;
  if (e < N_EDGES) atomicAdd(&deg[ei[N_EDGES + e]], 1);
}

__global__ __launch_bounds__(256) void dinv_kernel(const int* __restrict__ deg, float* __restrict__ dinv)
{
  int i = blockIdx.x * 256 + threadIdx.x;
  if (i < N_NODES) dinv[i] = rsqrtf((float)deg[i] + 1.0f);  // +1 self loop
}

__global__ __launch_bounds__(256) void scanA_kernel(const int* __restrict__ deg, int* __restrict__ bsum)
{
  __shared__ int sd[256];
  int i = blockIdx.x * 256 + threadIdx.x;
  sd[threadIdx.x] = deg[i];
  __syncthreads();
  for (int d = 128; d > 0; d >>= 1) {
    if (threadIdx.x < d) sd[threadIdx.x] += sd[threadIdx.x + d];
    __syncthreads();
  }
  if (threadIdx.x == 0) bsum[blockIdx.x] = sd[0];
}

__global__ __launch_bounds__(256) void scanB_kernel(int* __restrict__ bsum)
{
  __shared__ int s[256];
  int tid = threadIdx.x;
  int v = bsum[tid];
  s[tid] = v;
  __syncthreads();
  for (int d = 1; d < 256; d <<= 1) {
    int add = (tid >= d) ? s[tid - d] : 0;
    __syncthreads();
    s[tid] += add;
    __syncthreads();
  }
  bsum[tid] = s[tid] - v;  // exclusive
}

__global__ __launch_bounds__(256) void scanC_kernel(const int* __restrict__ deg, const int* __restrict__ bsum,
                                                    int* __restrict__ off, int* __restrict__ cursor)
{
  __shared__ int s[256];
  int tid = threadIdx.x;
  int i = blockIdx.x * 256 + tid;
  int v = deg[i];
  s[tid] = v;
  __syncthreads();
  for (int d = 1; d < 256; d <<= 1) {
    int add = (tid >= d) ? s[tid - d] : 0;
    __syncthreads();
    s[tid] += add;
    __syncthreads();
  }
  int excl = s[tid] - v + bsum[blockIdx.x];
  off[i] = excl;
  cursor[i] = excl;
  if (i == N_NODES - 1) off[N_NODES] = excl + v;
}

// store src index AND precomputed coef = dinv[src]*dinv[dst] (linear reads in agg)
__global__ __launch_bounds__(256) void scatter_kernel(const int* __restrict__ ei, int* __restrict__ cursor,
                                                      const float* __restrict__ dinv,
                                                      int* __restrict__ csr, float* __restrict__ coef)
{
  int e = blockIdx.x * 256 + threadIdx.x;
  if (e < N_EDGES) {
    int d = ei[N_EDGES + e];
    int s = ei[e];
    int p = atomicAdd(&cursor[d], 1);
    csr[p] = s;
    coef[p] = dinv[s] * dinv[d];
  }
}

// ---------------- conv1 + relu + pool: no LDS, direct global reads ----------------
// grid 2048 = 64 b * 32 tiles(64 pooled pos); block 256 = 16 o * 16 pg (4 pos each).
__global__ __launch_bounds__(256) void conv1_kernel(const float* __restrict__ x, const float* __restrict__ w1,
                                                    const float* __restrict__ b1, float* __restrict__ y1)
{
  int tid = threadIdx.x;
  int o = tid >> 4, pg = tid & 15;
  int b = blockIdx.x >> 5;
  int P0 = ((blockIdx.x & 31) << 6) + (pg << 2);   // 4 pooled positions P0..P0+3
  int base = 2 * P0 - 4;                            // 16-value aligned x window
  float bias = b1[o];
  float a[8];
  #pragma unroll
  for (int i = 0; i < 8; ++i) a[i] = bias;
  const float* xb = x + (size_t)(b * C_IN) * T0;
  bool fast = (base >= 0) && (base + 16 <= T0);
  #pragma unroll
  for (int c = 0; c < C_IN; ++c) {
    float wc[5];
    #pragma unroll
    for (int k = 0; k < 5; ++k) wc[k] = w1[o * 45 + c * 5 + k];
    float xv[16];
    if (fast) {
      #pragma unroll
      for (int q = 0; q < 4; ++q)
        *(float4*)&xv[4 * q] = *(const float4*)&xb[(size_t)c * T0 + base + 4 * q];
    } else {
      #pragma unroll
      for (int q = 0; q < 16; ++q) {
        int t = base + q;
        xv[q] = (t >= 0 && t < T0) ? xb[(size_t)c * T0 + t] : 0.f;
      }
    }
    // conv output t = 2*P0+i needs x[t-2+k] -> xv[i+2+k]
    #pragma unroll
    for (int i = 0; i < 8; ++i)
      a[i] += xv[i+2]*wc[0] + xv[i+3]*wc[1] + xv[i+4]*wc[2] + xv[i+5]*wc[3] + xv[i+6]*wc[4];
  }
  float4 r;
  r.x = fmaxf(fmaxf(a[0], a[1]), 0.f);
  r.y = fmaxf(fmaxf(a[2], a[3]), 0.f);
  r.z = fmaxf(fmaxf(a[4], a[5]), 0.f);
  r.w = fmaxf(fmaxf(a[6], a[7]), 0.f);
  *(float4*)&y1[(size_t)(b * C1 + o) * T1 + P0] = r;
}

// ---------------- conv2 + relu + pool -> bf16 feats [node][32] ----------------
// grid 2048 = 64 b * 32 tiles(32 final pos); block 256 = 32 o * 8 qg (4 pos each).
__global__ __launch_bounds__(256) void conv2_kernel(const float* __restrict__ y1, const float* __restrict__ w2,
                                                    const float* __restrict__ b2, unsigned short* __restrict__ feats)
{
  int tid = threadIdx.x;
  int o = tid >> 3, qg = tid & 7;
  int b = blockIdx.x >> 5;
  int Q0 = ((blockIdx.x & 31) << 5) + (qg << 2);   // 4 final positions
  int base = 2 * Q0 - 4;
  float bias = b2[o];
  float a[8];
  #pragma unroll
  for (int i = 0; i < 8; ++i) a[i] = bias;
  const float* yb = y1 + (size_t)(b * C1) * T1;
  bool fast = (base >= 0) && (base + 16 <= T1);
  #pragma unroll
  for (int c = 0; c < C1; ++c) {
    float wc[5];
    #pragma unroll
    for (int k = 0; k < 5; ++k) wc[k] = w2[o * 80 + c * 5 + k];
    float xv[16];
    if (fast) {
      #pragma unroll
      for (int q = 0; q < 4; ++q)
        *(float4*)&xv[4 * q] = *(const float4*)&yb[(size_t)c * T1 + base + 4 * q];
    } else {
      #pragma unroll
      for (int q = 0; q < 16; ++q) {
        int t = base + q;
        xv[q] = (t >= 0 && t < T1) ? yb[(size_t)c * T1 + t] : 0.f;
      }
    }
    #pragma unroll
    for (int i = 0; i < 8; ++i)
      a[i] += xv[i+2]*wc[0] + xv[i+3]*wc[1] + xv[i+4]*wc[2] + xv[i+5]*wc[3] + xv[i+6]*wc[4];
  }
  #pragma unroll
  for (int j = 0; j < 4; ++j) {
    int node = (b << 10) + Q0 + j;
    feats[(size_t)node * C2 + o] = f2us(fmaxf(fmaxf(a[2*j], a[2*j+1]), 0.f));
  }
}

// ---------------- aggX: aggregate 32-dim bf16 feats -> fp32 [N,32] ----------------
// block 256 = 64 nodes x 4 lanes (8 bf16 each); grid 1024
__global__ __launch_bounds__(256) void aggX_kernel(const unsigned short* __restrict__ F, const int* __restrict__ off,
                                                   const int* __restrict__ csr, const float* __restrict__ coef,
                                                   const float* __restrict__ dinv, float* __restrict__ aggX)
{
  int tid = threadIdx.x;
  int node = (blockIdx.x << 6) + (tid >> 2);
  int jq = (tid & 3) << 3;                  // bf16 element offset
  float dn = dinv[node];
  float acc[8];
  {
    ushort8_v r = *(const ushort8_v*)(F + (size_t)node * C2 + jq);
    float c = dn * dn;
    #pragma unroll
    for (int k = 0; k < 8; ++k) acc[k] = us2f(r[k]) * c;
  }
  int e0 = off[node], e1 = off[node + 1];
  int e = e0;
  for (; e + 2 <= e1; e += 2) {
    int s0 = csr[e], s1 = csr[e + 1];
    float c0 = coef[e], c1 = coef[e + 1];
    ushort8_v r0 = *(const ushort8_v*)(F + (size_t)s0 * C2 + jq);
    ushort8_v r1 = *(const ushort8_v*)(F + (size_t)s1 * C2 + jq);
    #pragma unroll
    for (int k = 0; k < 8; ++k) acc[k] += us2f(r0[k]) * c0 + us2f(r1[k]) * c1;
  }
  if (e < e1) {
    int s0 = csr[e];
    float c0 = coef[e];
    ushort8_v r0 = *(const ushort8_v*)(F + (size_t)s0 * C2 + jq);
    #pragma unroll
    for (int k = 0; k < 8; ++k) acc[k] += us2f(r0[k]) * c0;
  }
  float* dst = aggX + (size_t)node * C2 + jq;
  *(float4*)(dst)     = make_float4(acc[0], acc[1], acc[2], acc[3]);
  *(float4*)(dst + 4) = make_float4(acc[4], acc[5], acc[6], acc[7]);
}

// ---------------- GEMM: [nodes,K] @ [K,128] -> [nodes,128] ----------------
// MODE 0: out fp32 with bias+relu.  MODE 1: out bf16 raw.
template<int K, int MODE>
__global__ __launch_bounds__(256) void gemm_kernel(const float* __restrict__ A, const float* __restrict__ W,
                                                   const float* __restrict__ bias,
                                                   float* __restrict__ Cf, unsigned short* __restrict__ Cb)
{
  __shared__ float sA[32 * K];
  int tid = threadIdx.x;
  int n0 = blockIdx.x << 5;
  for (int i = tid; i < 32 * K / 4; i += 256)
    ((float4*)sA)[i] = ((const float4*)(A + (size_t)n0 * K))[i];
  __syncthreads();
  int nq = (tid >> 5) << 2;
  int jq = (tid & 31) << 2;
  float acc[4][4] = {};
  #pragma unroll 4
  for (int i4 = 0; i4 < K / 4; ++i4) {
    float wv[4][4];
    #pragma unroll
    for (int ii = 0; ii < 4; ++ii) {
      float4 u = *(const float4*)(&W[(size_t)(i4 * 4 + ii) * HID + jq]);
      wv[ii][0] = u.x; wv[ii][1] = u.y; wv[ii][2] = u.z; wv[ii][3] = u.w;
    }
    #pragma unroll
    for (int nn = 0; nn < 4; ++nn) {
      float4 g = *(const float4*)&sA[(nq + nn) * K + (i4 << 2)];
      #pragma unroll
      for (int jj = 0; jj < 4; ++jj)
        acc[nn][jj] += g.x * wv[0][jj] + g.y * wv[1][jj] + g.z * wv[2][jj] + g.w * wv[3][jj];
    }
  }
  if (MODE == 0) {
    float b0 = bias[jq], b1 = bias[jq + 1], b2 = bias[jq + 2], b3 = bias[jq + 3];
    #pragma unroll
    for (int nn = 0; nn < 4; ++nn) {
      float4 o4 = make_float4(fmaxf(acc[nn][0] + b0, 0.f), fmaxf(acc[nn][1] + b1, 0.f),
                              fmaxf(acc[nn][2] + b2, 0.f), fmaxf(acc[nn][3] + b3, 0.f));
      *(float4*)&Cf[((size_t)(n0 + nq + nn)) * HID + jq] = o4;
    }
  } else {
    #pragma unroll
    for (int nn = 0; nn < 4; ++nn) {
      ushort4 u;
      u.x = f2us(acc[nn][0]);
      u.y = f2us(acc[nn][1]);
      u.z = f2us(acc[nn][2]);
      u.w = f2us(acc[nn][3]);
      *(ushort4*)(Cb + ((size_t)(n0 + nq + nn)) * HID + jq) = u;
    }
  }
}

// ---------------- agg2 + bias + relu + mean-pool (fused) ----------------
// block 256 = 16 nodes x 16 lanes (8 bf16 each); grid 4096; never materializes G2
__global__ __launch_bounds__(256) void agg2_pool_kernel(const unsigned short* __restrict__ Hb, const int* __restrict__ off,
                                                        const int* __restrict__ csr, const float* __restrict__ coef,
                                                        const float* __restrict__ dinv, const float* __restrict__ bias,
                                                        float* __restrict__ pooled)
{
  __shared__ float red[16][HID];           // 8 KB
  int tid = threadIdx.x;
  int g = tid >> 4;                        // local node 0..15
  int jq = (tid & 15) << 3;                // bf16 element offset 0..120
  int node = (blockIdx.x << 4) + g;
  float dn = dinv[node];
  float acc[8];
  {
    ushort8_v r = *(const ushort8_v*)(Hb + (size_t)node * HID + jq);
    float c = dn * dn;
    #pragma unroll
    for (int k = 0; k < 8; ++k) acc[k] = us2f(r[k]) * c;
  }
  int e0 = off[node], e1 = off[node + 1];
  int e = e0;
  for (; e + 2 <= e1; e += 2) {
    int s0 = csr[e], s1 = csr[e + 1];
    float c0 = coef[e], c1 = coef[e + 1];
    ushort8_v r0 = *(const ushort8_v*)(Hb + (size_t)s0 * HID + jq);
    ushort8_v r1 = *(const ushort8_v*)(Hb + (size_t)s1 * HID + jq);
    #pragma unroll
    for (int k = 0; k < 8; ++k) acc[k] += us2f(r0[k]) * c0 + us2f(r1[k]) * c1;
  }
  if (e < e1) {
    int s0 = csr[e];
    float c0 = coef[e];
    ushort8_v r0 = *(const ushort8_v*)(Hb + (size_t)s0 * HID + jq);
    #pragma unroll
    for (int k = 0; k < 8; ++k) acc[k] += us2f(r0[k]) * c0;
  }
  #pragma unroll
  for (int k = 0; k < 8; ++k)
    red[g][jq + k] = fmaxf(acc[k] + bias[jq + k], 0.f);
  __syncthreads();
  if (tid < HID) {
    float s = 0.f;
    #pragma unroll
    for (int g2 = 0; g2 < 16; ++g2) s += red[g2][tid];
    int b = blockIdx.x >> 6;               // 64 blocks per graph
    atomicAdd(&pooled[b * HID + tid], s * (1.0f / 1024.0f));
  }
}

// ---------------- classifier ----------------

__global__ __launch_bounds__(64) void cls_kernel(const float* __restrict__ pooled, const float* __restrict__ w,
                                                 const float* __restrict__ cb, float* __restrict__ out)
{
  int b = blockIdx.x, o = threadIdx.x;
  if (o < OUT_C) {
    float acc = cb[o];
    for (int i = 0; i < HID; ++i)
      acc += pooled[b * HID + i] * w[i * OUT_C + o];
    out[b * OUT_C + o] = acc;
  }
}

// ---------------- launcher ----------------

extern "C" void kernel_launch(void* const* d_in, const int* in_sizes, int n_in,
                              void* d_out, int out_size, void* d_ws, size_t ws_size,
                              hipStream_t stream)
{
  const float* x    = (const float*)d_in[0];
  const int*   ei   = (const int*)d_in[1];
  const float* c1w  = (const float*)d_in[2];
  const float* c1b  = (const float*)d_in[3];
  const float* c2w  = (const float*)d_in[4];
  const float* c2b  = (const float*)d_in[5];
  const float* g1w  = (const float*)d_in[6];
  const float* g1b  = (const float*)d_in[7];
  const float* g2w  = (const float*)d_in[8];
  const float* g2b  = (const float*)d_in[9];
  const float* clsw = (const float*)d_in[10];
  const float* clsb = (const float*)d_in[11];
  float* outp = (float*)d_out;

  char* ws = (char*)d_ws;
  size_t off_b = 0;
  auto alloc = [&](size_t bytes) { void* p = ws + off_b; off_b = (off_b + bytes + 255) & ~(size_t)255; return p; };
  int*   deg    = (int*)  alloc((size_t)N_NODES * 4);
  float* dinvv  = (float*)alloc((size_t)N_NODES * 4);
  int*   offp   = (int*)  alloc((size_t)(N_NODES + 1) * 4);
  int*   cursor = (int*)  alloc((size_t)N_NODES * 4);
  int*   bsum   = (int*)  alloc(256 * 4);
  int*   csr    = (int*)  alloc((size_t)N_EDGES * 4);
  float* coefp  = (float*)alloc((size_t)N_EDGES * 4);
  float* y1     = (float*)alloc((size_t)N_B * C1 * T1 * 4);
  unsigned short* feats = (unsigned short*)alloc((size_t)N_NODES * C2 * 2);
  float* aggX   = (float*)alloc((size_t)N_NODES * C2 * 4);
  float* G      = (float*)alloc((size_t)N_NODES * HID * 4);
  unsigned short* H = (unsigned short*)alloc((size_t)N_NODES * HID * 2);
  float* pooled = (float*)alloc((size_t)N_B * HID * 4);
  (void)ws_size; (void)in_sizes; (void)n_in; (void)out_size;

  // CSR build
  init_kernel   <<<256, 256, 0, stream>>>(deg, pooled);
  count_kernel  <<<N_EDGES / 256, 256, 0, stream>>>(ei, deg);
  dinv_kernel   <<<N_NODES / 256, 256, 0, stream>>>(deg, dinvv);
  scanA_kernel  <<<256, 256, 0, stream>>>(deg, bsum);
  scanB_kernel  <<<1, 256, 0, stream>>>(bsum);
  scanC_kernel  <<<256, 256, 0, stream>>>(deg, bsum, offp, cursor);
  scatter_kernel<<<N_EDGES / 256, 256, 0, stream>>>(ei, cursor, dinvv, csr, coefp);

  // CNN feature extractor
  conv1_kernel<<<2048, 256, 0, stream>>>(x, c1w, c1b, y1);
  conv2_kernel<<<2048, 256, 0, stream>>>(y1, c2w, c2b, feats);

  // GCN layer 1: (A X) W1 + b1, relu
  aggX_kernel<<<N_NODES / 64, 256, 0, stream>>>(feats, offp, csr, coefp, dinvv, aggX);
  gemm_kernel<32, 0><<<N_NODES / 32, 256, 0, stream>>>(aggX, g1w, g1b, G, nullptr);

  // GCN layer 2: A (G W2) + b2, relu, fused mean-pool
  gemm_kernel<128, 1><<<N_NODES / 32, 256, 0, stream>>>(G, g2w, nullptr, nullptr, H);
  agg2_pool_kernel<<<N_NODES / 16, 256, 0, stream>>>(H, offp, csr, coefp, dinvv, g2b, pooled);

  // classifier
  cls_kernel<<<N_B, 64, 0, stream>>>(pooled, clsw, clsb, outp);
}

// Round 8
// 188.758 us; speedup vs baseline: 1.5035x; 1.5035x over previous
//
#include <hip/hip_runtime.h>
#include <hip/hip_bf16.h>

typedef __hip_bfloat16 bf16;
typedef unsigned short ushort8_v __attribute__((ext_vector_type(8)));

#define N_B     64
#define C_IN    9
#define T0      4096
#define C1      16
#define T1      2048
#define C2      32
#define T2      1024
#define N_NODES 65536
#define N_EDGES 524288
#define HID     128
#define OUT_C   10

__device__ __forceinline__ float us2f(unsigned short u) {
  union { unsigned int i; float f; } c; c.i = ((unsigned int)u) << 16; return c.f;
}
__device__ __forceinline__ unsigned short f2us(float f) {
  bf16 h = __float2bfloat16(f);
  unsigned short u;
  __builtin_memcpy(&u, &h, 2);
  return u;
}

// ---------------- CSR build ----------------

__global__ __launch_bounds__(256) void init_kernel(int* __restrict__ deg, float* __restrict__ pooled)
{
  int i = blockIdx.x * 256 + threadIdx.x;
  if (i < N_NODES) deg[i] = 0;
  if (i < N_B * HID) pooled[i] = 0.f;
}

__global__ __launch_bounds__(256) void count_kernel(const int* __restrict__ ei, int* __restrict__ deg)
{
  int e = blockIdx.x * 256 + threadIdx.x;
  if (e < N_EDGES) atomicAdd(&deg[ei[N_EDGES + e]], 1);
}

__global__ __launch_bounds__(256) void dinv_kernel(const int* __restrict__ deg, float* __restrict__ dinv)
{
  int i = blockIdx.x * 256 + threadIdx.x;
  if (i < N_NODES) dinv[i] = rsqrtf((float)deg[i] + 1.0f);  // +1 self loop
}

__global__ __launch_bounds__(256) void scanA_kernel(const int* __restrict__ deg, int* __restrict__ bsum)
{
  __shared__ int sd[256];
  int i = blockIdx.x * 256 + threadIdx.x;
  sd[threadIdx.x] = deg[i];
  __syncthreads();
  for (int d = 128; d > 0; d >>= 1) {
    if (threadIdx.x < d) sd[threadIdx.x] += sd[threadIdx.x + d];
    __syncthreads();
  }
  if (threadIdx.x == 0) bsum[blockIdx.x] = sd[0];
}

__global__ __launch_bounds__(256) void scanB_kernel(int* __restrict__ bsum)
{
  __shared__ int s[256];
  int tid = threadIdx.x;
  int v = bsum[tid];
  s[tid] = v;
  __syncthreads();
  for (int d = 1; d < 256; d <<= 1) {
    int add = (tid >= d) ? s[tid - d] : 0;
    __syncthreads();
    s[tid] += add;
    __syncthreads();
  }
  bsum[tid] = s[tid] - v;  // exclusive
}

__global__ __launch_bounds__(256) void scanC_kernel(const int* __restrict__ deg, const int* __restrict__ bsum,
                                                    int* __restrict__ off, int* __restrict__ cursor)
{
  __shared__ int s[256];
  int tid = threadIdx.x;
  int i = blockIdx.x * 256 + tid;
  int v = deg[i];
  s[tid] = v;
  __syncthreads();
  for (int d = 1; d < 256; d <<= 1) {
    int add = (tid >= d) ? s[tid - d] : 0;
    __syncthreads();
    s[tid] += add;
    __syncthreads();
  }
  int excl = s[tid] - v + bsum[blockIdx.x];
  off[i] = excl;
  cursor[i] = excl;
  if (i == N_NODES - 1) off[N_NODES] = excl + v;
}

// store src index AND precomputed coef = dinv[src]*dinv[dst] (linear reads in agg)
__global__ __launch_bounds__(256) void scatter_kernel(const int* __restrict__ ei, int* __restrict__ cursor,
                                                      const float* __restrict__ dinv,
                                                      int* __restrict__ csr, float* __restrict__ coef)
{
  int e = blockIdx.x * 256 + threadIdx.x;
  if (e < N_EDGES) {
    int d = ei[N_EDGES + e];
    int s = ei[e];
    int p = atomicAdd(&cursor[d], 1);
    csr[p] = s;
    coef[p] = dinv[s] * dinv[d];
  }
}

// ---------------- conv1 + relu + pool ----------------
// grid 2048 = 64 b * 32 tiles(64 pooled pos); block 256 = 16 o x 16 pg (4 pooled each).
// LDS: sx[9][136] (pg b128 reads hit banks {0,8,16,24}: conflict-free);
// sw [r][o] stride 17 (o-stride-1 reads: conflict-free).
__global__ __launch_bounds__(256) void conv1_kernel(const float* __restrict__ x, const float* __restrict__ w1,
                                                    const float* __restrict__ b1, float* __restrict__ y1)
{
  __shared__ float sx[C_IN * 136];
  __shared__ float sw[45 * 17];
  __shared__ float sb[C1];
  int tid = threadIdx.x;
  int b = blockIdx.x >> 5;
  int P0 = (blockIdx.x & 31) << 6;      // pooled tile start
  int t0 = 2 * P0 - 2;                  // x pos of sx[c][0]
  for (int i = tid; i < C_IN * 132; i += 256) {
    int c = i / 132, j = i % 132;
    int t = t0 + j;
    sx[c * 136 + j] = (t >= 0 && t < T0) ? x[(size_t)(b * C_IN + c) * T0 + t] : 0.f;
  }
  for (int i = tid; i < C1 * 45; i += 256) sw[(i % 45) * 17 + i / 45] = w1[i];
  if (tid < C1) sb[tid] = b1[tid];
  __syncthreads();

  int o = tid & 15, pg = tid >> 4;
  float bias = sb[o];
  float a[8];
  #pragma unroll
  for (int i = 0; i < 8; ++i) a[i] = bias;
  #pragma unroll
  for (int c = 0; c < C_IN; ++c) {
    float xv[12];
    #pragma unroll
    for (int q = 0; q < 3; ++q)
      *(float4*)&xv[4 * q] = *(const float4*)&sx[c * 136 + 8 * pg + 4 * q];
    const float* wr = &sw[(c * 5) * 17 + o];
    float w0 = wr[0], w1_ = wr[17], w2_ = wr[34], w3_ = wr[51], w4_ = wr[68];
    #pragma unroll
    for (int m = 0; m < 8; ++m)
      a[m] += xv[m]*w0 + xv[m+1]*w1_ + xv[m+2]*w2_ + xv[m+3]*w3_ + xv[m+4]*w4_;
  }
  float4 r;
  r.x = fmaxf(fmaxf(a[0], a[1]), 0.f);
  r.y = fmaxf(fmaxf(a[2], a[3]), 0.f);
  r.z = fmaxf(fmaxf(a[4], a[5]), 0.f);
  r.w = fmaxf(fmaxf(a[6], a[7]), 0.f);
  *(float4*)&y1[(size_t)(b * C1 + o) * T1 + P0 + 4 * pg] = r;
}

// ---------------- conv2 + relu + pool -> bf16 feats [node][32] ----------------
// grid 2048 = 64 b * 32 tiles(32 final pos); block 256 = 32 o x 8 pg (4 pos each).
__global__ __launch_bounds__(256) void conv2_kernel(const float* __restrict__ y1, const float* __restrict__ w2,
                                                    const float* __restrict__ b2, unsigned short* __restrict__ feats)
{
  __shared__ float sy[C1 * 72];
  __shared__ float sw[80 * 33];
  __shared__ float sb[C2];
  int tid = threadIdx.x;
  int b = blockIdx.x >> 5;
  int Q0 = (blockIdx.x & 31) << 5;      // final tile start
  int t0 = 2 * Q0 - 2;                  // y1 pos of sy[c][0]
  for (int i = tid; i < C1 * 68; i += 256) {
    int c = i / 68, j = i % 68;
    int t = t0 + j;
    sy[c * 72 + j] = (t >= 0 && t < T1) ? y1[(size_t)(b * C1 + c) * T1 + t] : 0.f;
  }
  for (int i = tid; i < C2 * 80; i += 256) sw[(i % 80) * 33 + i / 80] = w2[i];
  if (tid < C2) sb[tid] = b2[tid];
  __syncthreads();

  int o = tid & 31, pg = tid >> 5;
  float bias = sb[o];
  float a[8];
  #pragma unroll
  for (int i = 0; i < 8; ++i) a[i] = bias;
  #pragma unroll
  for (int c = 0; c < C1; ++c) {
    float yv[12];
    #pragma unroll
    for (int q = 0; q < 3; ++q)
      *(float4*)&yv[4 * q] = *(const float4*)&sy[c * 72 + 8 * pg + 4 * q];
    const float* wr = &sw[(c * 5) * 33 + o];
    float w0 = wr[0], w1_ = wr[33], w2_ = wr[66], w3_ = wr[99], w4_ = wr[132];
    #pragma unroll
    for (int m = 0; m < 8; ++m)
      a[m] += yv[m]*w0 + yv[m+1]*w1_ + yv[m+2]*w2_ + yv[m+3]*w3_ + yv[m+4]*w4_;
  }
  #pragma unroll
  for (int i = 0; i < 4; ++i) {
    int node = (b << 10) + Q0 + 4 * pg + i;
    feats[(size_t)node * C2 + o] = f2us(fmaxf(fmaxf(a[2*i], a[2*i+1]), 0.f));
  }
}

// ---------------- aggX: aggregate 32-dim bf16 feats -> fp32 [N,32] ----------------
// block 256 = 64 nodes x 4 lanes (8 bf16 each); grid 1024
__global__ __launch_bounds__(256) void aggX_kernel(const unsigned short* __restrict__ F, const int* __restrict__ off,
                                                   const int* __restrict__ csr, const float* __restrict__ coef,
                                                   const float* __restrict__ dinv, float* __restrict__ aggX)
{
  int tid = threadIdx.x;
  int node = (blockIdx.x << 6) + (tid >> 2);
  int jq = (tid & 3) << 3;                  // bf16 element offset
  float dn = dinv[node];
  float acc[8];
  {
    ushort8_v r = *(const ushort8_v*)(F + (size_t)node * C2 + jq);
    float c = dn * dn;
    #pragma unroll
    for (int k = 0; k < 8; ++k) acc[k] = us2f(r[k]) * c;
  }
  int e0 = off[node], e1 = off[node + 1];
  int e = e0;
  for (; e + 2 <= e1; e += 2) {
    int s0 = csr[e], s1 = csr[e + 1];
    float c0 = coef[e], c1 = coef[e + 1];
    ushort8_v r0 = *(const ushort8_v*)(F + (size_t)s0 * C2 + jq);
    ushort8_v r1 = *(const ushort8_v*)(F + (size_t)s1 * C2 + jq);
    #pragma unroll
    for (int k = 0; k < 8; ++k) acc[k] += us2f(r0[k]) * c0 + us2f(r1[k]) * c1;
  }
  if (e < e1) {
    int s0 = csr[e];
    float c0 = coef[e];
    ushort8_v r0 = *(const ushort8_v*)(F + (size_t)s0 * C2 + jq);
    #pragma unroll
    for (int k = 0; k < 8; ++k) acc[k] += us2f(r0[k]) * c0;
  }
  float* dst = aggX + (size_t)node * C2 + jq;
  *(float4*)(dst)     = make_float4(acc[0], acc[1], acc[2], acc[3]);
  *(float4*)(dst + 4) = make_float4(acc[4], acc[5], acc[6], acc[7]);
}

// ---------------- GEMM: [nodes,K] @ [K,128] -> [nodes,128] ----------------
// MODE 0: out fp32 with bias+relu.  MODE 1: out bf16 raw.
template<int K, int MODE>
__global__ __launch_bounds__(256) void gemm_kernel(const float* __restrict__ A, const float* __restrict__ W,
                                                   const float* __restrict__ bias,
                                                   float* __restrict__ Cf, unsigned short* __restrict__ Cb)
{
  __shared__ float sA[32 * K];
  int tid = threadIdx.x;
  int n0 = blockIdx.x << 5;
  for (int i = tid; i < 32 * K / 4; i += 256)
    ((float4*)sA)[i] = ((const float4*)(A + (size_t)n0 * K))[i];
  __syncthreads();
  int nq = (tid >> 5) << 2;
  int jq = (tid & 31) << 2;
  float acc[4][4] = {};
  #pragma unroll 4
  for (int i4 = 0; i4 < K / 4; ++i4) {
    float wv[4][4];
    #pragma unroll
    for (int ii = 0; ii < 4; ++ii) {
      float4 u = *(const float4*)(&W[(size_t)(i4 * 4 + ii) * HID + jq]);
      wv[ii][0] = u.x; wv[ii][1] = u.y; wv[ii][2] = u.z; wv[ii][3] = u.w;
    }
    #pragma unroll
    for (int nn = 0; nn < 4; ++nn) {
      float4 g = *(const float4*)&sA[(nq + nn) * K + (i4 << 2)];
      #pragma unroll
      for (int jj = 0; jj < 4; ++jj)
        acc[nn][jj] += g.x * wv[0][jj] + g.y * wv[1][jj] + g.z * wv[2][jj] + g.w * wv[3][jj];
    }
  }
  if (MODE == 0) {
    float b0 = bias[jq], b1 = bias[jq + 1], b2 = bias[jq + 2], b3 = bias[jq + 3];
    #pragma unroll
    for (int nn = 0; nn < 4; ++nn) {
      float4 o4 = make_float4(fmaxf(acc[nn][0] + b0, 0.f), fmaxf(acc[nn][1] + b1, 0.f),
                              fmaxf(acc[nn][2] + b2, 0.f), fmaxf(acc[nn][3] + b3, 0.f));
      *(float4*)&Cf[((size_t)(n0 + nq + nn)) * HID + jq] = o4;
    }
  } else {
    #pragma unroll
    for (int nn = 0; nn < 4; ++nn) {
      ushort4 u;
      u.x = f2us(acc[nn][0]);
      u.y = f2us(acc[nn][1]);
      u.z = f2us(acc[nn][2]);
      u.w = f2us(acc[nn][3]);
      *(ushort4*)(Cb + ((size_t)(n0 + nq + nn)) * HID + jq) = u;
    }
  }
}

// ---------------- agg2 + bias + relu + mean-pool (fused) ----------------
// block 256 = 16 nodes x 16 lanes (8 bf16 each); grid 4096; never materializes G2
__global__ __launch_bounds__(256) void agg2_pool_kernel(const unsigned short* __restrict__ Hb, const int* __restrict__ off,
                                                        const int* __restrict__ csr, const float* __restrict__ coef,
                                                        const float* __restrict__ dinv, const float* __restrict__ bias,
                                                        float* __restrict__ pooled)
{
  __shared__ float red[16][HID];           // 8 KB
  int tid = threadIdx.x;
  int g = tid >> 4;                        // local node 0..15
  int jq = (tid & 15) << 3;                // bf16 element offset 0..120
  int node = (blockIdx.x << 4) + g;
  float dn = dinv[node];
  float acc[8];
  {
    ushort8_v r = *(const ushort8_v*)(Hb + (size_t)node * HID + jq);
    float c = dn * dn;
    #pragma unroll
    for (int k = 0; k < 8; ++k) acc[k] = us2f(r[k]) * c;
  }
  int e0 = off[node], e1 = off[node + 1];
  int e = e0;
  for (; e + 2 <= e1; e += 2) {
    int s0 = csr[e], s1 = csr[e + 1];
    float c0 = coef[e], c1 = coef[e + 1];
    ushort8_v r0 = *(const ushort8_v*)(Hb + (size_t)s0 * HID + jq);
    ushort8_v r1 = *(const ushort8_v*)(Hb + (size_t)s1 * HID + jq);
    #pragma unroll
    for (int k = 0; k < 8; ++k) acc[k] += us2f(r0[k]) * c0 + us2f(r1[k]) * c1;
  }
  if (e < e1) {
    int s0 = csr[e];
    float c0 = coef[e];
    ushort8_v r0 = *(const ushort8_v*)(Hb + (size_t)s0 * HID + jq);
    #pragma unroll
    for (int k = 0; k < 8; ++k) acc[k] += us2f(r0[k]) * c0;
  }
  #pragma unroll
  for (int k = 0; k < 8; ++k)
    red[g][jq + k] = fmaxf(acc[k] + bias[jq + k], 0.f);
  __syncthreads();
  if (tid < HID) {
    float s = 0.f;
    #pragma unroll
    for (int g2 = 0; g2 < 16; ++g2) s += red[g2][tid];
    int b = blockIdx.x >> 6;               // 64 blocks per graph
    atomicAdd(&pooled[b * HID + tid], s * (1.0f / 1024.0f));
  }
}

// ---------------- classifier ----------------

__global__ __launch_bounds__(64) void cls_kernel(const float* __restrict__ pooled, const float* __restrict__ w,
                                                 const float* __restrict__ cb, float* __restrict__ out)
{
  int b = blockIdx.x, o = threadIdx.x;
  if (o < OUT_C) {
    float acc = cb[o];
    for (int i = 0; i < HID; ++i)
      acc += pooled[b * HID + i] * w[i * OUT_C + o];
    out[b * OUT_C + o] = acc;
  }
}

// ---------------- launcher ----------------

extern "C" void kernel_launch(void* const* d_in, const int* in_sizes, int n_in,
                              void* d_out, int out_size, void* d_ws, size_t ws_size,
                              hipStream_t stream)
{
  const float* x    = (const float*)d_in[0];
  const int*   ei   = (const int*)d_in[1];
  const float* c1w  = (const float*)d_in[2];
  const float* c1b  = (const float*)d_in[3];
  const float* c2w  = (const float*)d_in[4];
  const float* c2b  = (const float*)d_in[5];
  const float* g1w  = (const float*)d_in[6];
  const float* g1b  = (const float*)d_in[7];
  const float* g2w  = (const float*)d_in[8];
  const float* g2b  = (const float*)d_in[9];
  const float* clsw = (const float*)d_in[10];
  const float* clsb = (const float*)d_in[11];
  float* outp = (float*)d_out;

  char* ws = (char*)d_ws;
  size_t off_b = 0;
  auto alloc = [&](size_t bytes) { void* p = ws + off_b; off_b = (off_b + bytes + 255) & ~(size_t)255; return p; };
  int*   deg    = (int*)  alloc((size_t)N_NODES * 4);
  float* dinvv  = (float*)alloc((size_t)N_NODES * 4);
  int*   offp   = (int*)  alloc((size_t)(N_NODES + 1) * 4);
  int*   cursor = (int*)  alloc((size_t)N_NODES * 4);
  int*   bsum   = (int*)  alloc(256 * 4);
  int*   csr    = (int*)  alloc((size_t)N_EDGES * 4);
  float* coefp  = (float*)alloc((size_t)N_EDGES * 4);
  float* y1     = (float*)alloc((size_t)N_B * C1 * T1 * 4);
  unsigned short* feats = (unsigned short*)alloc((size_t)N_NODES * C2 * 2);
  float* aggX   = (float*)alloc((size_t)N_NODES * C2 * 4);
  float* G      = (float*)alloc((size_t)N_NODES * HID * 4);
  unsigned short* H = (unsigned short*)alloc((size_t)N_NODES * HID * 2);
  float* pooled = (float*)alloc((size_t)N_B * HID * 4);
  (void)ws_size; (void)in_sizes; (void)n_in; (void)out_size;

  // CSR build
  init_kernel   <<<256, 256, 0, stream>>>(deg, pooled);
  count_kernel  <<<N_EDGES / 256, 256, 0, stream>>>(ei, deg);
  dinv_kernel   <<<N_NODES / 256, 256, 0, stream>>>(deg, dinvv);
  scanA_kernel  <<<256, 256, 0, stream>>>(deg, bsum);
  scanB_kernel  <<<1, 256, 0, stream>>>(bsum);
  scanC_kernel  <<<256, 256, 0, stream>>>(deg, bsum, offp, cursor);
  scatter_kernel<<<N_EDGES / 256, 256, 0, stream>>>(ei, cursor, dinvv, csr, coefp);

  // CNN feature extractor
  conv1_kernel<<<2048, 256, 0, stream>>>(x, c1w, c1b, y1);
  conv2_kernel<<<2048, 256, 0, stream>>>(y1, c2w, c2b, feats);

  // GCN layer 1: (A X) W1 + b1, relu
  aggX_kernel<<<N_NODES / 64, 256, 0, stream>>>(feats, offp, csr, coefp, dinvv, aggX);
  gemm_kernel<32, 0><<<N_NODES / 32, 256, 0, stream>>>(aggX, g1w, g1b, G, nullptr);

  // GCN layer 2: A (G W2) + b2, relu, fused mean-pool
  gemm_kernel<128, 1><<<N_NODES / 32, 256, 0, stream>>>(G, g2w, nullptr, nullptr, H);
  agg2_pool_kernel<<<N_NODES / 16, 256, 0, stream>>>(H, offp, csr, coefp, dinvv, g2b, pooled);

  // classifier
  cls_kernel<<<N_B, 64, 0, stream>>>(pooled, clsw, clsb, outp);
}

// Round 9
// 172.156 us; speedup vs baseline: 1.6485x; 1.0964x over previous
//
#include <hip/hip_runtime.h>
#include <hip/hip_bf16.h>

typedef __hip_bfloat16 bf16;
typedef unsigned short ushort8_v __attribute__((ext_vector_type(8)));
typedef short bf16x8 __attribute__((ext_vector_type(8)));
typedef float f32x4 __attribute__((ext_vector_type(4)));

#define N_B     64
#define C_IN    9
#define T0      4096
#define C1      16
#define T1      2048
#define C2      32
#define T2      1024
#define N_NODES 65536
#define N_EDGES 524288
#define HID     128
#define OUT_C   10

__device__ __forceinline__ float us2f(unsigned short u) {
  union { unsigned int i; float f; } c; c.i = ((unsigned int)u) << 16; return c.f;
}
__device__ __forceinline__ unsigned short f2us(float f) {
  bf16 h = __float2bfloat16(f);
  unsigned short u;
  __builtin_memcpy(&u, &h, 2);
  return u;
}

// ---------------- CSR build ----------------

__global__ __launch_bounds__(256) void init_kernel(int* __restrict__ deg, float* __restrict__ pooled)
{
  int i = blockIdx.x * 256 + threadIdx.x;
  if (i < N_NODES) deg[i] = 0;
  if (i < N_B * HID) pooled[i] = 0.f;
}

__global__ __launch_bounds__(256) void count_kernel(const int* __restrict__ ei, int* __restrict__ deg)
{
  int e = blockIdx.x * 256 + threadIdx.x;
  if (e < N_EDGES) atomicAdd(&deg[ei[N_EDGES + e]], 1);
}

__global__ __launch_bounds__(256) void dinv_kernel(const int* __restrict__ deg, float* __restrict__ dinv)
{
  int i = blockIdx.x * 256 + threadIdx.x;
  if (i < N_NODES) dinv[i] = rsqrtf((float)deg[i] + 1.0f);  // +1 self loop
}

__global__ __launch_bounds__(256) void scanA_kernel(const int* __restrict__ deg, int* __restrict__ bsum)
{
  __shared__ int sd[256];
  int i = blockIdx.x * 256 + threadIdx.x;
  sd[threadIdx.x] = deg[i];
  __syncthreads();
  for (int d = 128; d > 0; d >>= 1) {
    if (threadIdx.x < d) sd[threadIdx.x] += sd[threadIdx.x + d];
    __syncthreads();
  }
  if (threadIdx.x == 0) bsum[blockIdx.x] = sd[0];
}

__global__ __launch_bounds__(256) void scanB_kernel(int* __restrict__ bsum)
{
  __shared__ int s[256];
  int tid = threadIdx.x;
  int v = bsum[tid];
  s[tid] = v;
  __syncthreads();
  for (int d = 1; d < 256; d <<= 1) {
    int add = (tid >= d) ? s[tid - d] : 0;
    __syncthreads();
    s[tid] += add;
    __syncthreads();
  }
  bsum[tid] = s[tid] - v;  // exclusive
}

__global__ __launch_bounds__(256) void scanC_kernel(const int* __restrict__ deg, const int* __restrict__ bsum,
                                                    int* __restrict__ off, int* __restrict__ cursor)
{
  __shared__ int s[256];
  int tid = threadIdx.x;
  int i = blockIdx.x * 256 + tid;
  int v = deg[i];
  s[tid] = v;
  __syncthreads();
  for (int d = 1; d < 256; d <<= 1) {
    int add = (tid >= d) ? s[tid - d] : 0;
    __syncthreads();
    s[tid] += add;
    __syncthreads();
  }
  int excl = s[tid] - v + bsum[blockIdx.x];
  off[i] = excl;
  cursor[i] = excl;
  if (i == N_NODES - 1) off[N_NODES] = excl + v;
}

// store src index AND precomputed coef = dinv[src]*dinv[dst] (linear reads in agg)
__global__ __launch_bounds__(256) void scatter_kernel(const int* __restrict__ ei, int* __restrict__ cursor,
                                                      const float* __restrict__ dinv,
                                                      int* __restrict__ csr, float* __restrict__ coef)
{
  int e = blockIdx.x * 256 + threadIdx.x;
  if (e < N_EDGES) {
    int d = ei[N_EDGES + e];
    int s = ei[e];
    int p = atomicAdd(&cursor[d], 1);
    csr[p] = s;
    coef[p] = dinv[s] * dinv[d];
  }
}

// ---------------- conv1 + relu + pool ----------------
// grid 2048 = 64 b * 32 tiles(64 pooled pos); block 256 = 16 o x 16 pg (4 pooled each).
__global__ __launch_bounds__(256) void conv1_kernel(const float* __restrict__ x, const float* __restrict__ w1,
                                                    const float* __restrict__ b1, float* __restrict__ y1)
{
  __shared__ float sx[C_IN * 136];
  __shared__ float sw[45 * 17];
  __shared__ float sb[C1];
  int tid = threadIdx.x;
  int b = blockIdx.x >> 5;
  int P0 = (blockIdx.x & 31) << 6;      // pooled tile start
  int t0 = 2 * P0 - 2;                  // x pos of sx[c][0]
  for (int i = tid; i < C_IN * 132; i += 256) {
    int c = i / 132, j = i % 132;
    int t = t0 + j;
    sx[c * 136 + j] = (t >= 0 && t < T0) ? x[(size_t)(b * C_IN + c) * T0 + t] : 0.f;
  }
  for (int i = tid; i < C1 * 45; i += 256) sw[(i % 45) * 17 + i / 45] = w1[i];
  if (tid < C1) sb[tid] = b1[tid];
  __syncthreads();

  int o = tid & 15, pg = tid >> 4;
  float bias = sb[o];
  float a[8];
  #pragma unroll
  for (int i = 0; i < 8; ++i) a[i] = bias;
  #pragma unroll
  for (int c = 0; c < C_IN; ++c) {
    float xv[12];
    #pragma unroll
    for (int q = 0; q < 3; ++q)
      *(float4*)&xv[4 * q] = *(const float4*)&sx[c * 136 + 8 * pg + 4 * q];
    const float* wr = &sw[(c * 5) * 17 + o];
    float w0 = wr[0], w1_ = wr[17], w2_ = wr[34], w3_ = wr[51], w4_ = wr[68];
    #pragma unroll
    for (int m = 0; m < 8; ++m)
      a[m] += xv[m]*w0 + xv[m+1]*w1_ + xv[m+2]*w2_ + xv[m+3]*w3_ + xv[m+4]*w4_;
  }
  float4 r;
  r.x = fmaxf(fmaxf(a[0], a[1]), 0.f);
  r.y = fmaxf(fmaxf(a[2], a[3]), 0.f);
  r.z = fmaxf(fmaxf(a[4], a[5]), 0.f);
  r.w = fmaxf(fmaxf(a[6], a[7]), 0.f);
  *(float4*)&y1[(size_t)(b * C1 + o) * T1 + P0 + 4 * pg] = r;
}

// ---------------- conv2 + relu + pool -> bf16 feats [node][32] ----------------
// grid 2048 = 64 b * 32 tiles(32 final pos); block 256 = 32 o x 8 pg (4 pos each).
__global__ __launch_bounds__(256) void conv2_kernel(const float* __restrict__ y1, const float* __restrict__ w2,
                                                    const float* __restrict__ b2, unsigned short* __restrict__ feats)
{
  __shared__ float sy[C1 * 72];
  __shared__ float sw[80 * 33];
  __shared__ float sb[C2];
  int tid = threadIdx.x;
  int b = blockIdx.x >> 5;
  int Q0 = (blockIdx.x & 31) << 5;      // final tile start
  int t0 = 2 * Q0 - 2;                  // y1 pos of sy[c][0]
  for (int i = tid; i < C1 * 68; i += 256) {
    int c = i / 68, j = i % 68;
    int t = t0 + j;
    sy[c * 72 + j] = (t >= 0 && t < T1) ? y1[(size_t)(b * C1 + c) * T1 + t] : 0.f;
  }
  for (int i = tid; i < C2 * 80; i += 256) sw[(i % 80) * 33 + i / 80] = w2[i];
  if (tid < C2) sb[tid] = b2[tid];
  __syncthreads();

  int o = tid & 31, pg = tid >> 5;
  float bias = sb[o];
  float a[8];
  #pragma unroll
  for (int i = 0; i < 8; ++i) a[i] = bias;
  #pragma unroll
  for (int c = 0; c < C1; ++c) {
    float yv[12];
    #pragma unroll
    for (int q = 0; q < 3; ++q)
      *(float4*)&yv[4 * q] = *(const float4*)&sy[c * 72 + 8 * pg + 4 * q];
    const float* wr = &sw[(c * 5) * 33 + o];
    float w0 = wr[0], w1_ = wr[33], w2_ = wr[66], w3_ = wr[99], w4_ = wr[132];
    #pragma unroll
    for (int m = 0; m < 8; ++m)
      a[m] += yv[m]*w0 + yv[m+1]*w1_ + yv[m+2]*w2_ + yv[m+3]*w3_ + yv[m+4]*w4_;
  }
  #pragma unroll
  for (int i = 0; i < 4; ++i) {
    int node = (b << 10) + Q0 + 4 * pg + i;
    feats[(size_t)node * C2 + o] = f2us(fmaxf(fmaxf(a[2*i], a[2*i+1]), 0.f));
  }
}

// ---------------- aggX: aggregate 32-dim bf16 feats -> fp32 [N,32] ----------------
// block 256 = 64 nodes x 4 lanes (8 bf16 each); grid 1024
__global__ __launch_bounds__(256) void aggX_kernel(const unsigned short* __restrict__ F, const int* __restrict__ off,
                                                   const int* __restrict__ csr, const float* __restrict__ coef,
                                                   const float* __restrict__ dinv, float* __restrict__ aggX)
{
  int tid = threadIdx.x;
  int node = (blockIdx.x << 6) + (tid >> 2);
  int jq = (tid & 3) << 3;                  // bf16 element offset
  float dn = dinv[node];
  float acc[8];
  {
    ushort8_v r = *(const ushort8_v*)(F + (size_t)node * C2 + jq);
    float c = dn * dn;
    #pragma unroll
    for (int k = 0; k < 8; ++k) acc[k] = us2f(r[k]) * c;
  }
  int e0 = off[node], e1 = off[node + 1];
  int e = e0;
  for (; e + 2 <= e1; e += 2) {
    int s0 = csr[e], s1 = csr[e + 1];
    float c0 = coef[e], c1 = coef[e + 1];
    ushort8_v r0 = *(const ushort8_v*)(F + (size_t)s0 * C2 + jq);
    ushort8_v r1 = *(const ushort8_v*)(F + (size_t)s1 * C2 + jq);
    #pragma unroll
    for (int k = 0; k < 8; ++k) acc[k] += us2f(r0[k]) * c0 + us2f(r1[k]) * c1;
  }
  if (e < e1) {
    int s0 = csr[e];
    float c0 = coef[e];
    ushort8_v r0 = *(const ushort8_v*)(F + (size_t)s0 * C2 + jq);
    #pragma unroll
    for (int k = 0; k < 8; ++k) acc[k] += us2f(r0[k]) * c0;
  }
  float* dst = aggX + (size_t)node * C2 + jq;
  *(float4*)(dst)     = make_float4(acc[0], acc[1], acc[2], acc[3]);
  *(float4*)(dst + 4) = make_float4(acc[4], acc[5], acc[6], acc[7]);
}

// ---------------- GEMM1: [nodes,32] @ [32,128] + bias, relu -> bf16 G ----------------
__global__ __launch_bounds__(256) void gemm1_kernel(const float* __restrict__ A, const float* __restrict__ W,
                                                    const float* __restrict__ bias, unsigned short* __restrict__ Cb)
{
  __shared__ float sA[32 * 32];
  int tid = threadIdx.x;
  int n0 = blockIdx.x << 5;
  for (int i = tid; i < 32 * 32 / 4; i += 256)
    ((float4*)sA)[i] = ((const float4*)(A + (size_t)n0 * 32))[i];
  __syncthreads();
  int nq = (tid >> 5) << 2;
  int jq = (tid & 31) << 2;
  float acc[4][4] = {};
  #pragma unroll
  for (int i4 = 0; i4 < 8; ++i4) {
    float wv[4][4];
    #pragma unroll
    for (int ii = 0; ii < 4; ++ii) {
      float4 u = *(const float4*)(&W[(size_t)(i4 * 4 + ii) * HID + jq]);
      wv[ii][0] = u.x; wv[ii][1] = u.y; wv[ii][2] = u.z; wv[ii][3] = u.w;
    }
    #pragma unroll
    for (int nn = 0; nn < 4; ++nn) {
      float4 g = *(const float4*)&sA[(nq + nn) * 32 + (i4 << 2)];
      #pragma unroll
      for (int jj = 0; jj < 4; ++jj)
        acc[nn][jj] += g.x * wv[0][jj] + g.y * wv[1][jj] + g.z * wv[2][jj] + g.w * wv[3][jj];
    }
  }
  float b0 = bias[jq], b1 = bias[jq + 1], b2 = bias[jq + 2], b3 = bias[jq + 3];
  #pragma unroll
  for (int nn = 0; nn < 4; ++nn) {
    ushort4 u;
    u.x = f2us(fmaxf(acc[nn][0] + b0, 0.f));
    u.y = f2us(fmaxf(acc[nn][1] + b1, 0.f));
    u.z = f2us(fmaxf(acc[nn][2] + b2, 0.f));
    u.w = f2us(fmaxf(acc[nn][3] + b3, 0.f));
    *(ushort4*)(Cb + ((size_t)(n0 + nq + nn)) * HID + jq) = u;
  }
}

// ---------------- GEMM2 (MFMA bf16): H = G @ W2, bf16 in/out, fp32 accum ----------------
// grid 1024 = 64 nodes/block; block 256 = 4 waves x 16 nodes.
// W2 staged transposed in LDS as bf16 [j][k] stride 136 (pad -> 2-way reads, free).
// mfma_f32_16x16x32_bf16: A lane l: row=l&15, k=(l>>4)*8+i ; B: col=l&15, same k ;
// C lane l reg r: row=(l>>4)*4+r, col=l&15  (m89-verified layout).
__global__ __launch_bounds__(256) void gemm2_mfma_kernel(const unsigned short* __restrict__ Gb,
                                                         const float* __restrict__ W2,
                                                         unsigned short* __restrict__ Hb)
{
  __shared__ unsigned short sw[HID * 136];   // 34.8 KB
  int tid = threadIdx.x;
  // stage W2^T: read W2[k][j0..j0+3] (coalesced float4), write sw[j][k] as bf16
  for (int i = tid; i < HID * 32; i += 256) {
    int k = i >> 5;
    int j4 = (i & 31) << 2;
    float4 v = *(const float4*)&W2[(size_t)k * HID + j4];
    sw[(j4 + 0) * 136 + k] = f2us(v.x);
    sw[(j4 + 1) * 136 + k] = f2us(v.y);
    sw[(j4 + 2) * 136 + k] = f2us(v.z);
    sw[(j4 + 3) * 136 + k] = f2us(v.w);
  }
  __syncthreads();

  int w = tid >> 6, l = tid & 63;
  int lr = l & 15, lk = l >> 4;
  int n0 = (blockIdx.x << 6) + (w << 4);     // 16 nodes for this wave
  const short* Gs = (const short*)Gb;

  bf16x8 af[4];
  #pragma unroll
  for (int ks = 0; ks < 4; ++ks)
    af[ks] = *(const bf16x8*)(Gs + (size_t)(n0 + lr) * HID + ks * 32 + lk * 8);

  #pragma unroll
  for (int nt = 0; nt < 8; ++nt) {
    f32x4 acc = {0.f, 0.f, 0.f, 0.f};
    #pragma unroll
    for (int ks = 0; ks < 4; ++ks) {
      bf16x8 bf = *(const bf16x8*)((const short*)sw + (nt * 16 + lr) * 136 + ks * 32 + lk * 8);
      acc = __builtin_amdgcn_mfma_f32_16x16x32_bf16(af[ks], bf, acc, 0, 0, 0);
    }
    #pragma unroll
    for (int r = 0; r < 4; ++r) {
      int row = lk * 4 + r;
      Hb[(size_t)(n0 + row) * HID + nt * 16 + lr] = f2us(acc[r]);
    }
  }
}

// ---------------- agg2 + bias + relu + mean-pool (fused) ----------------
// block 256 = 16 nodes x 16 lanes (8 bf16 each); grid 4096; never materializes G2
__global__ __launch_bounds__(256) void agg2_pool_kernel(const unsigned short* __restrict__ Hb, const int* __restrict__ off,
                                                        const int* __restrict__ csr, const float* __restrict__ coef,
                                                        const float* __restrict__ dinv, const float* __restrict__ bias,
                                                        float* __restrict__ pooled)
{
  __shared__ float red[16][HID];           // 8 KB
  int tid = threadIdx.x;
  int g = tid >> 4;                        // local node 0..15
  int jq = (tid & 15) << 3;                // bf16 element offset 0..120
  int node = (blockIdx.x << 4) + g;
  float dn = dinv[node];
  float acc[8];
  {
    ushort8_v r = *(const ushort8_v*)(Hb + (size_t)node * HID + jq);
    float c = dn * dn;
    #pragma unroll
    for (int k = 0; k < 8; ++k) acc[k] = us2f(r[k]) * c;
  }
  int e0 = off[node], e1 = off[node + 1];
  int e = e0;
  for (; e + 2 <= e1; e += 2) {
    int s0 = csr[e], s1 = csr[e + 1];
    float c0 = coef[e], c1 = coef[e + 1];
    ushort8_v r0 = *(const ushort8_v*)(Hb + (size_t)s0 * HID + jq);
    ushort8_v r1 = *(const ushort8_v*)(Hb + (size_t)s1 * HID + jq);
    #pragma unroll
    for (int k = 0; k < 8; ++k) acc[k] += us2f(r0[k]) * c0 + us2f(r1[k]) * c1;
  }
  if (e < e1) {
    int s0 = csr[e];
    float c0 = coef[e];
    ushort8_v r0 = *(const ushort8_v*)(Hb + (size_t)s0 * HID + jq);
    #pragma unroll
    for (int k = 0; k < 8; ++k) acc[k] += us2f(r0[k]) * c0;
  }
  #pragma unroll
  for (int k = 0; k < 8; ++k)
    red[g][jq + k] = fmaxf(acc[k] + bias[jq + k], 0.f);
  __syncthreads();
  if (tid < HID) {
    float s = 0.f;
    #pragma unroll
    for (int g2 = 0; g2 < 16; ++g2) s += red[g2][tid];
    int b = blockIdx.x >> 6;               // 64 blocks per graph
    atomicAdd(&pooled[b * HID + tid], s * (1.0f / 1024.0f));
  }
}

// ---------------- classifier ----------------

__global__ __launch_bounds__(64) void cls_kernel(const float* __restrict__ pooled, const float* __restrict__ w,
                                                 const float* __restrict__ cb, float* __restrict__ out)
{
  int b = blockIdx.x, o = threadIdx.x;
  if (o < OUT_C) {
    float acc = cb[o];
    for (int i = 0; i < HID; ++i)
      acc += pooled[b * HID + i] * w[i * OUT_C + o];
    out[b * OUT_C + o] = acc;
  }
}

// ---------------- launcher ----------------

extern "C" void kernel_launch(void* const* d_in, const int* in_sizes, int n_in,
                              void* d_out, int out_size, void* d_ws, size_t ws_size,
                              hipStream_t stream)
{
  const float* x    = (const float*)d_in[0];
  const int*   ei   = (const int*)d_in[1];
  const float* c1w  = (const float*)d_in[2];
  const float* c1b  = (const float*)d_in[3];
  const float* c2w  = (const float*)d_in[4];
  const float* c2b  = (const float*)d_in[5];
  const float* g1w  = (const float*)d_in[6];
  const float* g1b  = (const float*)d_in[7];
  const float* g2w  = (const float*)d_in[8];
  const float* g2b  = (const float*)d_in[9];
  const float* clsw = (const float*)d_in[10];
  const float* clsb = (const float*)d_in[11];
  float* outp = (float*)d_out;

  char* ws = (char*)d_ws;
  size_t off_b = 0;
  auto alloc = [&](size_t bytes) { void* p = ws + off_b; off_b = (off_b + bytes + 255) & ~(size_t)255; return p; };
  int*   deg    = (int*)  alloc((size_t)N_NODES * 4);
  float* dinvv  = (float*)alloc((size_t)N_NODES * 4);
  int*   offp   = (int*)  alloc((size_t)(N_NODES + 1) * 4);
  int*   cursor = (int*)  alloc((size_t)N_NODES * 4);
  int*   bsum   = (int*)  alloc(256 * 4);
  int*   csr    = (int*)  alloc((size_t)N_EDGES * 4);
  float* coefp  = (float*)alloc((size_t)N_EDGES * 4);
  float* y1     = (float*)alloc((size_t)N_B * C1 * T1 * 4);
  unsigned short* feats = (unsigned short*)alloc((size_t)N_NODES * C2 * 2);
  float* aggX   = (float*)alloc((size_t)N_NODES * C2 * 4);
  unsigned short* G = (unsigned short*)alloc((size_t)N_NODES * HID * 2);
  unsigned short* H = (unsigned short*)alloc((size_t)N_NODES * HID * 2);
  float* pooled = (float*)alloc((size_t)N_B * HID * 4);
  (void)ws_size; (void)in_sizes; (void)n_in; (void)out_size;

  // CSR build
  init_kernel   <<<256, 256, 0, stream>>>(deg, pooled);
  count_kernel  <<<N_EDGES / 256, 256, 0, stream>>>(ei, deg);
  dinv_kernel   <<<N_NODES / 256, 256, 0, stream>>>(deg, dinvv);
  scanA_kernel  <<<256, 256, 0, stream>>>(deg, bsum);
  scanB_kernel  <<<1, 256, 0, stream>>>(bsum);
  scanC_kernel  <<<256, 256, 0, stream>>>(deg, bsum, offp, cursor);
  scatter_kernel<<<N_EDGES / 256, 256, 0, stream>>>(ei, cursor, dinvv, csr, coefp);

  // CNN feature extractor
  conv1_kernel<<<2048, 256, 0, stream>>>(x, c1w, c1b, y1);
  conv2_kernel<<<2048, 256, 0, stream>>>(y1, c2w, c2b, feats);

  // GCN layer 1: (A X) W1 + b1, relu -> bf16 G
  aggX_kernel<<<N_NODES / 64, 256, 0, stream>>>(feats, offp, csr, coefp, dinvv, aggX);
  gemm1_kernel<<<N_NODES / 32, 256, 0, stream>>>(aggX, g1w, g1b, G);

  // GCN layer 2: A (G W2) + b2, relu, fused mean-pool
  gemm2_mfma_kernel<<<N_NODES / 64, 256, 0, stream>>>(G, g2w, H);
  agg2_pool_kernel<<<N_NODES / 16, 256, 0, stream>>>(H, offp, csr, coefp, dinvv, g2b, pooled);

  // classifier
  cls_kernel<<<N_B, 64, 0, stream>>>(pooled, clsw, clsb, outp);
}

// Round 10
// 141.745 us; speedup vs baseline: 2.0022x; 1.2145x over previous
//
#include <hip/hip_runtime.h>
#include <hip/hip_bf16.h>

typedef __hip_bfloat16 bf16;
typedef unsigned short ushort8_v __attribute__((ext_vector_type(8)));
typedef short bf16x8 __attribute__((ext_vector_type(8)));
typedef float f32x4 __attribute__((ext_vector_type(4)));

#define N_B     64
#define C_IN    9
#define T0      4096
#define C1      16
#define T1      2048
#define C2      32
#define T2      1024
#define N_NODES 65536
#define N_EDGES 524288
#define HID     128
#define OUT_C   10

__device__ __forceinline__ float us2f(unsigned short u) {
  union { unsigned int i; float f; } c; c.i = ((unsigned int)u) << 16; return c.f;
}
__device__ __forceinline__ unsigned short f2us(float f) {
  bf16 h = __float2bfloat16(f);
  unsigned short u;
  __builtin_memcpy(&u, &h, 2);
  return u;
}

// ---------------- graph build: ONE atomic pass, no scans, no coef ----------------

__global__ __launch_bounds__(256) void init_kernel(int* __restrict__ cnt, float* __restrict__ pooled)
{
  int i = blockIdx.x * 256 + threadIdx.x;
  if (i < N_NODES) cnt[i] = 0;
  if (i < N_B * HID) pooled[i] = 0.f;
}

// slots[d*64 + rank] = src ; cnt ends as degree
__global__ __launch_bounds__(256) void scatter_direct_kernel(const int* __restrict__ ei, int* __restrict__ cnt,
                                                             int* __restrict__ slots)
{
  int e = blockIdx.x * 256 + threadIdx.x;
  if (e < N_EDGES) {
    int d = ei[N_EDGES + e];
    int s = ei[e];
    int r = atomicAdd(&cnt[d], 1);
    slots[((size_t)d << 6) + r] = s;
  }
}

__global__ __launch_bounds__(256) void dinv_kernel(const int* __restrict__ cnt, float* __restrict__ dinv)
{
  int i = blockIdx.x * 256 + threadIdx.x;
  if (i < N_NODES) dinv[i] = rsqrtf((float)cnt[i] + 1.0f);  // +1 self loop
}

// ---------------- conv1 + relu + pool ----------------
// grid 2048 = 64 b * 32 tiles(64 pooled pos); block 256 = 16 o x 16 pg (4 pooled each).
__global__ __launch_bounds__(256) void conv1_kernel(const float* __restrict__ x, const float* __restrict__ w1,
                                                    const float* __restrict__ b1, float* __restrict__ y1)
{
  __shared__ float sx[C_IN * 136];
  __shared__ float sw[45 * 17];
  __shared__ float sb[C1];
  int tid = threadIdx.x;
  int b = blockIdx.x >> 5;
  int P0 = (blockIdx.x & 31) << 6;      // pooled tile start
  int t0 = 2 * P0 - 2;                  // x pos of sx[c][0]
  for (int i = tid; i < C_IN * 132; i += 256) {
    int c = i / 132, j = i % 132;
    int t = t0 + j;
    sx[c * 136 + j] = (t >= 0 && t < T0) ? x[(size_t)(b * C_IN + c) * T0 + t] : 0.f;
  }
  for (int i = tid; i < C1 * 45; i += 256) sw[(i % 45) * 17 + i / 45] = w1[i];
  if (tid < C1) sb[tid] = b1[tid];
  __syncthreads();

  int o = tid & 15, pg = tid >> 4;
  float bias = sb[o];
  float a[8];
  #pragma unroll
  for (int i = 0; i < 8; ++i) a[i] = bias;
  #pragma unroll
  for (int c = 0; c < C_IN; ++c) {
    float xv[12];
    #pragma unroll
    for (int q = 0; q < 3; ++q)
      *(float4*)&xv[4 * q] = *(const float4*)&sx[c * 136 + 8 * pg + 4 * q];
    const float* wr = &sw[(c * 5) * 17 + o];
    float w0 = wr[0], w1_ = wr[17], w2_ = wr[34], w3_ = wr[51], w4_ = wr[68];
    #pragma unroll
    for (int m = 0; m < 8; ++m)
      a[m] += xv[m]*w0 + xv[m+1]*w1_ + xv[m+2]*w2_ + xv[m+3]*w3_ + xv[m+4]*w4_;
  }
  float4 r;
  r.x = fmaxf(fmaxf(a[0], a[1]), 0.f);
  r.y = fmaxf(fmaxf(a[2], a[3]), 0.f);
  r.z = fmaxf(fmaxf(a[4], a[5]), 0.f);
  r.w = fmaxf(fmaxf(a[6], a[7]), 0.f);
  *(float4*)&y1[(size_t)(b * C1 + o) * T1 + P0 + 4 * pg] = r;
}

// ---------------- conv2 + relu + pool -> PRE-SCALED bf16 feats F~ = F * dinv[node] ----------------
// grid 2048 = 64 b * 32 tiles(32 final pos); block 256 = 32 o x 8 pg (4 pos each).
__global__ __launch_bounds__(256) void conv2_kernel(const float* __restrict__ y1, const float* __restrict__ w2,
                                                    const float* __restrict__ b2, const float* __restrict__ dinv,
                                                    unsigned short* __restrict__ feats)
{
  __shared__ float sy[C1 * 72];
  __shared__ float sw[80 * 33];
  __shared__ float sb[C2];
  int tid = threadIdx.x;
  int b = blockIdx.x >> 5;
  int Q0 = (blockIdx.x & 31) << 5;      // final tile start
  int t0 = 2 * Q0 - 2;                  // y1 pos of sy[c][0]
  for (int i = tid; i < C1 * 68; i += 256) {
    int c = i / 68, j = i % 68;
    int t = t0 + j;
    sy[c * 72 + j] = (t >= 0 && t < T1) ? y1[(size_t)(b * C1 + c) * T1 + t] : 0.f;
  }
  for (int i = tid; i < C2 * 80; i += 256) sw[(i % 80) * 33 + i / 80] = w2[i];
  if (tid < C2) sb[tid] = b2[tid];
  __syncthreads();

  int o = tid & 31, pg = tid >> 5;
  float bias = sb[o];
  float a[8];
  #pragma unroll
  for (int i = 0; i < 8; ++i) a[i] = bias;
  #pragma unroll
  for (int c = 0; c < C1; ++c) {
    float yv[12];
    #pragma unroll
    for (int q = 0; q < 3; ++q)
      *(float4*)&yv[4 * q] = *(const float4*)&sy[c * 72 + 8 * pg + 4 * q];
    const float* wr = &sw[(c * 5) * 33 + o];
    float w0 = wr[0], w1_ = wr[33], w2_ = wr[66], w3_ = wr[99], w4_ = wr[132];
    #pragma unroll
    for (int m = 0; m < 8; ++m)
      a[m] += yv[m]*w0 + yv[m+1]*w1_ + yv[m+2]*w2_ + yv[m+3]*w3_ + yv[m+4]*w4_;
  }
  #pragma unroll
  for (int i = 0; i < 4; ++i) {
    int node = (b << 10) + Q0 + 4 * pg + i;
    float dv = dinv[node];
    feats[(size_t)node * C2 + o] = f2us(fmaxf(fmaxf(a[2*i], a[2*i+1]), 0.f) * dv);
  }
}

// ---------------- aggX: aggX[n] = dinv[n] * (F~[n] + sum_slots F~[s]) -> fp32 [N,32] ----------------
// block 256 = 64 nodes x 4 lanes (8 bf16 each); grid 1024
__global__ __launch_bounds__(256) void aggX_kernel(const unsigned short* __restrict__ F, const int* __restrict__ cnt,
                                                   const int* __restrict__ slots, const float* __restrict__ dinv,
                                                   float* __restrict__ aggX)
{
  int tid = threadIdx.x;
  int node = (blockIdx.x << 6) + (tid >> 2);
  int jq = (tid & 3) << 3;                  // bf16 element offset
  float dn = dinv[node];
  float acc[8];
  {
    ushort8_v r = *(const ushort8_v*)(F + (size_t)node * C2 + jq);
    #pragma unroll
    for (int k = 0; k < 8; ++k) acc[k] = us2f(r[k]);
  }
  const int* sl = slots + ((size_t)node << 6);
  int e1 = cnt[node];
  int e = 0;
  for (; e + 2 <= e1; e += 2) {
    int s0 = sl[e], s1 = sl[e + 1];
    ushort8_v r0 = *(const ushort8_v*)(F + (size_t)s0 * C2 + jq);
    ushort8_v r1 = *(const ushort8_v*)(F + (size_t)s1 * C2 + jq);
    #pragma unroll
    for (int k = 0; k < 8; ++k) acc[k] += us2f(r0[k]) + us2f(r1[k]);
  }
  if (e < e1) {
    int s0 = sl[e];
    ushort8_v r0 = *(const ushort8_v*)(F + (size_t)s0 * C2 + jq);
    #pragma unroll
    for (int k = 0; k < 8; ++k) acc[k] += us2f(r0[k]);
  }
  float* dst = aggX + (size_t)node * C2 + jq;
  *(float4*)(dst)     = make_float4(acc[0]*dn, acc[1]*dn, acc[2]*dn, acc[3]*dn);
  *(float4*)(dst + 4) = make_float4(acc[4]*dn, acc[5]*dn, acc[6]*dn, acc[7]*dn);
}

// ---------------- GEMM1: [nodes,32] @ [32,128] + bias, relu -> bf16 G ----------------
__global__ __launch_bounds__(256) void gemm1_kernel(const float* __restrict__ A, const float* __restrict__ W,
                                                    const float* __restrict__ bias, unsigned short* __restrict__ Cb)
{
  __shared__ float sA[32 * 32];
  int tid = threadIdx.x;
  int n0 = blockIdx.x << 5;
  for (int i = tid; i < 32 * 32 / 4; i += 256)
    ((float4*)sA)[i] = ((const float4*)(A + (size_t)n0 * 32))[i];
  __syncthreads();
  int nq = (tid >> 5) << 2;
  int jq = (tid & 31) << 2;
  float acc[4][4] = {};
  #pragma unroll
  for (int i4 = 0; i4 < 8; ++i4) {
    float wv[4][4];
    #pragma unroll
    for (int ii = 0; ii < 4; ++ii) {
      float4 u = *(const float4*)(&W[(size_t)(i4 * 4 + ii) * HID + jq]);
      wv[ii][0] = u.x; wv[ii][1] = u.y; wv[ii][2] = u.z; wv[ii][3] = u.w;
    }
    #pragma unroll
    for (int nn = 0; nn < 4; ++nn) {
      float4 g = *(const float4*)&sA[(nq + nn) * 32 + (i4 << 2)];
      #pragma unroll
      for (int jj = 0; jj < 4; ++jj)
        acc[nn][jj] += g.x * wv[0][jj] + g.y * wv[1][jj] + g.z * wv[2][jj] + g.w * wv[3][jj];
    }
  }
  float b0 = bias[jq], b1 = bias[jq + 1], b2 = bias[jq + 2], b3 = bias[jq + 3];
  #pragma unroll
  for (int nn = 0; nn < 4; ++nn) {
    ushort4 u;
    u.x = f2us(fmaxf(acc[nn][0] + b0, 0.f));
    u.y = f2us(fmaxf(acc[nn][1] + b1, 0.f));
    u.z = f2us(fmaxf(acc[nn][2] + b2, 0.f));
    u.w = f2us(fmaxf(acc[nn][3] + b3, 0.f));
    *(ushort4*)(Cb + ((size_t)(n0 + nq + nn)) * HID + jq) = u;
  }
}

// ---------------- GEMM2 (MFMA bf16): H~ = (G @ W2) * dinv[row], bf16 out, fp32 accum ----------------
// grid 1024 = 64 nodes/block; block 256 = 4 waves x 16 nodes.
// W2 staged transposed in LDS as bf16 [j][k] stride 136.
// mfma_f32_16x16x32_bf16 layouts per m89: A: row=l&15,k=(l>>4)*8+i ; B: col=l&15 ;
// C: col=l&15, row=(l>>4)*4+r.
__global__ __launch_bounds__(256) void gemm2_mfma_kernel(const unsigned short* __restrict__ Gb,
                                                         const float* __restrict__ W2,
                                                         const float* __restrict__ dinv,
                                                         unsigned short* __restrict__ Hb)
{
  __shared__ unsigned short sw[HID * 136];   // 34.8 KB
  int tid = threadIdx.x;
  for (int i = tid; i < HID * 32; i += 256) {
    int k = i >> 5;
    int j4 = (i & 31) << 2;
    float4 v = *(const float4*)&W2[(size_t)k * HID + j4];
    sw[(j4 + 0) * 136 + k] = f2us(v.x);
    sw[(j4 + 1) * 136 + k] = f2us(v.y);
    sw[(j4 + 2) * 136 + k] = f2us(v.z);
    sw[(j4 + 3) * 136 + k] = f2us(v.w);
  }
  __syncthreads();

  int w = tid >> 6, l = tid & 63;
  int lr = l & 15, lk = l >> 4;
  int n0 = (blockIdx.x << 6) + (w << 4);     // 16 nodes for this wave
  const short* Gs = (const short*)Gb;

  bf16x8 af[4];
  #pragma unroll
  for (int ks = 0; ks < 4; ++ks)
    af[ks] = *(const bf16x8*)(Gs + (size_t)(n0 + lr) * HID + ks * 32 + lk * 8);

  float4 dv = *(const float4*)&dinv[n0 + lk * 4];   // dinv for this lane's 4 C-rows
  float dvr[4] = {dv.x, dv.y, dv.z, dv.w};

  #pragma unroll
  for (int nt = 0; nt < 8; ++nt) {
    f32x4 acc = {0.f, 0.f, 0.f, 0.f};
    #pragma unroll
    for (int ks = 0; ks < 4; ++ks) {
      bf16x8 bf = *(const bf16x8*)((const short*)sw + (nt * 16 + lr) * 136 + ks * 32 + lk * 8);
      acc = __builtin_amdgcn_mfma_f32_16x16x32_bf16(af[ks], bf, acc, 0, 0, 0);
    }
    #pragma unroll
    for (int r = 0; r < 4; ++r) {
      int row = lk * 4 + r;
      Hb[(size_t)(n0 + row) * HID + nt * 16 + lr] = f2us(acc[r] * dvr[r]);
    }
  }
}

// ---------------- agg2 + bias + relu + mean-pool: dinv[n]*(H~[n]+sum H~[s]) ----------------
// block 256 = 16 nodes x 16 lanes (8 bf16 each); grid 4096; never materializes G2
__global__ __launch_bounds__(256) void agg2_pool_kernel(const unsigned short* __restrict__ Hb, const int* __restrict__ cnt,
                                                        const int* __restrict__ slots, const float* __restrict__ dinv,
                                                        const float* __restrict__ bias, float* __restrict__ pooled)
{
  __shared__ float red[16][HID];           // 8 KB
  int tid = threadIdx.x;
  int g = tid >> 4;                        // local node 0..15
  int jq = (tid & 15) << 3;                // bf16 element offset 0..120
  int node = (blockIdx.x << 4) + g;
  float dn = dinv[node];
  float acc[8];
  {
    ushort8_v r = *(const ushort8_v*)(Hb + (size_t)node * HID + jq);
    #pragma unroll
    for (int k = 0; k < 8; ++k) acc[k] = us2f(r[k]);
  }
  const int* sl = slots + ((size_t)node << 6);
  int e1 = cnt[node];
  int e = 0;
  for (; e + 2 <= e1; e += 2) {
    int s0 = sl[e], s1 = sl[e + 1];
    ushort8_v r0 = *(const ushort8_v*)(Hb + (size_t)s0 * HID + jq);
    ushort8_v r1 = *(const ushort8_v*)(Hb + (size_t)s1 * HID + jq);
    #pragma unroll
    for (int k = 0; k < 8; ++k) acc[k] += us2f(r0[k]) + us2f(r1[k]);
  }
  if (e < e1) {
    int s0 = sl[e];
    ushort8_v r0 = *(const ushort8_v*)(Hb + (size_t)s0 * HID + jq);
    #pragma unroll
    for (int k = 0; k < 8; ++k) acc[k] += us2f(r0[k]);
  }
  #pragma unroll
  for (int k = 0; k < 8; ++k)
    red[g][jq + k] = fmaxf(dn * acc[k] + bias[jq + k], 0.f);
  __syncthreads();
  if (tid < HID) {
    float s = 0.f;
    #pragma unroll
    for (int g2 = 0; g2 < 16; ++g2) s += red[g2][tid];
    int b = blockIdx.x >> 6;               // 64 blocks per graph
    atomicAdd(&pooled[b * HID + tid], s * (1.0f / 1024.0f));
  }
}

// ---------------- classifier ----------------

__global__ __launch_bounds__(64) void cls_kernel(const float* __restrict__ pooled, const float* __restrict__ w,
                                                 const float* __restrict__ cb, float* __restrict__ out)
{
  int b = blockIdx.x, o = threadIdx.x;
  if (o < OUT_C) {
    float acc = cb[o];
    for (int i = 0; i < HID; ++i)
      acc += pooled[b * HID + i] * w[i * OUT_C + o];
    out[b * OUT_C + o] = acc;
  }
}

// ---------------- launcher ----------------

extern "C" void kernel_launch(void* const* d_in, const int* in_sizes, int n_in,
                              void* d_out, int out_size, void* d_ws, size_t ws_size,
                              hipStream_t stream)
{
  const float* x    = (const float*)d_in[0];
  const int*   ei   = (const int*)d_in[1];
  const float* c1w  = (const float*)d_in[2];
  const float* c1b  = (const float*)d_in[3];
  const float* c2w  = (const float*)d_in[4];
  const float* c2b  = (const float*)d_in[5];
  const float* g1w  = (const float*)d_in[6];
  const float* g1b  = (const float*)d_in[7];
  const float* g2w  = (const float*)d_in[8];
  const float* g2b  = (const float*)d_in[9];
  const float* clsw = (const float*)d_in[10];
  const float* clsb = (const float*)d_in[11];
  float* outp = (float*)d_out;

  char* ws = (char*)d_ws;
  size_t off_b = 0;
  auto alloc = [&](size_t bytes) { void* p = ws + off_b; off_b = (off_b + bytes + 255) & ~(size_t)255; return p; };
  int*   cnt    = (int*)  alloc((size_t)N_NODES * 4);
  float* dinvv  = (float*)alloc((size_t)N_NODES * 4);
  int*   slots  = (int*)  alloc((size_t)N_NODES * 64 * 4);   // 16 MB
  float* y1     = (float*)alloc((size_t)N_B * C1 * T1 * 4);
  unsigned short* feats = (unsigned short*)alloc((size_t)N_NODES * C2 * 2);
  float* aggX   = (float*)alloc((size_t)N_NODES * C2 * 4);
  unsigned short* G = (unsigned short*)alloc((size_t)N_NODES * HID * 2);
  unsigned short* H = (unsigned short*)alloc((size_t)N_NODES * HID * 2);
  float* pooled = (float*)alloc((size_t)N_B * HID * 4);
  (void)ws_size; (void)in_sizes; (void)n_in; (void)out_size;

  // graph build: single atomic pass
  init_kernel          <<<256, 256, 0, stream>>>(cnt, pooled);
  scatter_direct_kernel<<<N_EDGES / 256, 256, 0, stream>>>(ei, cnt, slots);
  dinv_kernel          <<<N_NODES / 256, 256, 0, stream>>>(cnt, dinvv);

  // CNN feature extractor (conv2 pre-scales by dinv)
  conv1_kernel<<<2048, 256, 0, stream>>>(x, c1w, c1b, y1);
  conv2_kernel<<<2048, 256, 0, stream>>>(y1, c2w, c2b, dinvv, feats);

  // GCN layer 1: (A X) W1 + b1, relu -> bf16 G
  aggX_kernel<<<N_NODES / 64, 256, 0, stream>>>(feats, cnt, slots, dinvv, aggX);
  gemm1_kernel<<<N_NODES / 32, 256, 0, stream>>>(aggX, g1w, g1b, G);

  // GCN layer 2: A (G W2) + b2, relu, fused mean-pool
  gemm2_mfma_kernel<<<N_NODES / 64, 256, 0, stream>>>(G, g2w, dinvv, H);
  agg2_pool_kernel<<<N_NODES / 16, 256, 0, stream>>>(H, cnt, slots, dinvv, g2b, pooled);

  // classifier
  cls_kernel<<<N_B, 64, 0, stream>>>(pooled, clsw, clsb, outp);
}

// Round 11
// 131.590 us; speedup vs baseline: 2.1567x; 1.0772x over previous
//
#include <hip/hip_runtime.h>
#include <hip/hip_bf16.h>

typedef __hip_bfloat16 bf16;
typedef unsigned short ushort8_v __attribute__((ext_vector_type(8)));
typedef short bf16x8 __attribute__((ext_vector_type(8)));
typedef float f32x4 __attribute__((ext_vector_type(4)));

#define N_B     64
#define C_IN    9
#define T0      4096
#define C1      16
#define T1      2048
#define C2      32
#define T2      1024
#define N_NODES 65536
#define N_EDGES 524288
#define HID     128
#define OUT_C   10

__device__ __forceinline__ float us2f(unsigned short u) {
  union { unsigned int i; float f; } c; c.i = ((unsigned int)u) << 16; return c.f;
}
__device__ __forceinline__ unsigned short f2us(float f) {
  bf16 h = __float2bfloat16(f);
  unsigned short u;
  __builtin_memcpy(&u, &h, 2);
  return u;
}

// ---------------- init ----------------

__global__ __launch_bounds__(256) void init_kernel(int* __restrict__ cnt, float* __restrict__ pooled)
{
  int i = blockIdx.x * 256 + threadIdx.x;
  if (i < N_NODES) cnt[i] = 0;
  if (i < N_B * HID) pooled[i] = 0.f;
}

// ---------------- fused: scatter (blocks 0..2047) || conv1+relu+pool (blocks 2048..4095) ----------------
// scatter: slots[d*64+rank]=src, cnt ends as degree (one atomic pass).
// conv1: 16 o x 16 pg, 4 pooled pos/thread, bf16 y1 out.
__global__ __launch_bounds__(256) void conv1_scatter_kernel(const float* __restrict__ x, const float* __restrict__ w1,
                                                            const float* __restrict__ b1,
                                                            const int* __restrict__ ei, int* __restrict__ cnt,
                                                            int* __restrict__ slots, unsigned short* __restrict__ y1)
{
  __shared__ float sx[C_IN * 136];
  __shared__ float sw[45 * 17];
  __shared__ float sb[C1];
  int tid = threadIdx.x;
  if (blockIdx.x < 2048) {
    int e = blockIdx.x * 256 + tid;
    int d = ei[N_EDGES + e];
    int s = ei[e];
    int r = atomicAdd(&cnt[d], 1);
    slots[((size_t)d << 6) + r] = s;
    return;
  }
  int blk = blockIdx.x - 2048;
  int b = blk >> 5;
  int P0 = (blk & 31) << 6;             // pooled tile start
  int t0 = 2 * P0 - 2;                  // x pos of sx[c][0]
  for (int i = tid; i < C_IN * 132; i += 256) {
    int c = i / 132, j = i % 132;
    int t = t0 + j;
    sx[c * 136 + j] = (t >= 0 && t < T0) ? x[(size_t)(b * C_IN + c) * T0 + t] : 0.f;
  }
  for (int i = tid; i < C1 * 45; i += 256) sw[(i % 45) * 17 + i / 45] = w1[i];
  if (tid < C1) sb[tid] = b1[tid];
  __syncthreads();

  int o = tid & 15, pg = tid >> 4;
  float bias = sb[o];
  float a[8];
  #pragma unroll
  for (int i = 0; i < 8; ++i) a[i] = bias;
  #pragma unroll
  for (int c = 0; c < C_IN; ++c) {
    float xv[12];
    #pragma unroll
    for (int q = 0; q < 3; ++q)
      *(float4*)&xv[4 * q] = *(const float4*)&sx[c * 136 + 8 * pg + 4 * q];
    const float* wr = &sw[(c * 5) * 17 + o];
    float w0 = wr[0], w1_ = wr[17], w2_ = wr[34], w3_ = wr[51], w4_ = wr[68];
    #pragma unroll
    for (int m = 0; m < 8; ++m)
      a[m] += xv[m]*w0 + xv[m+1]*w1_ + xv[m+2]*w2_ + xv[m+3]*w3_ + xv[m+4]*w4_;
  }
  ushort4 r;
  r.x = f2us(fmaxf(fmaxf(a[0], a[1]), 0.f));
  r.y = f2us(fmaxf(fmaxf(a[2], a[3]), 0.f));
  r.z = f2us(fmaxf(fmaxf(a[4], a[5]), 0.f));
  r.w = f2us(fmaxf(fmaxf(a[6], a[7]), 0.f));
  *(ushort4*)&y1[(size_t)(b * C1 + o) * T1 + P0 + 4 * pg] = r;
}

__global__ __launch_bounds__(256) void dinv_kernel(const int* __restrict__ cnt, float* __restrict__ dinv)
{
  int i = blockIdx.x * 256 + threadIdx.x;
  if (i < N_NODES) dinv[i] = rsqrtf((float)cnt[i] + 1.0f);  // +1 self loop
}

// ---------------- conv2 + relu + pool -> PRE-SCALED bf16 feats F~ = F * dinv[node] ----------------
// grid 2048 = 64 b * 32 tiles(32 final pos); block 256 = 32 o x 8 pg (4 pos each).
__global__ __launch_bounds__(256) void conv2_kernel(const unsigned short* __restrict__ y1, const float* __restrict__ w2,
                                                    const float* __restrict__ b2, const float* __restrict__ dinv,
                                                    unsigned short* __restrict__ feats)
{
  __shared__ float sy[C1 * 72];
  __shared__ float sw[80 * 33];
  __shared__ float sb[C2];
  int tid = threadIdx.x;
  int b = blockIdx.x >> 5;
  int Q0 = (blockIdx.x & 31) << 5;      // final tile start
  int t0 = 2 * Q0 - 2;                  // y1 pos of sy[c][0]
  for (int i = tid; i < C1 * 68; i += 256) {
    int c = i / 68, j = i % 68;
    int t = t0 + j;
    sy[c * 72 + j] = (t >= 0 && t < T1) ? us2f(y1[(size_t)(b * C1 + c) * T1 + t]) : 0.f;
  }
  for (int i = tid; i < C2 * 80; i += 256) sw[(i % 80) * 33 + i / 80] = w2[i];
  if (tid < C2) sb[tid] = b2[tid];
  __syncthreads();

  int o = tid & 31, pg = tid >> 5;
  float bias = sb[o];
  float a[8];
  #pragma unroll
  for (int i = 0; i < 8; ++i) a[i] = bias;
  #pragma unroll
  for (int c = 0; c < C1; ++c) {
    float yv[12];
    #pragma unroll
    for (int q = 0; q < 3; ++q)
      *(float4*)&yv[4 * q] = *(const float4*)&sy[c * 72 + 8 * pg + 4 * q];
    const float* wr = &sw[(c * 5) * 33 + o];
    float w0 = wr[0], w1_ = wr[33], w2_ = wr[66], w3_ = wr[99], w4_ = wr[132];
    #pragma unroll
    for (int m = 0; m < 8; ++m)
      a[m] += yv[m]*w0 + yv[m+1]*w1_ + yv[m+2]*w2_ + yv[m+3]*w3_ + yv[m+4]*w4_;
  }
  #pragma unroll
  for (int i = 0; i < 4; ++i) {
    int node = (b << 10) + Q0 + 4 * pg + i;
    float dv = dinv[node];
    feats[(size_t)node * C2 + o] = f2us(fmaxf(fmaxf(a[2*i], a[2*i+1]), 0.f) * dv);
  }
}

// ---------------- fused aggX + GEMM1 + GEMM2(MFMA): F~ -> H~ (64 nodes/block) ----------------
// Phase A: agg = dinv[n]*(F~[n]+sum F~[s]) -> sAgg[64][36] fp32 (stride 36: 16B-aligned b128 reads)
// Phase B: G = relu(agg @ W1 + b1) -> bf16 sG[64][136]
// Phase C: H~ = (G @ W2) * dinv[row]  via mfma_f32_16x16x32_bf16 (m89 layout), W2^T bf16 in sw2[128][136]
__global__ __launch_bounds__(256) void agg_gemm_kernel(const unsigned short* __restrict__ F,
                                                       const int* __restrict__ cnt, const int* __restrict__ slots,
                                                       const float* __restrict__ dinv,
                                                       const float* __restrict__ W1, const float* __restrict__ gb1,
                                                       const float* __restrict__ W2,
                                                       unsigned short* __restrict__ Hb)
{
  __shared__ float sAgg[64 * 36];            // 9.2 KB
  __shared__ unsigned short sG[64 * 136];    // 17.4 KB
  __shared__ unsigned short sw2[HID * 136];  // 34.8 KB
  int tid = threadIdx.x;
  int n0b = blockIdx.x << 6;

  // stage W2^T as bf16 [j][k]
  for (int i = tid; i < HID * 32; i += 256) {
    int k = i >> 5, j4 = (i & 31) << 2;
    float4 v = *(const float4*)&W2[(size_t)k * HID + j4];
    sw2[(j4 + 0) * 136 + k] = f2us(v.x);
    sw2[(j4 + 1) * 136 + k] = f2us(v.y);
    sw2[(j4 + 2) * 136 + k] = f2us(v.z);
    sw2[(j4 + 3) * 136 + k] = f2us(v.w);
  }

  // phase A: gather-aggregate (4 lanes/node x 8 bf16)
  {
    int ln = tid >> 2;
    int node = n0b + ln;
    int jq = (tid & 3) << 3;
    float dn = dinv[node];
    float acc[8];
    ushort8_v r = *(const ushort8_v*)(F + (size_t)node * C2 + jq);
    #pragma unroll
    for (int k = 0; k < 8; ++k) acc[k] = us2f(r[k]);
    const int* sl = slots + ((size_t)node << 6);
    int e1 = cnt[node];
    int e = 0;
    for (; e + 2 <= e1; e += 2) {
      int s0 = sl[e], s1 = sl[e + 1];
      ushort8_v r0 = *(const ushort8_v*)(F + (size_t)s0 * C2 + jq);
      ushort8_v r1 = *(const ushort8_v*)(F + (size_t)s1 * C2 + jq);
      #pragma unroll
      for (int k = 0; k < 8; ++k) acc[k] += us2f(r0[k]) + us2f(r1[k]);
    }
    if (e < e1) {
      int s0 = sl[e];
      ushort8_v r0 = *(const ushort8_v*)(F + (size_t)s0 * C2 + jq);
      #pragma unroll
      for (int k = 0; k < 8; ++k) acc[k] += us2f(r0[k]);
    }
    #pragma unroll
    for (int k = 0; k < 8; ++k) sAgg[ln * 36 + jq + k] = acc[k] * dn;
  }
  __syncthreads();

  // phase B: 8 node-groups x 32 j-groups; 8 nodes x 4 j per thread
  {
    int ng = tid >> 5;
    int jq4 = (tid & 31) << 2;
    float acc[8][4] = {};
    #pragma unroll
    for (int i4 = 0; i4 < 8; ++i4) {
      float wv[4][4];
      #pragma unroll
      for (int ii = 0; ii < 4; ++ii) {
        float4 u = *(const float4*)&W1[(size_t)(i4 * 4 + ii) * HID + jq4];
        wv[ii][0] = u.x; wv[ii][1] = u.y; wv[ii][2] = u.z; wv[ii][3] = u.w;
      }
      #pragma unroll
      for (int nn = 0; nn < 8; ++nn) {
        float4 g = *(const float4*)&sAgg[(ng * 8 + nn) * 36 + i4 * 4];
        #pragma unroll
        for (int jj = 0; jj < 4; ++jj)
          acc[nn][jj] += g.x * wv[0][jj] + g.y * wv[1][jj] + g.z * wv[2][jj] + g.w * wv[3][jj];
      }
    }
    float b0 = gb1[jq4], bb1 = gb1[jq4 + 1], b2 = gb1[jq4 + 2], b3 = gb1[jq4 + 3];
    #pragma unroll
    for (int nn = 0; nn < 8; ++nn) {
      ushort4 u;
      u.x = f2us(fmaxf(acc[nn][0] + b0, 0.f));
      u.y = f2us(fmaxf(acc[nn][1] + bb1, 0.f));
      u.z = f2us(fmaxf(acc[nn][2] + b2, 0.f));
      u.w = f2us(fmaxf(acc[nn][3] + b3, 0.f));
      *(ushort4*)&sG[(ng * 8 + nn) * 136 + jq4] = u;
    }
  }
  __syncthreads();

  // phase C: 4 waves x 16 nodes, MFMA from LDS
  {
    int w = tid >> 6, l = tid & 63;
    int lr = l & 15, lk = l >> 4;
    int nloc = w << 4;
    bf16x8 af[4];
    #pragma unroll
    for (int ks = 0; ks < 4; ++ks)
      af[ks] = *(const bf16x8*)((const short*)sG + (size_t)(nloc + lr) * 136 + ks * 32 + lk * 8);
    float4 dv = *(const float4*)&dinv[n0b + nloc + lk * 4];
    float dvr[4] = {dv.x, dv.y, dv.z, dv.w};
    #pragma unroll
    for (int nt = 0; nt < 8; ++nt) {
      f32x4 acc = {0.f, 0.f, 0.f, 0.f};
      #pragma unroll
      for (int ks = 0; ks < 4; ++ks) {
        bf16x8 bf = *(const bf16x8*)((const short*)sw2 + (size_t)(nt * 16 + lr) * 136 + ks * 32 + lk * 8);
        acc = __builtin_amdgcn_mfma_f32_16x16x32_bf16(af[ks], bf, acc, 0, 0, 0);
      }
      #pragma unroll
      for (int r = 0; r < 4; ++r)
        Hb[(size_t)(n0b + nloc + lk * 4 + r) * HID + nt * 16 + lr] = f2us(acc[r] * dvr[r]);
    }
  }
}

// ---------------- agg2 + bias + relu + mean-pool: dinv[n]*(H~[n]+sum H~[s]) ----------------
// block 256 = 16 nodes x 16 lanes (8 bf16 each); grid 4096; never materializes G2
__global__ __launch_bounds__(256) void agg2_pool_kernel(const unsigned short* __restrict__ Hb, const int* __restrict__ cnt,
                                                        const int* __restrict__ slots, const float* __restrict__ dinv,
                                                        const float* __restrict__ bias, float* __restrict__ pooled)
{
  __shared__ float red[16][HID];           // 8 KB
  int tid = threadIdx.x;
  int g = tid >> 4;                        // local node 0..15
  int jq = (tid & 15) << 3;                // bf16 element offset 0..120
  int node = (blockIdx.x << 4) + g;
  float dn = dinv[node];
  float acc[8];
  {
    ushort8_v r = *(const ushort8_v*)(Hb + (size_t)node * HID + jq);
    #pragma unroll
    for (int k = 0; k < 8; ++k) acc[k] = us2f(r[k]);
  }
  const int* sl = slots + ((size_t)node << 6);
  int e1 = cnt[node];
  int e = 0;
  for (; e + 2 <= e1; e += 2) {
    int s0 = sl[e], s1 = sl[e + 1];
    ushort8_v r0 = *(const ushort8_v*)(Hb + (size_t)s0 * HID + jq);
    ushort8_v r1 = *(const ushort8_v*)(Hb + (size_t)s1 * HID + jq);
    #pragma unroll
    for (int k = 0; k < 8; ++k) acc[k] += us2f(r0[k]) + us2f(r1[k]);
  }
  if (e < e1) {
    int s0 = sl[e];
    ushort8_v r0 = *(const ushort8_v*)(Hb + (size_t)s0 * HID + jq);
    #pragma unroll
    for (int k = 0; k < 8; ++k) acc[k] += us2f(r0[k]);
  }
  #pragma unroll
  for (int k = 0; k < 8; ++k)
    red[g][jq + k] = fmaxf(dn * acc[k] + bias[jq + k], 0.f);
  __syncthreads();
  if (tid < HID) {
    float s = 0.f;
    #pragma unroll
    for (int g2 = 0; g2 < 16; ++g2) s += red[g2][tid];
    int b = blockIdx.x >> 6;               // 64 blocks per graph
    atomicAdd(&pooled[b * HID + tid], s * (1.0f / 1024.0f));
  }
}

// ---------------- classifier ----------------

__global__ __launch_bounds__(64) void cls_kernel(const float* __restrict__ pooled, const float* __restrict__ w,
                                                 const float* __restrict__ cb, float* __restrict__ out)
{
  int b = blockIdx.x, o = threadIdx.x;
  if (o < OUT_C) {
    float acc = cb[o];
    for (int i = 0; i < HID; ++i)
      acc += pooled[b * HID + i] * w[i * OUT_C + o];
    out[b * OUT_C + o] = acc;
  }
}

// ---------------- launcher ----------------

extern "C" void kernel_launch(void* const* d_in, const int* in_sizes, int n_in,
                              void* d_out, int out_size, void* d_ws, size_t ws_size,
                              hipStream_t stream)
{
  const float* x    = (const float*)d_in[0];
  const int*   ei   = (const int*)d_in[1];
  const float* c1w  = (const float*)d_in[2];
  const float* c1b  = (const float*)d_in[3];
  const float* c2w  = (const float*)d_in[4];
  const float* c2b  = (const float*)d_in[5];
  const float* g1w  = (const float*)d_in[6];
  const float* g1b  = (const float*)d_in[7];
  const float* g2w  = (const float*)d_in[8];
  const float* g2b  = (const float*)d_in[9];
  const float* clsw = (const float*)d_in[10];
  const float* clsb = (const float*)d_in[11];
  float* outp = (float*)d_out;

  char* ws = (char*)d_ws;
  size_t off_b = 0;
  auto alloc = [&](size_t bytes) { void* p = ws + off_b; off_b = (off_b + bytes + 255) & ~(size_t)255; return p; };
  int*   cnt    = (int*)  alloc((size_t)N_NODES * 4);
  float* dinvv  = (float*)alloc((size_t)N_NODES * 4);
  int*   slots  = (int*)  alloc((size_t)N_NODES * 64 * 4);   // 16 MB
  unsigned short* y1    = (unsigned short*)alloc((size_t)N_B * C1 * T1 * 2);
  unsigned short* feats = (unsigned short*)alloc((size_t)N_NODES * C2 * 2);
  unsigned short* H     = (unsigned short*)alloc((size_t)N_NODES * HID * 2);
  float* pooled = (float*)alloc((size_t)N_B * HID * 4);
  (void)ws_size; (void)in_sizes; (void)n_in; (void)out_size;

  // init, then scatter || conv1 (independent, fused launch)
  init_kernel         <<<256, 256, 0, stream>>>(cnt, pooled);
  conv1_scatter_kernel<<<4096, 256, 0, stream>>>(x, c1w, c1b, ei, cnt, slots, y1);
  dinv_kernel         <<<N_NODES / 256, 256, 0, stream>>>(cnt, dinvv);

  // conv2 (pre-scales by dinv)
  conv2_kernel<<<2048, 256, 0, stream>>>(y1, c2w, c2b, dinvv, feats);

  // GCN layer 1 + gemm of layer 2, fused per 64-node tile
  agg_gemm_kernel<<<N_NODES / 64, 256, 0, stream>>>(feats, cnt, slots, dinvv, g1w, g1b, g2w, H);

  // GCN layer 2 aggregation + bias + relu + mean-pool
  agg2_pool_kernel<<<N_NODES / 16, 256, 0, stream>>>(H, cnt, slots, dinvv, g2b, pooled);

  // classifier
  cls_kernel<<<N_B, 64, 0, stream>>>(pooled, clsw, clsb, outp);
}

// Round 12
// 119.612 us; speedup vs baseline: 2.3727x; 1.1001x over previous
//
#include <hip/hip_runtime.h>
#include <hip/hip_bf16.h>

typedef __hip_bfloat16 bf16;
typedef unsigned short ushort8_v __attribute__((ext_vector_type(8)));
typedef short bf16x8 __attribute__((ext_vector_type(8)));
typedef float f32x4 __attribute__((ext_vector_type(4)));

#define N_B     64
#define C_IN    9
#define T0      4096
#define C1      16
#define T1      2048
#define C2      32
#define T2      1024
#define N_NODES 65536
#define N_EDGES 524288
#define HID     128
#define OUT_C   10
#define SLOT_CAP 32

__device__ __forceinline__ float us2f(unsigned short u) {
  union { unsigned int i; float f; } c; c.i = ((unsigned int)u) << 16; return c.f;
}
__device__ __forceinline__ unsigned short f2us(float f) {
  bf16 h = __float2bfloat16(f);
  unsigned short u;
  __builtin_memcpy(&u, &h, 2);
  return u;
}

// ---------------- init ----------------

__global__ __launch_bounds__(256) void init_kernel(int* __restrict__ cnt, float* __restrict__ pooled)
{
  int i = blockIdx.x * 256 + threadIdx.x;
  if (i < N_NODES) cnt[i] = 0;
  if (i < N_B * HID) pooled[i] = 0.f;
}

// ---------------- fused: scatter (blocks 0..2047) || conv1+relu+pool (blocks 2048..4095) ----------------
// slots: ushort, 32 per node = exactly one 64B line/node (4 MB total, L2-resident).
__global__ __launch_bounds__(256) void conv1_scatter_kernel(const float* __restrict__ x, const float* __restrict__ w1,
                                                            const float* __restrict__ b1,
                                                            const int* __restrict__ ei, int* __restrict__ cnt,
                                                            unsigned short* __restrict__ slots,
                                                            unsigned short* __restrict__ y1)
{
  __shared__ float sx[C_IN * 136];
  __shared__ float sw[45 * 17];
  __shared__ float sb[C1];
  int tid = threadIdx.x;
  if (blockIdx.x < 2048) {
    int e = blockIdx.x * 256 + tid;
    int d = ei[N_EDGES + e];
    int s = ei[e];
    int r = atomicAdd(&cnt[d], 1);
    if (r < SLOT_CAP) slots[((size_t)d << 5) + r] = (unsigned short)s;
    return;
  }
  int blk = blockIdx.x - 2048;
  int b = blk >> 5;
  int P0 = (blk & 31) << 6;             // pooled tile start
  int t0 = 2 * P0 - 2;                  // x pos of sx[c][0]
  for (int i = tid; i < C_IN * 132; i += 256) {
    int c = i / 132, j = i % 132;
    int t = t0 + j;
    sx[c * 136 + j] = (t >= 0 && t < T0) ? x[(size_t)(b * C_IN + c) * T0 + t] : 0.f;
  }
  for (int i = tid; i < C1 * 45; i += 256) sw[(i % 45) * 17 + i / 45] = w1[i];
  if (tid < C1) sb[tid] = b1[tid];
  __syncthreads();

  int o = tid & 15, pg = tid >> 4;
  float bias = sb[o];
  float a[8];
  #pragma unroll
  for (int i = 0; i < 8; ++i) a[i] = bias;
  #pragma unroll
  for (int c = 0; c < C_IN; ++c) {
    float xv[12];
    #pragma unroll
    for (int q = 0; q < 3; ++q)
      *(float4*)&xv[4 * q] = *(const float4*)&sx[c * 136 + 8 * pg + 4 * q];
    const float* wr = &sw[(c * 5) * 17 + o];
    float w0 = wr[0], w1_ = wr[17], w2_ = wr[34], w3_ = wr[51], w4_ = wr[68];
    #pragma unroll
    for (int m = 0; m < 8; ++m)
      a[m] += xv[m]*w0 + xv[m+1]*w1_ + xv[m+2]*w2_ + xv[m+3]*w3_ + xv[m+4]*w4_;
  }
  ushort4 r;
  r.x = f2us(fmaxf(fmaxf(a[0], a[1]), 0.f));
  r.y = f2us(fmaxf(fmaxf(a[2], a[3]), 0.f));
  r.z = f2us(fmaxf(fmaxf(a[4], a[5]), 0.f));
  r.w = f2us(fmaxf(fmaxf(a[6], a[7]), 0.f));
  *(ushort4*)&y1[(size_t)(b * C1 + o) * T1 + P0 + 4 * pg] = r;
}

__global__ __launch_bounds__(256) void dinv_kernel(const int* __restrict__ cnt, float* __restrict__ dinv)
{
  int i = blockIdx.x * 256 + threadIdx.x;
  if (i < N_NODES) dinv[i] = rsqrtf((float)cnt[i] + 1.0f);  // +1 self loop
}

// ---------------- conv2 + relu + pool -> PRE-SCALED bf16 feats F~ = F * dinv[node] ----------------
__global__ __launch_bounds__(256) void conv2_kernel(const unsigned short* __restrict__ y1, const float* __restrict__ w2,
                                                    const float* __restrict__ b2, const float* __restrict__ dinv,
                                                    unsigned short* __restrict__ feats)
{
  __shared__ float sy[C1 * 72];
  __shared__ float sw[80 * 33];
  __shared__ float sb[C2];
  int tid = threadIdx.x;
  int b = blockIdx.x >> 5;
  int Q0 = (blockIdx.x & 31) << 5;      // final tile start
  int t0 = 2 * Q0 - 2;                  // y1 pos of sy[c][0]
  for (int i = tid; i < C1 * 68; i += 256) {
    int c = i / 68, j = i % 68;
    int t = t0 + j;
    sy[c * 72 + j] = (t >= 0 && t < T1) ? us2f(y1[(size_t)(b * C1 + c) * T1 + t]) : 0.f;
  }
  for (int i = tid; i < C2 * 80; i += 256) sw[(i % 80) * 33 + i / 80] = w2[i];
  if (tid < C2) sb[tid] = b2[tid];
  __syncthreads();

  int o = tid & 31, pg = tid >> 5;
  float bias = sb[o];
  float a[8];
  #pragma unroll
  for (int i = 0; i < 8; ++i) a[i] = bias;
  #pragma unroll
  for (int c = 0; c < C1; ++c) {
    float yv[12];
    #pragma unroll
    for (int q = 0; q < 3; ++q)
      *(float4*)&yv[4 * q] = *(const float4*)&sy[c * 72 + 8 * pg + 4 * q];
    const float* wr = &sw[(c * 5) * 33 + o];
    float w0 = wr[0], w1_ = wr[33], w2_ = wr[66], w3_ = wr[99], w4_ = wr[132];
    #pragma unroll
    for (int m = 0; m < 8; ++m)
      a[m] += yv[m]*w0 + yv[m+1]*w1_ + yv[m+2]*w2_ + yv[m+3]*w3_ + yv[m+4]*w4_;
  }
  #pragma unroll
  for (int i = 0; i < 4; ++i) {
    int node = (b << 10) + Q0 + 4 * pg + i;
    float dv = dinv[node];
    feats[(size_t)node * C2 + o] = f2us(fmaxf(fmaxf(a[2*i], a[2*i+1]), 0.f) * dv);
  }
}

// ---------------- aggX: dinv[n]*(F~[n]+sum F~[s]) -> bf16 [N,32]; lean, high-occupancy ----------------
// block 256 = 64 nodes x 4 lanes (8 bf16 each); grid 1024
__global__ __launch_bounds__(256) void aggX_kernel(const unsigned short* __restrict__ F, const int* __restrict__ cnt,
                                                   const unsigned short* __restrict__ slots,
                                                   const float* __restrict__ dinv,
                                                   unsigned short* __restrict__ aggXb)
{
  int tid = threadIdx.x;
  int node = (blockIdx.x << 6) + (tid >> 2);
  int jq = (tid & 3) << 3;                  // bf16 element offset
  float dn = dinv[node];
  float acc[8];
  {
    ushort8_v r = *(const ushort8_v*)(F + (size_t)node * C2 + jq);
    #pragma unroll
    for (int k = 0; k < 8; ++k) acc[k] = us2f(r[k]);
  }
  const unsigned short* sl = slots + ((size_t)node << 5);
  int e1 = min(cnt[node], SLOT_CAP);
  int e = 0;
  for (; e + 2 <= e1; e += 2) {
    int s0 = sl[e], s1 = sl[e + 1];
    ushort8_v r0 = *(const ushort8_v*)(F + (size_t)s0 * C2 + jq);
    ushort8_v r1 = *(const ushort8_v*)(F + (size_t)s1 * C2 + jq);
    #pragma unroll
    for (int k = 0; k < 8; ++k) acc[k] += us2f(r0[k]) + us2f(r1[k]);
  }
  if (e < e1) {
    int s0 = sl[e];
    ushort8_v r0 = *(const ushort8_v*)(F + (size_t)s0 * C2 + jq);
    #pragma unroll
    for (int k = 0; k < 8; ++k) acc[k] += us2f(r0[k]);
  }
  ushort8_v o;
  #pragma unroll
  for (int k = 0; k < 8; ++k) o[k] = f2us(acc[k] * dn);
  *(ushort8_v*)(aggXb + (size_t)node * C2 + jq) = o;
}

// ---------------- gemm12 (all-MFMA): G = relu(aggX@W1+b1); H~ = (G@W2)*dinv ----------------
// grid 1024 = 64 nodes/block; block 256 = 4 waves x 16 nodes.
// LDS: W1^T bf16 [j=128][k=32] stride 36; G bf16 [64][132]; W2^T bf16 [j=128][k=128] stride 132.
// mfma_f32_16x16x32_bf16 (m89): A row=l&15,k=(l>>4)*8+i ; B col=l&15,same k ; C col=l&15,row=(l>>4)*4+r.
__global__ __launch_bounds__(256) void gemm12_kernel(const unsigned short* __restrict__ aggXb,
                                                     const float* __restrict__ W1, const float* __restrict__ gb1,
                                                     const float* __restrict__ W2, const float* __restrict__ dinv,
                                                     unsigned short* __restrict__ Hb)
{
  __shared__ unsigned short sw1[32 * 36 * 4];   // [j][k] stride 36: 9.2 KB (128*36)
  __shared__ unsigned short sG[64 * 132];       // 16.9 KB
  __shared__ unsigned short sw2[HID * 132];     // 33.8 KB
  int tid = threadIdx.x;
  int n0b = blockIdx.x << 6;

  // stage W1^T: W1 is [k=32][j=128] fp32
  for (int i = tid; i < 32 * 32; i += 256) {
    int k = i >> 5, j4 = (i & 31) << 2;
    float4 v = *(const float4*)&W1[(size_t)k * HID + j4];
    sw1[(j4 + 0) * 36 + k] = f2us(v.x);
    sw1[(j4 + 1) * 36 + k] = f2us(v.y);
    sw1[(j4 + 2) * 36 + k] = f2us(v.z);
    sw1[(j4 + 3) * 36 + k] = f2us(v.w);
  }
  // stage W2^T: W2 is [k=128][j=128] fp32
  for (int i = tid; i < HID * 32; i += 256) {
    int k = i >> 5, j4 = (i & 31) << 2;
    float4 v = *(const float4*)&W2[(size_t)k * HID + j4];
    sw2[(j4 + 0) * 132 + k] = f2us(v.x);
    sw2[(j4 + 1) * 132 + k] = f2us(v.y);
    sw2[(j4 + 2) * 132 + k] = f2us(v.z);
    sw2[(j4 + 3) * 132 + k] = f2us(v.w);
  }
  __syncthreads();

  int w = tid >> 6, l = tid & 63;
  int lr = l & 15, lk = l >> 4;
  int nloc = w << 4;

  // GEMM1: A-frag straight from global bf16 aggX rows
  bf16x8 af1 = *(const bf16x8*)((const short*)aggXb + (size_t)(n0b + nloc + lr) * C2 + lk * 8);
  #pragma unroll
  for (int jt = 0; jt < 8; ++jt) {
    f32x4 acc = {0.f, 0.f, 0.f, 0.f};
    bf16x8 bf = *(const bf16x8*)((const short*)sw1 + (size_t)(jt * 16 + lr) * 36 + lk * 8);
    acc = __builtin_amdgcn_mfma_f32_16x16x32_bf16(af1, bf, acc, 0, 0, 0);
    float bj = gb1[jt * 16 + lr];
    #pragma unroll
    for (int r = 0; r < 4; ++r)
      sG[(size_t)(nloc + lk * 4 + r) * 132 + jt * 16 + lr] = f2us(fmaxf(acc[r] + bj, 0.f));
  }
  __syncthreads();

  // GEMM2 from LDS
  bf16x8 af2[4];
  #pragma unroll
  for (int ks = 0; ks < 4; ++ks)
    af2[ks] = *(const bf16x8*)((const short*)sG + (size_t)(nloc + lr) * 132 + ks * 32 + lk * 8);
  float4 dv = *(const float4*)&dinv[n0b + nloc + lk * 4];
  float dvr[4] = {dv.x, dv.y, dv.z, dv.w};
  #pragma unroll
  for (int nt = 0; nt < 8; ++nt) {
    f32x4 acc = {0.f, 0.f, 0.f, 0.f};
    #pragma unroll
    for (int ks = 0; ks < 4; ++ks) {
      bf16x8 bf = *(const bf16x8*)((const short*)sw2 + (size_t)(nt * 16 + lr) * 132 + ks * 32 + lk * 8);
      acc = __builtin_amdgcn_mfma_f32_16x16x32_bf16(af2[ks], bf, acc, 0, 0, 0);
    }
    #pragma unroll
    for (int r = 0; r < 4; ++r)
      Hb[(size_t)(n0b + nloc + lk * 4 + r) * HID + nt * 16 + lr] = f2us(acc[r] * dvr[r]);
  }
}

// ---------------- agg2 + bias + relu + mean-pool: dinv[n]*(H~[n]+sum H~[s]) ----------------
// block 256 = 16 nodes x 16 lanes (8 bf16 each); grid 4096
__global__ __launch_bounds__(256) void agg2_pool_kernel(const unsigned short* __restrict__ Hb, const int* __restrict__ cnt,
                                                        const unsigned short* __restrict__ slots,
                                                        const float* __restrict__ dinv,
                                                        const float* __restrict__ bias, float* __restrict__ pooled)
{
  __shared__ float red[16][HID];           // 8 KB
  int tid = threadIdx.x;
  int g = tid >> 4;                        // local node 0..15
  int jq = (tid & 15) << 3;                // bf16 element offset 0..120
  int node = (blockIdx.x << 4) + g;
  float dn = dinv[node];
  float acc[8];
  {
    ushort8_v r = *(const ushort8_v*)(Hb + (size_t)node * HID + jq);
    #pragma unroll
    for (int k = 0; k < 8; ++k) acc[k] = us2f(r[k]);
  }
  const unsigned short* sl = slots + ((size_t)node << 5);
  int e1 = min(cnt[node], SLOT_CAP);
  int e = 0;
  for (; e + 2 <= e1; e += 2) {
    int s0 = sl[e], s1 = sl[e + 1];
    ushort8_v r0 = *(const ushort8_v*)(Hb + (size_t)s0 * HID + jq);
    ushort8_v r1 = *(const ushort8_v*)(Hb + (size_t)s1 * HID + jq);
    #pragma unroll
    for (int k = 0; k < 8; ++k) acc[k] += us2f(r0[k]) + us2f(r1[k]);
  }
  if (e < e1) {
    int s0 = sl[e];
    ushort8_v r0 = *(const ushort8_v*)(Hb + (size_t)s0 * HID + jq);
    #pragma unroll
    for (int k = 0; k < 8; ++k) acc[k] += us2f(r0[k]);
  }
  #pragma unroll
  for (int k = 0; k < 8; ++k)
    red[g][jq + k] = fmaxf(dn * acc[k] + bias[jq + k], 0.f);
  __syncthreads();
  if (tid < HID) {
    float s = 0.f;
    #pragma unroll
    for (int g2 = 0; g2 < 16; ++g2) s += red[g2][tid];
    int b = blockIdx.x >> 6;               // 64 blocks per graph
    atomicAdd(&pooled[b * HID + tid], s * (1.0f / 1024.0f));
  }
}

// ---------------- classifier ----------------

__global__ __launch_bounds__(64) void cls_kernel(const float* __restrict__ pooled, const float* __restrict__ w,
                                                 const float* __restrict__ cb, float* __restrict__ out)
{
  int b = blockIdx.x, o = threadIdx.x;
  if (o < OUT_C) {
    float acc = cb[o];
    for (int i = 0; i < HID; ++i)
      acc += pooled[b * HID + i] * w[i * OUT_C + o];
    out[b * OUT_C + o] = acc;
  }
}

// ---------------- launcher ----------------

extern "C" void kernel_launch(void* const* d_in, const int* in_sizes, int n_in,
                              void* d_out, int out_size, void* d_ws, size_t ws_size,
                              hipStream_t stream)
{
  const float* x    = (const float*)d_in[0];
  const int*   ei   = (const int*)d_in[1];
  const float* c1w  = (const float*)d_in[2];
  const float* c1b  = (const float*)d_in[3];
  const float* c2w  = (const float*)d_in[4];
  const float* c2b  = (const float*)d_in[5];
  const float* g1w  = (const float*)d_in[6];
  const float* g1b  = (const float*)d_in[7];
  const float* g2w  = (const float*)d_in[8];
  const float* g2b  = (const float*)d_in[9];
  const float* clsw = (const float*)d_in[10];
  const float* clsb = (const float*)d_in[11];
  float* outp = (float*)d_out;

  char* ws = (char*)d_ws;
  size_t off_b = 0;
  auto alloc = [&](size_t bytes) { void* p = ws + off_b; off_b = (off_b + bytes + 255) & ~(size_t)255; return p; };
  int*   cnt    = (int*)  alloc((size_t)N_NODES * 4);
  float* dinvv  = (float*)alloc((size_t)N_NODES * 4);
  unsigned short* slots = (unsigned short*)alloc((size_t)N_NODES * SLOT_CAP * 2);  // 4 MB
  unsigned short* y1    = (unsigned short*)alloc((size_t)N_B * C1 * T1 * 2);
  unsigned short* feats = (unsigned short*)alloc((size_t)N_NODES * C2 * 2);
  unsigned short* aggXb = (unsigned short*)alloc((size_t)N_NODES * C2 * 2);
  unsigned short* H     = (unsigned short*)alloc((size_t)N_NODES * HID * 2);
  float* pooled = (float*)alloc((size_t)N_B * HID * 4);
  (void)ws_size; (void)in_sizes; (void)n_in; (void)out_size;

  // init, then scatter || conv1 (independent, fused launch)
  init_kernel         <<<256, 256, 0, stream>>>(cnt, pooled);
  conv1_scatter_kernel<<<4096, 256, 0, stream>>>(x, c1w, c1b, ei, cnt, slots, y1);
  dinv_kernel         <<<N_NODES / 256, 256, 0, stream>>>(cnt, dinvv);

  // conv2 (pre-scales by dinv)
  conv2_kernel<<<2048, 256, 0, stream>>>(y1, c2w, c2b, dinvv, feats);

  // GCN layer 1 aggregation (lean, latency-tolerant)
  aggX_kernel<<<N_NODES / 64, 256, 0, stream>>>(feats, cnt, slots, dinvv, aggXb);

  // both GEMMs, MFMA, fused
  gemm12_kernel<<<N_NODES / 64, 256, 0, stream>>>(aggXb, g1w, g1b, g2w, dinvv, H);

  // GCN layer 2 aggregation + bias + relu + mean-pool
  agg2_pool_kernel<<<N_NODES / 16, 256, 0, stream>>>(H, cnt, slots, dinvv, g2b, pooled);

  // classifier
  cls_kernel<<<N_B, 64, 0, stream>>>(pooled, clsw, clsb, outp);
}

// Round 13
// 110.825 us; speedup vs baseline: 2.5608x; 1.0793x over previous
//
#include <hip/hip_runtime.h>
#include <hip/hip_bf16.h>

typedef __hip_bfloat16 bf16;
typedef unsigned short ushort8_v __attribute__((ext_vector_type(8)));
typedef short bf16x8 __attribute__((ext_vector_type(8)));
typedef float f32x4 __attribute__((ext_vector_type(4)));

#define N_B     64
#define C_IN    9
#define T0      4096
#define C1      16
#define T1      2048
#define C2      32
#define T2      1024
#define N_NODES 65536
#define N_EDGES 524288
#define HID     128
#define OUT_C   10
#define SLOT_CAP 32

__device__ __forceinline__ float us2f(unsigned short u) {
  union { unsigned int i; float f; } c; c.i = ((unsigned int)u) << 16; return c.f;
}
__device__ __forceinline__ unsigned short f2us(float f) {
  bf16 h = __float2bfloat16(f);
  unsigned short u;
  __builtin_memcpy(&u, &h, 2);
  return u;
}

// ---------------- init: zero cnt/pooled + pre-transpose weights to bf16 [j][k] ----------------

__global__ __launch_bounds__(256) void init_kernel(int* __restrict__ cnt, float* __restrict__ pooled,
                                                   const float* __restrict__ W1, const float* __restrict__ W2,
                                                   unsigned short* __restrict__ W1T, unsigned short* __restrict__ W2T)
{
  int gid = blockIdx.x * 256 + threadIdx.x;
  if (gid < N_NODES) cnt[gid] = 0;
  if (gid < N_B * HID) pooled[gid] = 0.f;
  if (gid < HID * HID) {                       // W2T[j][k] = bf16(W2[k][j])
    int j = gid >> 7, k = gid & 127;
    W2T[j * HID + k] = f2us(W2[(size_t)k * HID + j]);
  }
  if (gid >= 32768 && gid < 32768 + HID * 32) { // W1T[j][k] = bf16(W1[k][j])
    int i = gid - 32768;
    int j = i >> 5, k = i & 31;
    W1T[j * 32 + k] = f2us(W1[(size_t)k * HID + j]);
  }
}

// ---------------- fused: scatter (blocks 0..2047) || conv1+relu+pool (blocks 2048..4095) ----------------
// slots: ushort, 32 per node = exactly one 64B line/node (4 MB total, L2-resident).
__global__ __launch_bounds__(256) void conv1_scatter_kernel(const float* __restrict__ x, const float* __restrict__ w1,
                                                            const float* __restrict__ b1,
                                                            const int* __restrict__ ei, int* __restrict__ cnt,
                                                            unsigned short* __restrict__ slots,
                                                            unsigned short* __restrict__ y1)
{
  __shared__ float sx[C_IN * 136];
  __shared__ float sw[45 * 17];
  __shared__ float sb[C1];
  int tid = threadIdx.x;
  if (blockIdx.x < 2048) {
    int e = blockIdx.x * 256 + tid;
    int d = ei[N_EDGES + e];
    int s = ei[e];
    int r = atomicAdd(&cnt[d], 1);
    if (r < SLOT_CAP) slots[((size_t)d << 5) + r] = (unsigned short)s;
    return;
  }
  int blk = blockIdx.x - 2048;
  int b = blk >> 5;
  int P0 = (blk & 31) << 6;             // pooled tile start
  int t0 = 2 * P0 - 2;                  // x pos of sx[c][0]
  for (int i = tid; i < C_IN * 132; i += 256) {
    int c = i / 132, j = i % 132;
    int t = t0 + j;
    sx[c * 136 + j] = (t >= 0 && t < T0) ? x[(size_t)(b * C_IN + c) * T0 + t] : 0.f;
  }
  for (int i = tid; i < C1 * 45; i += 256) sw[(i % 45) * 17 + i / 45] = w1[i];
  if (tid < C1) sb[tid] = b1[tid];
  __syncthreads();

  int o = tid & 15, pg = tid >> 4;
  float bias = sb[o];
  float a[8];
  #pragma unroll
  for (int i = 0; i < 8; ++i) a[i] = bias;
  #pragma unroll
  for (int c = 0; c < C_IN; ++c) {
    float xv[12];
    #pragma unroll
    for (int q = 0; q < 3; ++q)
      *(float4*)&xv[4 * q] = *(const float4*)&sx[c * 136 + 8 * pg + 4 * q];
    const float* wr = &sw[(c * 5) * 17 + o];
    float w0 = wr[0], w1_ = wr[17], w2_ = wr[34], w3_ = wr[51], w4_ = wr[68];
    #pragma unroll
    for (int m = 0; m < 8; ++m)
      a[m] += xv[m]*w0 + xv[m+1]*w1_ + xv[m+2]*w2_ + xv[m+3]*w3_ + xv[m+4]*w4_;
  }
  ushort4 r;
  r.x = f2us(fmaxf(fmaxf(a[0], a[1]), 0.f));
  r.y = f2us(fmaxf(fmaxf(a[2], a[3]), 0.f));
  r.z = f2us(fmaxf(fmaxf(a[4], a[5]), 0.f));
  r.w = f2us(fmaxf(fmaxf(a[6], a[7]), 0.f));
  *(ushort4*)&y1[(size_t)(b * C1 + o) * T1 + P0 + 4 * pg] = r;
}

// ---------------- conv2 + relu + pool -> PRE-SCALED bf16 feats F~ = F * rsqrt(cnt+1) ----------------
__global__ __launch_bounds__(256) void conv2_kernel(const unsigned short* __restrict__ y1, const float* __restrict__ w2,
                                                    const float* __restrict__ b2, const int* __restrict__ cnt,
                                                    unsigned short* __restrict__ feats)
{
  __shared__ float sy[C1 * 72];
  __shared__ float sw[80 * 33];
  __shared__ float sb[C2];
  int tid = threadIdx.x;
  int b = blockIdx.x >> 5;
  int Q0 = (blockIdx.x & 31) << 5;      // final tile start
  int t0 = 2 * Q0 - 2;                  // y1 pos of sy[c][0]
  for (int i = tid; i < C1 * 68; i += 256) {
    int c = i / 68, j = i % 68;
    int t = t0 + j;
    sy[c * 72 + j] = (t >= 0 && t < T1) ? us2f(y1[(size_t)(b * C1 + c) * T1 + t]) : 0.f;
  }
  for (int i = tid; i < C2 * 80; i += 256) sw[(i % 80) * 33 + i / 80] = w2[i];
  if (tid < C2) sb[tid] = b2[tid];
  __syncthreads();

  int o = tid & 31, pg = tid >> 5;
  float bias = sb[o];
  float a[8];
  #pragma unroll
  for (int i = 0; i < 8; ++i) a[i] = bias;
  #pragma unroll
  for (int c = 0; c < C1; ++c) {
    float yv[12];
    #pragma unroll
    for (int q = 0; q < 3; ++q)
      *(float4*)&yv[4 * q] = *(const float4*)&sy[c * 72 + 8 * pg + 4 * q];
    const float* wr = &sw[(c * 5) * 33 + o];
    float w0 = wr[0], w1_ = wr[33], w2_ = wr[66], w3_ = wr[99], w4_ = wr[132];
    #pragma unroll
    for (int m = 0; m < 8; ++m)
      a[m] += yv[m]*w0 + yv[m+1]*w1_ + yv[m+2]*w2_ + yv[m+3]*w3_ + yv[m+4]*w4_;
  }
  #pragma unroll
  for (int i = 0; i < 4; ++i) {
    int node = (b << 10) + Q0 + 4 * pg + i;
    float dv = rsqrtf((float)cnt[node] + 1.0f);
    feats[(size_t)node * C2 + o] = f2us(fmaxf(fmaxf(a[2*i], a[2*i+1]), 0.f) * dv);
  }
}

// ---------------- aggX: rsqrt(cnt+1)*(F~[n]+sum F~[s]) -> bf16 [N,32]; lean, high-occupancy ----------------
// block 256 = 64 nodes x 4 lanes (8 bf16 each); grid 1024
__global__ __launch_bounds__(256) void aggX_kernel(const unsigned short* __restrict__ F, const int* __restrict__ cnt,
                                                   const unsigned short* __restrict__ slots,
                                                   unsigned short* __restrict__ aggXb)
{
  int tid = threadIdx.x;
  int node = (blockIdx.x << 6) + (tid >> 2);
  int jq = (tid & 3) << 3;                  // bf16 element offset
  int cn = cnt[node];
  float dn = rsqrtf((float)cn + 1.0f);
  float acc[8];
  {
    ushort8_v r = *(const ushort8_v*)(F + (size_t)node * C2 + jq);
    #pragma unroll
    for (int k = 0; k < 8; ++k) acc[k] = us2f(r[k]);
  }
  const unsigned short* sl = slots + ((size_t)node << 5);
  int e1 = min(cn, SLOT_CAP);
  int e = 0;
  for (; e + 2 <= e1; e += 2) {
    int s0 = sl[e], s1 = sl[e + 1];
    ushort8_v r0 = *(const ushort8_v*)(F + (size_t)s0 * C2 + jq);
    ushort8_v r1 = *(const ushort8_v*)(F + (size_t)s1 * C2 + jq);
    #pragma unroll
    for (int k = 0; k < 8; ++k) acc[k] += us2f(r0[k]) + us2f(r1[k]);
  }
  if (e < e1) {
    int s0 = sl[e];
    ushort8_v r0 = *(const ushort8_v*)(F + (size_t)s0 * C2 + jq);
    #pragma unroll
    for (int k = 0; k < 8; ++k) acc[k] += us2f(r0[k]);
  }
  ushort8_v o;
  #pragma unroll
  for (int k = 0; k < 8; ++k) o[k] = f2us(acc[k] * dn);
  *(ushort8_v*)(aggXb + (size_t)node * C2 + jq) = o;
}

// ---------------- gemm12 (all-MFMA, no weight LDS): G=relu(aggX@W1+b1); H~=(G@W2)*rsqrt(cnt+1) ----------------
// grid 1024 = 64 nodes/block; block 256 = 4 waves.
// GEMM1: wave w -> nodes [w*16,w*16+16), all 128 cols; B-frags from global W1T bf16 [j][32].
// GEMM2: wave w -> cols [w*32,w*32+32), all 64 nodes; A from LDS sG [64][132]; B from global W2T bf16 [j][128].
// mfma_f32_16x16x32_bf16 (m89): A row=l&15,k=(l>>4)*8+i ; B col=l&15,same k ; C col=l&15,row=(l>>4)*4+r.
__global__ __launch_bounds__(256) void gemm12_kernel(const unsigned short* __restrict__ aggXb,
                                                     const unsigned short* __restrict__ W1T,
                                                     const float* __restrict__ gb1,
                                                     const unsigned short* __restrict__ W2T,
                                                     const int* __restrict__ cnt,
                                                     unsigned short* __restrict__ Hb)
{
  __shared__ unsigned short sG[64 * 132];   // 16.9 KB
  int tid = threadIdx.x;
  int w = tid >> 6, l = tid & 63;
  int lr = l & 15, lk = l >> 4;
  int n0b = blockIdx.x << 6;

  // GEMM1
  {
    int nb = w << 4;
    bf16x8 af = *(const bf16x8*)((const short*)aggXb + (size_t)(n0b + nb + lr) * C2 + lk * 8);
    #pragma unroll
    for (int jt = 0; jt < 8; ++jt) {
      bf16x8 bfr = *(const bf16x8*)((const short*)W1T + (jt * 16 + lr) * 32 + lk * 8);
      f32x4 acc = {0.f, 0.f, 0.f, 0.f};
      acc = __builtin_amdgcn_mfma_f32_16x16x32_bf16(af, bfr, acc, 0, 0, 0);
      float bj = gb1[jt * 16 + lr];
      #pragma unroll
      for (int r = 0; r < 4; ++r)
        sG[(nb + lk * 4 + r) * 132 + jt * 16 + lr] = f2us(fmaxf(acc[r] + bj, 0.f));
    }
  }
  __syncthreads();

  // GEMM2
  {
    int jb = w << 5;
    bf16x8 bfr[2][4];
    #pragma unroll
    for (int jtt = 0; jtt < 2; ++jtt)
      #pragma unroll
      for (int ks = 0; ks < 4; ++ks)
        bfr[jtt][ks] = *(const bf16x8*)((const short*)W2T + (size_t)(jb + jtt * 16 + lr) * HID + ks * 32 + lk * 8);
    #pragma unroll
    for (int nt = 0; nt < 4; ++nt) {
      bf16x8 afr[4];
      #pragma unroll
      for (int ks = 0; ks < 4; ++ks)
        afr[ks] = *(const bf16x8*)((const short*)sG + (nt * 16 + lr) * 132 + ks * 32 + lk * 8);
      int rowb = n0b + nt * 16 + lk * 4;
      int4 c4 = *(const int4*)&cnt[rowb];
      float dvr[4] = { rsqrtf((float)c4.x + 1.f), rsqrtf((float)c4.y + 1.f),
                       rsqrtf((float)c4.z + 1.f), rsqrtf((float)c4.w + 1.f) };
      #pragma unroll
      for (int jtt = 0; jtt < 2; ++jtt) {
        f32x4 acc = {0.f, 0.f, 0.f, 0.f};
        #pragma unroll
        for (int ks = 0; ks < 4; ++ks)
          acc = __builtin_amdgcn_mfma_f32_16x16x32_bf16(afr[ks], bfr[jtt][ks], acc, 0, 0, 0);
        #pragma unroll
        for (int r = 0; r < 4; ++r)
          Hb[(size_t)(rowb + r) * HID + jb + jtt * 16 + lr] = f2us(acc[r] * dvr[r]);
      }
    }
  }
}

// ---------------- agg2 + bias + relu + mean-pool: rsqrt(cnt+1)*(H~[n]+sum H~[s]) ----------------
// block 256 = 16 nodes x 16 lanes (8 bf16 each); grid 4096
__global__ __launch_bounds__(256) void agg2_pool_kernel(const unsigned short* __restrict__ Hb, const int* __restrict__ cnt,
                                                        const unsigned short* __restrict__ slots,
                                                        const float* __restrict__ bias, float* __restrict__ pooled)
{
  __shared__ float red[16][HID];           // 8 KB
  int tid = threadIdx.x;
  int g = tid >> 4;                        // local node 0..15
  int jq = (tid & 15) << 3;                // bf16 element offset 0..120
  int node = (blockIdx.x << 4) + g;
  int cn = cnt[node];
  float dn = rsqrtf((float)cn + 1.0f);
  float acc[8];
  {
    ushort8_v r = *(const ushort8_v*)(Hb + (size_t)node * HID + jq);
    #pragma unroll
    for (int k = 0; k < 8; ++k) acc[k] = us2f(r[k]);
  }
  const unsigned short* sl = slots + ((size_t)node << 5);
  int e1 = min(cn, SLOT_CAP);
  int e = 0;
  for (; e + 2 <= e1; e += 2) {
    int s0 = sl[e], s1 = sl[e + 1];
    ushort8_v r0 = *(const ushort8_v*)(Hb + (size_t)s0 * HID + jq);
    ushort8_v r1 = *(const ushort8_v*)(Hb + (size_t)s1 * HID + jq);
    #pragma unroll
    for (int k = 0; k < 8; ++k) acc[k] += us2f(r0[k]) + us2f(r1[k]);
  }
  if (e < e1) {
    int s0 = sl[e];
    ushort8_v r0 = *(const ushort8_v*)(Hb + (size_t)s0 * HID + jq);
    #pragma unroll
    for (int k = 0; k < 8; ++k) acc[k] += us2f(r0[k]);
  }
  #pragma unroll
  for (int k = 0; k < 8; ++k)
    red[g][jq + k] = fmaxf(dn * acc[k] + bias[jq + k], 0.f);
  __syncthreads();
  if (tid < HID) {
    float s = 0.f;
    #pragma unroll
    for (int g2 = 0; g2 < 16; ++g2) s += red[g2][tid];
    int b = blockIdx.x >> 6;               // 64 blocks per graph
    atomicAdd(&pooled[b * HID + tid], s * (1.0f / 1024.0f));
  }
}

// ---------------- classifier ----------------

__global__ __launch_bounds__(64) void cls_kernel(const float* __restrict__ pooled, const float* __restrict__ w,
                                                 const float* __restrict__ cb, float* __restrict__ out)
{
  int b = blockIdx.x, o = threadIdx.x;
  if (o < OUT_C) {
    float acc = cb[o];
    for (int i = 0; i < HID; ++i)
      acc += pooled[b * HID + i] * w[i * OUT_C + o];
    out[b * OUT_C + o] = acc;
  }
}

// ---------------- launcher ----------------

extern "C" void kernel_launch(void* const* d_in, const int* in_sizes, int n_in,
                              void* d_out, int out_size, void* d_ws, size_t ws_size,
                              hipStream_t stream)
{
  const float* x    = (const float*)d_in[0];
  const int*   ei   = (const int*)d_in[1];
  const float* c1w  = (const float*)d_in[2];
  const float* c1b  = (const float*)d_in[3];
  const float* c2w  = (const float*)d_in[4];
  const float* c2b  = (const float*)d_in[5];
  const float* g1w  = (const float*)d_in[6];
  const float* g1b  = (const float*)d_in[7];
  const float* g2w  = (const float*)d_in[8];
  const float* g2b  = (const float*)d_in[9];
  const float* clsw = (const float*)d_in[10];
  const float* clsb = (const float*)d_in[11];
  float* outp = (float*)d_out;

  char* ws = (char*)d_ws;
  size_t off_b = 0;
  auto alloc = [&](size_t bytes) { void* p = ws + off_b; off_b = (off_b + bytes + 255) & ~(size_t)255; return p; };
  int*   cnt    = (int*)  alloc((size_t)N_NODES * 4);
  unsigned short* slots = (unsigned short*)alloc((size_t)N_NODES * SLOT_CAP * 2);  // 4 MB
  unsigned short* w1t   = (unsigned short*)alloc((size_t)HID * 32 * 2);
  unsigned short* w2t   = (unsigned short*)alloc((size_t)HID * HID * 2);
  unsigned short* y1    = (unsigned short*)alloc((size_t)N_B * C1 * T1 * 2);
  unsigned short* feats = (unsigned short*)alloc((size_t)N_NODES * C2 * 2);
  unsigned short* aggXb = (unsigned short*)alloc((size_t)N_NODES * C2 * 2);
  unsigned short* H     = (unsigned short*)alloc((size_t)N_NODES * HID * 2);
  float* pooled = (float*)alloc((size_t)N_B * HID * 4);
  (void)ws_size; (void)in_sizes; (void)n_in; (void)out_size;

  // init (+ weight transpose/convert), then scatter || conv1 (independent, fused launch)
  init_kernel         <<<256, 256, 0, stream>>>(cnt, pooled, g1w, g2w, w1t, w2t);
  conv1_scatter_kernel<<<4096, 256, 0, stream>>>(x, c1w, c1b, ei, cnt, slots, y1);

  // conv2 (pre-scales by rsqrt(cnt+1))
  conv2_kernel<<<2048, 256, 0, stream>>>(y1, c2w, c2b, cnt, feats);

  // GCN layer 1 aggregation (lean, latency-tolerant)
  aggX_kernel<<<N_NODES / 64, 256, 0, stream>>>(feats, cnt, slots, aggXb);

  // both GEMMs, MFMA, fused, no weight LDS
  gemm12_kernel<<<N_NODES / 64, 256, 0, stream>>>(aggXb, w1t, g1b, w2t, cnt, H);

  // GCN layer 2 aggregation + bias + relu + mean-pool
  agg2_pool_kernel<<<N_NODES / 16, 256, 0, stream>>>(H, cnt, slots, g2b, pooled);

  // classifier
  cls_kernel<<<N_B, 64, 0, stream>>>(pooled, clsw, clsb, outp);
}

// Round 14
// 107.263 us; speedup vs baseline: 2.6459x; 1.0332x over previous
//
#include <hip/hip_runtime.h>
#include <hip/hip_bf16.h>

typedef __hip_bfloat16 bf16;
typedef unsigned short ushort8_v __attribute__((ext_vector_type(8)));
typedef short bf16x8 __attribute__((ext_vector_type(8)));
typedef float f32x4 __attribute__((ext_vector_type(4)));

#define N_B     64
#define C_IN    9
#define T0      4096
#define C1      16
#define T1      2048
#define C2      32
#define T2      1024
#define N_NODES 65536
#define N_EDGES 524288
#define HID     128
#define OUT_C   10
#define SLOT_CAP 32

__device__ __forceinline__ float us2f(unsigned short u) {
  union { unsigned int i; float f; } c; c.i = ((unsigned int)u) << 16; return c.f;
}
__device__ __forceinline__ unsigned short f2us(float f) {
  bf16 h = __float2bfloat16(f);
  unsigned short u;
  __builtin_memcpy(&u, &h, 2);
  return u;
}

// ---------------- fused: scatter (0..2047) || conv1 (2048..4095) || weight transpose (4096..4112) ----------------
// slots: ushort, 32 per node = exactly one 64B line/node (4 MB total, L2-resident).
__global__ __launch_bounds__(256) void conv1_scatter_kernel(const float* __restrict__ x, const float* __restrict__ w1,
                                                            const float* __restrict__ b1,
                                                            const int* __restrict__ ei, int* __restrict__ cnt,
                                                            unsigned short* __restrict__ slots,
                                                            unsigned short* __restrict__ y1,
                                                            const float* __restrict__ W1, const float* __restrict__ W2,
                                                            unsigned short* __restrict__ W1T,
                                                            unsigned short* __restrict__ W2T)
{
  __shared__ float sx[C_IN * 136];
  __shared__ float sw[45 * 17];
  __shared__ float sb[C1];
  int tid = threadIdx.x;
  if (blockIdx.x < 2048) {
    int e = blockIdx.x * 256 + tid;
    int d = ei[N_EDGES + e];
    int s = ei[e];
    int r = atomicAdd(&cnt[d], 1);
    if (r < SLOT_CAP) slots[((size_t)d << 5) + r] = (unsigned short)s;
    return;
  }
  if (blockIdx.x >= 4096) {
    int blk = blockIdx.x - 4096;
    if (blk < 16) {                     // W2T[j][k] = bf16(W2[k][j]), 1024 elems/block
      int base = blk * 1024 + tid * 4;
      #pragma unroll
      for (int i = 0; i < 4; ++i) {
        int idx = base + i;
        int j = idx >> 7, k = idx & 127;
        W2T[j * HID + k] = f2us(W2[(size_t)k * HID + j]);
      }
    } else {                            // W1T[j][k] = bf16(W1[k][j]), 4096 elems
      #pragma unroll
      for (int i = 0; i < 16; ++i) {
        int idx = tid * 16 + i;
        int j = idx >> 5, k = idx & 31;
        W1T[j * 32 + k] = f2us(W1[(size_t)k * HID + j]);
      }
    }
    return;
  }
  int blk = blockIdx.x - 2048;
  int b = blk >> 5;
  int P0 = (blk & 31) << 6;             // pooled tile start
  int t0 = 2 * P0 - 2;                  // x pos of sx[c][0]
  for (int i = tid; i < C_IN * 132; i += 256) {
    int c = i / 132, j = i % 132;
    int t = t0 + j;
    sx[c * 136 + j] = (t >= 0 && t < T0) ? x[(size_t)(b * C_IN + c) * T0 + t] : 0.f;
  }
  for (int i = tid; i < C1 * 45; i += 256) sw[(i % 45) * 17 + i / 45] = w1[i];
  if (tid < C1) sb[tid] = b1[tid];
  __syncthreads();

  int o = tid & 15, pg = tid >> 4;
  float bias = sb[o];
  float a[8];
  #pragma unroll
  for (int i = 0; i < 8; ++i) a[i] = bias;
  #pragma unroll
  for (int c = 0; c < C_IN; ++c) {
    float xv[12];
    #pragma unroll
    for (int q = 0; q < 3; ++q)
      *(float4*)&xv[4 * q] = *(const float4*)&sx[c * 136 + 8 * pg + 4 * q];
    const float* wr = &sw[(c * 5) * 17 + o];
    float w0 = wr[0], w1_ = wr[17], w2_ = wr[34], w3_ = wr[51], w4_ = wr[68];
    #pragma unroll
    for (int m = 0; m < 8; ++m)
      a[m] += xv[m]*w0 + xv[m+1]*w1_ + xv[m+2]*w2_ + xv[m+3]*w3_ + xv[m+4]*w4_;
  }
  ushort4 r;
  r.x = f2us(fmaxf(fmaxf(a[0], a[1]), 0.f));
  r.y = f2us(fmaxf(fmaxf(a[2], a[3]), 0.f));
  r.z = f2us(fmaxf(fmaxf(a[4], a[5]), 0.f));
  r.w = f2us(fmaxf(fmaxf(a[6], a[7]), 0.f));
  *(ushort4*)&y1[(size_t)(b * C1 + o) * T1 + P0 + 4 * pg] = r;
}

// ---------------- conv2 + relu + pool -> PRE-SCALED bf16 feats F~ = F * rsqrt(cnt+1) ----------------
__global__ __launch_bounds__(256) void conv2_kernel(const unsigned short* __restrict__ y1, const float* __restrict__ w2,
                                                    const float* __restrict__ b2, const int* __restrict__ cnt,
                                                    unsigned short* __restrict__ feats)
{
  __shared__ float sy[C1 * 72];
  __shared__ float sw[80 * 33];
  __shared__ float sb[C2];
  int tid = threadIdx.x;
  int b = blockIdx.x >> 5;
  int Q0 = (blockIdx.x & 31) << 5;      // final tile start
  int t0 = 2 * Q0 - 2;                  // y1 pos of sy[c][0]
  for (int i = tid; i < C1 * 68; i += 256) {
    int c = i / 68, j = i % 68;
    int t = t0 + j;
    sy[c * 72 + j] = (t >= 0 && t < T1) ? us2f(y1[(size_t)(b * C1 + c) * T1 + t]) : 0.f;
  }
  for (int i = tid; i < C2 * 80; i += 256) sw[(i % 80) * 33 + i / 80] = w2[i];
  if (tid < C2) sb[tid] = b2[tid];
  __syncthreads();

  int o = tid & 31, pg = tid >> 5;
  float bias = sb[o];
  float a[8];
  #pragma unroll
  for (int i = 0; i < 8; ++i) a[i] = bias;
  #pragma unroll
  for (int c = 0; c < C1; ++c) {
    float yv[12];
    #pragma unroll
    for (int q = 0; q < 3; ++q)
      *(float4*)&yv[4 * q] = *(const float4*)&sy[c * 72 + 8 * pg + 4 * q];
    const float* wr = &sw[(c * 5) * 33 + o];
    float w0 = wr[0], w1_ = wr[33], w2_ = wr[66], w3_ = wr[99], w4_ = wr[132];
    #pragma unroll
    for (int m = 0; m < 8; ++m)
      a[m] += yv[m]*w0 + yv[m+1]*w1_ + yv[m+2]*w2_ + yv[m+3]*w3_ + yv[m+4]*w4_;
  }
  #pragma unroll
  for (int i = 0; i < 4; ++i) {
    int node = (b << 10) + Q0 + 4 * pg + i;
    float dv = rsqrtf((float)cnt[node] + 1.0f);
    feats[(size_t)node * C2 + o] = f2us(fmaxf(fmaxf(a[2*i], a[2*i+1]), 0.f) * dv);
  }
}

// ---------------- gemm12 (gather + all-MFMA): aggX in-register; G=relu(..@W1+b1); H~=(G@W2)*rsqrt ----------------
// grid 1024 = 64 nodes/block; block 256 = 4 waves.
// Phase A (per lane): gather-accumulate aggX[node=lr][lk*8..+8] fp32, pack bf16 -> GEMM1 A-frag.
// GEMM1: wave w -> nodes [w*16..+16), B-frags from global W1T bf16 [j][32]; G -> LDS sG[64][132].
// GEMM2: wave w -> cols [w*32..+32), A from sG, B from global W2T bf16 [j][128].
// mfma_f32_16x16x32_bf16 (m89): A row=l&15,k=(l>>4)*8+i ; B col=l&15,same k ; C col=l&15,row=(l>>4)*4+r.
__global__ __launch_bounds__(256) void gemm12_kernel(const unsigned short* __restrict__ F,
                                                     const int* __restrict__ cnt,
                                                     const unsigned short* __restrict__ slots,
                                                     const unsigned short* __restrict__ W1T,
                                                     const float* __restrict__ gb1,
                                                     const unsigned short* __restrict__ W2T,
                                                     unsigned short* __restrict__ Hb)
{
  __shared__ unsigned short sG[64 * 132];   // 16.9 KB
  int tid = threadIdx.x;
  int w = tid >> 6, l = tid & 63;
  int lr = l & 15, lk = l >> 4;
  int n0b = blockIdx.x << 6;

  // phase A + GEMM1
  {
    int nb = w << 4;
    int node = n0b + nb + lr;
    int cn = cnt[node];
    float dn = rsqrtf((float)cn + 1.0f);
    int koff = lk << 3;
    float accf[8];
    {
      ushort8_v r = *(const ushort8_v*)(F + (size_t)node * C2 + koff);
      #pragma unroll
      for (int k = 0; k < 8; ++k) accf[k] = us2f(r[k]);
    }
    const unsigned short* sl = slots + ((size_t)node << 5);
    int e1 = min(cn, SLOT_CAP);
    int e = 0;
    for (; e + 4 <= e1; e += 4) {
      int s0 = sl[e], s1 = sl[e + 1], s2 = sl[e + 2], s3 = sl[e + 3];
      ushort8_v r0 = *(const ushort8_v*)(F + (size_t)s0 * C2 + koff);
      ushort8_v r1 = *(const ushort8_v*)(F + (size_t)s1 * C2 + koff);
      ushort8_v r2 = *(const ushort8_v*)(F + (size_t)s2 * C2 + koff);
      ushort8_v r3 = *(const ushort8_v*)(F + (size_t)s3 * C2 + koff);
      #pragma unroll
      for (int k = 0; k < 8; ++k)
        accf[k] += (us2f(r0[k]) + us2f(r1[k])) + (us2f(r2[k]) + us2f(r3[k]));
    }
    for (; e < e1; ++e) {
      int s0 = sl[e];
      ushort8_v r0 = *(const ushort8_v*)(F + (size_t)s0 * C2 + koff);
      #pragma unroll
      for (int k = 0; k < 8; ++k) accf[k] += us2f(r0[k]);
    }
    bf16x8 af;
    #pragma unroll
    for (int k = 0; k < 8; ++k) af[k] = (short)f2us(accf[k] * dn);

    #pragma unroll
    for (int jt = 0; jt < 8; ++jt) {
      bf16x8 bfr = *(const bf16x8*)((const short*)W1T + (jt * 16 + lr) * 32 + lk * 8);
      f32x4 acc = {0.f, 0.f, 0.f, 0.f};
      acc = __builtin_amdgcn_mfma_f32_16x16x32_bf16(af, bfr, acc, 0, 0, 0);
      float bj = gb1[jt * 16 + lr];
      #pragma unroll
      for (int r = 0; r < 4; ++r)
        sG[(nb + lk * 4 + r) * 132 + jt * 16 + lr] = f2us(fmaxf(acc[r] + bj, 0.f));
    }
  }
  __syncthreads();

  // GEMM2
  {
    int jb = w << 5;
    bf16x8 bfr[2][4];
    #pragma unroll
    for (int jtt = 0; jtt < 2; ++jtt)
      #pragma unroll
      for (int ks = 0; ks < 4; ++ks)
        bfr[jtt][ks] = *(const bf16x8*)((const short*)W2T + (size_t)(jb + jtt * 16 + lr) * HID + ks * 32 + lk * 8);
    #pragma unroll
    for (int nt = 0; nt < 4; ++nt) {
      bf16x8 afr[4];
      #pragma unroll
      for (int ks = 0; ks < 4; ++ks)
        afr[ks] = *(const bf16x8*)((const short*)sG + (nt * 16 + lr) * 132 + ks * 32 + lk * 8);
      int rowb = n0b + nt * 16 + lk * 4;
      int4 c4 = *(const int4*)&cnt[rowb];
      float dvr[4] = { rsqrtf((float)c4.x + 1.f), rsqrtf((float)c4.y + 1.f),
                       rsqrtf((float)c4.z + 1.f), rsqrtf((float)c4.w + 1.f) };
      #pragma unroll
      for (int jtt = 0; jtt < 2; ++jtt) {
        f32x4 acc = {0.f, 0.f, 0.f, 0.f};
        #pragma unroll
        for (int ks = 0; ks < 4; ++ks)
          acc = __builtin_amdgcn_mfma_f32_16x16x32_bf16(afr[ks], bfr[jtt][ks], acc, 0, 0, 0);
        #pragma unroll
        for (int r = 0; r < 4; ++r)
          Hb[(size_t)(rowb + r) * HID + jb + jtt * 16 + lr] = f2us(acc[r] * dvr[r]);
      }
    }
  }
}

// ---------------- agg2 + bias + relu + mean-pool: rsqrt(cnt+1)*(H~[n]+sum H~[s]) ----------------
// block 256 = 16 nodes x 16 lanes (8 bf16 each); grid 4096; 4-deep gather MLP
__global__ __launch_bounds__(256) void agg2_pool_kernel(const unsigned short* __restrict__ Hb, const int* __restrict__ cnt,
                                                        const unsigned short* __restrict__ slots,
                                                        const float* __restrict__ bias, float* __restrict__ pooled)
{
  __shared__ float red[16][HID];           // 8 KB
  int tid = threadIdx.x;
  int g = tid >> 4;                        // local node 0..15
  int jq = (tid & 15) << 3;                // bf16 element offset 0..120
  int node = (blockIdx.x << 4) + g;
  int cn = cnt[node];
  float dn = rsqrtf((float)cn + 1.0f);
  float acc[8];
  {
    ushort8_v r = *(const ushort8_v*)(Hb + (size_t)node * HID + jq);
    #pragma unroll
    for (int k = 0; k < 8; ++k) acc[k] = us2f(r[k]);
  }
  const unsigned short* sl = slots + ((size_t)node << 5);
  int e1 = min(cn, SLOT_CAP);
  int e = 0;
  for (; e + 4 <= e1; e += 4) {
    int s0 = sl[e], s1 = sl[e + 1], s2 = sl[e + 2], s3 = sl[e + 3];
    ushort8_v r0 = *(const ushort8_v*)(Hb + (size_t)s0 * HID + jq);
    ushort8_v r1 = *(const ushort8_v*)(Hb + (size_t)s1 * HID + jq);
    ushort8_v r2 = *(const ushort8_v*)(Hb + (size_t)s2 * HID + jq);
    ushort8_v r3 = *(const ushort8_v*)(Hb + (size_t)s3 * HID + jq);
    #pragma unroll
    for (int k = 0; k < 8; ++k)
      acc[k] += (us2f(r0[k]) + us2f(r1[k])) + (us2f(r2[k]) + us2f(r3[k]));
  }
  for (; e < e1; ++e) {
    int s0 = sl[e];
    ushort8_v r0 = *(const ushort8_v*)(Hb + (size_t)s0 * HID + jq);
    #pragma unroll
    for (int k = 0; k < 8; ++k) acc[k] += us2f(r0[k]);
  }
  #pragma unroll
  for (int k = 0; k < 8; ++k)
    red[g][jq + k] = fmaxf(dn * acc[k] + bias[jq + k], 0.f);
  __syncthreads();
  if (tid < HID) {
    float s = 0.f;
    #pragma unroll
    for (int g2 = 0; g2 < 16; ++g2) s += red[g2][tid];
    int b = blockIdx.x >> 6;               // 64 blocks per graph
    atomicAdd(&pooled[b * HID + tid], s * (1.0f / 1024.0f));
  }
}

// ---------------- classifier ----------------

__global__ __launch_bounds__(64) void cls_kernel(const float* __restrict__ pooled, const float* __restrict__ w,
                                                 const float* __restrict__ cb, float* __restrict__ out)
{
  int b = blockIdx.x, o = threadIdx.x;
  if (o < OUT_C) {
    float acc = cb[o];
    for (int i = 0; i < HID; ++i)
      acc += pooled[b * HID + i] * w[i * OUT_C + o];
    out[b * OUT_C + o] = acc;
  }
}

// ---------------- launcher ----------------

extern "C" void kernel_launch(void* const* d_in, const int* in_sizes, int n_in,
                              void* d_out, int out_size, void* d_ws, size_t ws_size,
                              hipStream_t stream)
{
  const float* x    = (const float*)d_in[0];
  const int*   ei   = (const int*)d_in[1];
  const float* c1w  = (const float*)d_in[2];
  const float* c1b  = (const float*)d_in[3];
  const float* c2w  = (const float*)d_in[4];
  const float* c2b  = (const float*)d_in[5];
  const float* g1w  = (const float*)d_in[6];
  const float* g1b  = (const float*)d_in[7];
  const float* g2w  = (const float*)d_in[8];
  const float* g2b  = (const float*)d_in[9];
  const float* clsw = (const float*)d_in[10];
  const float* clsb = (const float*)d_in[11];
  float* outp = (float*)d_out;

  char* ws = (char*)d_ws;
  size_t off_b = 0;
  auto alloc = [&](size_t bytes) { void* p = ws + off_b; off_b = (off_b + bytes + 255) & ~(size_t)255; return p; };
  int*   cnt    = (int*)  alloc((size_t)N_NODES * 4);
  unsigned short* slots = (unsigned short*)alloc((size_t)N_NODES * SLOT_CAP * 2);  // 4 MB
  unsigned short* w1t   = (unsigned short*)alloc((size_t)HID * 32 * 2);
  unsigned short* w2t   = (unsigned short*)alloc((size_t)HID * HID * 2);
  unsigned short* y1    = (unsigned short*)alloc((size_t)N_B * C1 * T1 * 2);
  unsigned short* feats = (unsigned short*)alloc((size_t)N_NODES * C2 * 2);
  unsigned short* H     = (unsigned short*)alloc((size_t)N_NODES * HID * 2);
  float* pooled = (float*)alloc((size_t)N_B * HID * 4);
  (void)ws_size; (void)in_sizes; (void)n_in; (void)out_size;

  // zero cnt + pooled (graph-capturable async memsets)
  hipMemsetAsync(cnt, 0, (size_t)N_NODES * 4, stream);
  hipMemsetAsync(pooled, 0, (size_t)N_B * HID * 4, stream);

  // scatter || conv1 || weight transpose (one launch)
  conv1_scatter_kernel<<<4113, 256, 0, stream>>>(x, c1w, c1b, ei, cnt, slots, y1, g1w, g2w, w1t, w2t);

  // conv2 (pre-scales by rsqrt(cnt+1))
  conv2_kernel<<<2048, 256, 0, stream>>>(y1, c2w, c2b, cnt, feats);

  // aggX (in-register) + both GEMMs (MFMA), one kernel
  gemm12_kernel<<<N_NODES / 64, 256, 0, stream>>>(feats, cnt, slots, w1t, g1b, w2t, H);

  // GCN layer 2 aggregation + bias + relu + mean-pool
  agg2_pool_kernel<<<N_NODES / 16, 256, 0, stream>>>(H, cnt, slots, g2b, pooled);

  // classifier
  cls_kernel<<<N_B, 64, 0, stream>>>(pooled, clsw, clsb, outp);
}

// Round 15
// 106.765 us; speedup vs baseline: 2.6582x; 1.0047x over previous
//
#include <hip/hip_runtime.h>
#include <hip/hip_bf16.h>

typedef __hip_bfloat16 bf16;
typedef unsigned short ushort8_v __attribute__((ext_vector_type(8)));
typedef short bf16x8 __attribute__((ext_vector_type(8)));
typedef float f32x4 __attribute__((ext_vector_type(4)));

#define N_B     64
#define C_IN    9
#define T0      4096
#define C1      16
#define T1      2048
#define C2      32
#define T2      1024
#define N_NODES 65536
#define N_EDGES 524288
#define HID     128
#define OUT_C   10
#define SLOT_CAP 32

__device__ __forceinline__ float us2f(unsigned short u) {
  union { unsigned int i; float f; } c; c.i = ((unsigned int)u) << 16; return c.f;
}
__device__ __forceinline__ unsigned short f2us(float f) {
  bf16 h = __float2bfloat16(f);
  unsigned short u;
  __builtin_memcpy(&u, &h, 2);
  return u;
}

// ---------------- fused: scatter (0..2047) || conv1 (2048..4095) || weight transpose + pooled-zero (4096..4112) ----------------
// slots: ushort, 32 per node = exactly one 64B line/node (4 MB total, L2-resident).
__global__ __launch_bounds__(256) void conv1_scatter_kernel(const float* __restrict__ x, const float* __restrict__ w1,
                                                            const float* __restrict__ b1,
                                                            const int* __restrict__ ei, int* __restrict__ cnt,
                                                            unsigned short* __restrict__ slots,
                                                            unsigned short* __restrict__ y1,
                                                            const float* __restrict__ W1, const float* __restrict__ W2,
                                                            unsigned short* __restrict__ W1T,
                                                            unsigned short* __restrict__ W2T,
                                                            float* __restrict__ pooled)
{
  __shared__ float sx[C_IN * 136];
  __shared__ float sw[45 * 17];
  __shared__ float sb[C1];
  int tid = threadIdx.x;
  if (blockIdx.x < 2048) {
    int e = blockIdx.x * 256 + tid;
    int d = ei[N_EDGES + e];
    int s = ei[e];
    int r = atomicAdd(&cnt[d], 1);
    if (r < SLOT_CAP) slots[((size_t)d << 5) + r] = (unsigned short)s;
    return;
  }
  if (blockIdx.x >= 4096) {
    int blk = blockIdx.x - 4096;
    if (blk < 16) {                     // W2T[j][k] = bf16(W2[k][j]), 1024 elems/block
      int base = blk * 1024 + tid * 4;
      #pragma unroll
      for (int i = 0; i < 4; ++i) {
        int idx = base + i;
        int j = idx >> 7, k = idx & 127;
        W2T[j * HID + k] = f2us(W2[(size_t)k * HID + j]);
      }
    } else {                            // W1T[j][k] = bf16(W1[k][j]), 4096 elems; + zero pooled
      #pragma unroll
      for (int i = 0; i < 16; ++i) {
        int idx = tid * 16 + i;
        int j = idx >> 5, k = idx & 31;
        W1T[j * 32 + k] = f2us(W1[(size_t)k * HID + j]);
      }
      float4 z4 = make_float4(0.f, 0.f, 0.f, 0.f);
      for (int i = tid; i < N_B * HID / 4; i += 256)
        ((float4*)pooled)[i] = z4;
    }
    return;
  }
  int blk = blockIdx.x - 2048;
  int b = blk >> 5;
  int P0 = (blk & 31) << 6;             // pooled tile start
  int t0 = 2 * P0 - 2;                  // x pos of sx[c][0]
  for (int i = tid; i < C_IN * 132; i += 256) {
    int c = i / 132, j = i % 132;
    int t = t0 + j;
    sx[c * 136 + j] = (t >= 0 && t < T0) ? x[(size_t)(b * C_IN + c) * T0 + t] : 0.f;
  }
  for (int i = tid; i < C1 * 45; i += 256) sw[(i % 45) * 17 + i / 45] = w1[i];
  if (tid < C1) sb[tid] = b1[tid];
  __syncthreads();

  int o = tid & 15, pg = tid >> 4;
  float bias = sb[o];
  float a[8];
  #pragma unroll
  for (int i = 0; i < 8; ++i) a[i] = bias;
  #pragma unroll
  for (int c = 0; c < C_IN; ++c) {
    float xv[12];
    #pragma unroll
    for (int q = 0; q < 3; ++q)
      *(float4*)&xv[4 * q] = *(const float4*)&sx[c * 136 + 8 * pg + 4 * q];
    const float* wr = &sw[(c * 5) * 17 + o];
    float w0 = wr[0], w1_ = wr[17], w2_ = wr[34], w3_ = wr[51], w4_ = wr[68];
    #pragma unroll
    for (int m = 0; m < 8; ++m)
      a[m] += xv[m]*w0 + xv[m+1]*w1_ + xv[m+2]*w2_ + xv[m+3]*w3_ + xv[m+4]*w4_;
  }
  ushort4 r;
  r.x = f2us(fmaxf(fmaxf(a[0], a[1]), 0.f));
  r.y = f2us(fmaxf(fmaxf(a[2], a[3]), 0.f));
  r.z = f2us(fmaxf(fmaxf(a[4], a[5]), 0.f));
  r.w = f2us(fmaxf(fmaxf(a[6], a[7]), 0.f));
  *(ushort4*)&y1[(size_t)(b * C1 + o) * T1 + P0 + 4 * pg] = r;
}

// ---------------- conv2 + relu + pool -> PRE-SCALED bf16 feats F~ = F * rsqrt(cnt+1) ----------------
__global__ __launch_bounds__(256) void conv2_kernel(const unsigned short* __restrict__ y1, const float* __restrict__ w2,
                                                    const float* __restrict__ b2, const int* __restrict__ cnt,
                                                    unsigned short* __restrict__ feats)
{
  __shared__ float sy[C1 * 72];
  __shared__ float sw[80 * 33];
  __shared__ float sb[C2];
  int tid = threadIdx.x;
  int b = blockIdx.x >> 5;
  int Q0 = (blockIdx.x & 31) << 5;      // final tile start
  int t0 = 2 * Q0 - 2;                  // y1 pos of sy[c][0]
  for (int i = tid; i < C1 * 68; i += 256) {
    int c = i / 68, j = i % 68;
    int t = t0 + j;
    sy[c * 72 + j] = (t >= 0 && t < T1) ? us2f(y1[(size_t)(b * C1 + c) * T1 + t]) : 0.f;
  }
  for (int i = tid; i < C2 * 80; i += 256) sw[(i % 80) * 33 + i / 80] = w2[i];
  if (tid < C2) sb[tid] = b2[tid];
  __syncthreads();

  int o = tid & 31, pg = tid >> 5;
  float bias = sb[o];
  float a[8];
  #pragma unroll
  for (int i = 0; i < 8; ++i) a[i] = bias;
  #pragma unroll
  for (int c = 0; c < C1; ++c) {
    float yv[12];
    #pragma unroll
    for (int q = 0; q < 3; ++q)
      *(float4*)&yv[4 * q] = *(const float4*)&sy[c * 72 + 8 * pg + 4 * q];
    const float* wr = &sw[(c * 5) * 33 + o];
    float w0 = wr[0], w1_ = wr[33], w2_ = wr[66], w3_ = wr[99], w4_ = wr[132];
    #pragma unroll
    for (int m = 0; m < 8; ++m)
      a[m] += yv[m]*w0 + yv[m+1]*w1_ + yv[m+2]*w2_ + yv[m+3]*w3_ + yv[m+4]*w4_;
  }
  #pragma unroll
  for (int i = 0; i < 4; ++i) {
    int node = (b << 10) + Q0 + 4 * pg + i;
    float dv = rsqrtf((float)cnt[node] + 1.0f);
    feats[(size_t)node * C2 + o] = f2us(fmaxf(fmaxf(a[2*i], a[2*i+1]), 0.f) * dv);
  }
}

// ---------------- gemm12 (gather + all-MFMA): aggX in-register; G=relu(..@W1+b1); H~=(G@W2)*rsqrt ----------------
// grid 1024 = 64 nodes/block; block 256 = 4 waves.
// Phase A (per lane): gather-accumulate aggX[node=lr][lk*8..+8] fp32, pack bf16 -> GEMM1 A-frag.
// GEMM1: wave w -> nodes [w*16..+16), B-frags from global W1T bf16 [j][32]; G -> LDS sG[64][132].
// GEMM2: wave w -> cols [w*32..+32), A from sG, B from global W2T bf16 [j][128] (hoisted above barrier).
// mfma_f32_16x16x32_bf16 (m89): A row=l&15,k=(l>>4)*8+i ; B col=l&15,same k ; C col=l&15,row=(l>>4)*4+r.
__global__ __launch_bounds__(256) void gemm12_kernel(const unsigned short* __restrict__ F,
                                                     const int* __restrict__ cnt,
                                                     const unsigned short* __restrict__ slots,
                                                     const unsigned short* __restrict__ W1T,
                                                     const float* __restrict__ gb1,
                                                     const unsigned short* __restrict__ W2T,
                                                     unsigned short* __restrict__ Hb)
{
  __shared__ unsigned short sG[64 * 132];   // 16.9 KB
  int tid = threadIdx.x;
  int w = tid >> 6, l = tid & 63;
  int lr = l & 15, lk = l >> 4;
  int n0b = blockIdx.x << 6;
  int jb = w << 5;

  // phase A + GEMM1
  {
    int nb = w << 4;
    int node = n0b + nb + lr;
    int cn = cnt[node];
    float dn = rsqrtf((float)cn + 1.0f);
    int koff = lk << 3;
    float accf[8];
    {
      ushort8_v r = *(const ushort8_v*)(F + (size_t)node * C2 + koff);
      #pragma unroll
      for (int k = 0; k < 8; ++k) accf[k] = us2f(r[k]);
    }
    const unsigned short* sl = slots + ((size_t)node << 5);
    int e1 = min(cn, SLOT_CAP);
    int e = 0;
    for (; e + 4 <= e1; e += 4) {
      int s0 = sl[e], s1 = sl[e + 1], s2 = sl[e + 2], s3 = sl[e + 3];
      ushort8_v r0 = *(const ushort8_v*)(F + (size_t)s0 * C2 + koff);
      ushort8_v r1 = *(const ushort8_v*)(F + (size_t)s1 * C2 + koff);
      ushort8_v r2 = *(const ushort8_v*)(F + (size_t)s2 * C2 + koff);
      ushort8_v r3 = *(const ushort8_v*)(F + (size_t)s3 * C2 + koff);
      #pragma unroll
      for (int k = 0; k < 8; ++k)
        accf[k] += (us2f(r0[k]) + us2f(r1[k])) + (us2f(r2[k]) + us2f(r3[k]));
    }
    for (; e < e1; ++e) {
      int s0 = sl[e];
      ushort8_v r0 = *(const ushort8_v*)(F + (size_t)s0 * C2 + koff);
      #pragma unroll
      for (int k = 0; k < 8; ++k) accf[k] += us2f(r0[k]);
    }
    bf16x8 af;
    #pragma unroll
    for (int k = 0; k < 8; ++k) af[k] = (short)f2us(accf[k] * dn);

    #pragma unroll
    for (int jt = 0; jt < 8; ++jt) {
      bf16x8 bfr = *(const bf16x8*)((const short*)W1T + (jt * 16 + lr) * 32 + lk * 8);
      f32x4 acc = {0.f, 0.f, 0.f, 0.f};
      acc = __builtin_amdgcn_mfma_f32_16x16x32_bf16(af, bfr, acc, 0, 0, 0);
      float bj = gb1[jt * 16 + lr];
      #pragma unroll
      for (int r = 0; r < 4; ++r)
        sG[(nb + lk * 4 + r) * 132 + jt * 16 + lr] = f2us(fmaxf(acc[r] + bj, 0.f));
    }
  }

  // hoist GEMM2 B-frags (global, no sG dependence) above the barrier so their
  // latency hides under the barrier drain instead of serializing after it
  bf16x8 bfr[2][4];
  #pragma unroll
  for (int jtt = 0; jtt < 2; ++jtt)
    #pragma unroll
    for (int ks = 0; ks < 4; ++ks)
      bfr[jtt][ks] = *(const bf16x8*)((const short*)W2T + (size_t)(jb + jtt * 16 + lr) * HID + ks * 32 + lk * 8);

  __syncthreads();

  // GEMM2
  {
    #pragma unroll
    for (int nt = 0; nt < 4; ++nt) {
      bf16x8 afr[4];
      #pragma unroll
      for (int ks = 0; ks < 4; ++ks)
        afr[ks] = *(const bf16x8*)((const short*)sG + (nt * 16 + lr) * 132 + ks * 32 + lk * 8);
      int rowb = n0b + nt * 16 + lk * 4;
      int4 c4 = *(const int4*)&cnt[rowb];
      float dvr[4] = { rsqrtf((float)c4.x + 1.f), rsqrtf((float)c4.y + 1.f),
                       rsqrtf((float)c4.z + 1.f), rsqrtf((float)c4.w + 1.f) };
      #pragma unroll
      for (int jtt = 0; jtt < 2; ++jtt) {
        f32x4 acc = {0.f, 0.f, 0.f, 0.f};
        #pragma unroll
        for (int ks = 0; ks < 4; ++ks)
          acc = __builtin_amdgcn_mfma_f32_16x16x32_bf16(afr[ks], bfr[jtt][ks], acc, 0, 0, 0);
        #pragma unroll
        for (int r = 0; r < 4; ++r)
          Hb[(size_t)(rowb + r) * HID + jb + jtt * 16 + lr] = f2us(acc[r] * dvr[r]);
      }
    }
  }
}

// ---------------- agg2 + bias + relu + mean-pool: rsqrt(cnt+1)*(H~[n]+sum H~[s]) ----------------
// block 256 = 16 nodes x 16 lanes (8 bf16 each); grid 4096; 8-deep gather MLP
__global__ __launch_bounds__(256) void agg2_pool_kernel(const unsigned short* __restrict__ Hb, const int* __restrict__ cnt,
                                                        const unsigned short* __restrict__ slots,
                                                        const float* __restrict__ bias, float* __restrict__ pooled)
{
  __shared__ float red[16][HID];           // 8 KB
  int tid = threadIdx.x;
  int g = tid >> 4;                        // local node 0..15
  int jq = (tid & 15) << 3;                // bf16 element offset 0..120
  int node = (blockIdx.x << 4) + g;
  int cn = cnt[node];
  float dn = rsqrtf((float)cn + 1.0f);
  float acc[8];
  {
    ushort8_v r = *(const ushort8_v*)(Hb + (size_t)node * HID + jq);
    #pragma unroll
    for (int k = 0; k < 8; ++k) acc[k] = us2f(r[k]);
  }
  const unsigned short* sl = slots + ((size_t)node << 5);
  int e1 = min(cn, SLOT_CAP);
  int e = 0;
  for (; e + 8 <= e1; e += 8) {
    ushort8_v r0 = *(const ushort8_v*)(Hb + (size_t)sl[e]     * HID + jq);
    ushort8_v r1 = *(const ushort8_v*)(Hb + (size_t)sl[e + 1] * HID + jq);
    ushort8_v r2 = *(const ushort8_v*)(Hb + (size_t)sl[e + 2] * HID + jq);
    ushort8_v r3 = *(const ushort8_v*)(Hb + (size_t)sl[e + 3] * HID + jq);
    ushort8_v r4 = *(const ushort8_v*)(Hb + (size_t)sl[e + 4] * HID + jq);
    ushort8_v r5 = *(const ushort8_v*)(Hb + (size_t)sl[e + 5] * HID + jq);
    ushort8_v r6 = *(const ushort8_v*)(Hb + (size_t)sl[e + 6] * HID + jq);
    ushort8_v r7 = *(const ushort8_v*)(Hb + (size_t)sl[e + 7] * HID + jq);
    #pragma unroll
    for (int k = 0; k < 8; ++k)
      acc[k] += ((us2f(r0[k]) + us2f(r1[k])) + (us2f(r2[k]) + us2f(r3[k])))
              + ((us2f(r4[k]) + us2f(r5[k])) + (us2f(r6[k]) + us2f(r7[k])));
  }
  for (; e + 4 <= e1; e += 4) {
    ushort8_v r0 = *(const ushort8_v*)(Hb + (size_t)sl[e]     * HID + jq);
    ushort8_v r1 = *(const ushort8_v*)(Hb + (size_t)sl[e + 1] * HID + jq);
    ushort8_v r2 = *(const ushort8_v*)(Hb + (size_t)sl[e + 2] * HID + jq);
    ushort8_v r3 = *(const ushort8_v*)(Hb + (size_t)sl[e + 3] * HID + jq);
    #pragma unroll
    for (int k = 0; k < 8; ++k)
      acc[k] += (us2f(r0[k]) + us2f(r1[k])) + (us2f(r2[k]) + us2f(r3[k]));
  }
  for (; e < e1; ++e) {
    ushort8_v r0 = *(const ushort8_v*)(Hb + (size_t)sl[e] * HID + jq);
    #pragma unroll
    for (int k = 0; k < 8; ++k) acc[k] += us2f(r0[k]);
  }
  #pragma unroll
  for (int k = 0; k < 8; ++k)
    red[g][jq + k] = fmaxf(dn * acc[k] + bias[jq + k], 0.f);
  __syncthreads();
  if (tid < HID) {
    float s = 0.f;
    #pragma unroll
    for (int g2 = 0; g2 < 16; ++g2) s += red[g2][tid];
    int b = blockIdx.x >> 6;               // 64 blocks per graph
    atomicAdd(&pooled[b * HID + tid], s * (1.0f / 1024.0f));
  }
}

// ---------------- classifier ----------------

__global__ __launch_bounds__(64) void cls_kernel(const float* __restrict__ pooled, const float* __restrict__ w,
                                                 const float* __restrict__ cb, float* __restrict__ out)
{
  int b = blockIdx.x, o = threadIdx.x;
  if (o < OUT_C) {
    float acc = cb[o];
    for (int i = 0; i < HID; ++i)
      acc += pooled[b * HID + i] * w[i * OUT_C + o];
    out[b * OUT_C + o] = acc;
  }
}

// ---------------- launcher ----------------

extern "C" void kernel_launch(void* const* d_in, const int* in_sizes, int n_in,
                              void* d_out, int out_size, void* d_ws, size_t ws_size,
                              hipStream_t stream)
{
  const float* x    = (const float*)d_in[0];
  const int*   ei   = (const int*)d_in[1];
  const float* c1w  = (const float*)d_in[2];
  const float* c1b  = (const float*)d_in[3];
  const float* c2w  = (const float*)d_in[4];
  const float* c2b  = (const float*)d_in[5];
  const float* g1w  = (const float*)d_in[6];
  const float* g1b  = (const float*)d_in[7];
  const float* g2w  = (const float*)d_in[8];
  const float* g2b  = (const float*)d_in[9];
  const float* clsw = (const float*)d_in[10];
  const float* clsb = (const float*)d_in[11];
  float* outp = (float*)d_out;

  char* ws = (char*)d_ws;
  size_t off_b = 0;
  auto alloc = [&](size_t bytes) { void* p = ws + off_b; off_b = (off_b + bytes + 255) & ~(size_t)255; return p; };
  int*   cnt    = (int*)  alloc((size_t)N_NODES * 4);
  unsigned short* slots = (unsigned short*)alloc((size_t)N_NODES * SLOT_CAP * 2);  // 4 MB
  unsigned short* w1t   = (unsigned short*)alloc((size_t)HID * 32 * 2);
  unsigned short* w2t   = (unsigned short*)alloc((size_t)HID * HID * 2);
  unsigned short* y1    = (unsigned short*)alloc((size_t)N_B * C1 * T1 * 2);
  unsigned short* feats = (unsigned short*)alloc((size_t)N_NODES * C2 * 2);
  unsigned short* H     = (unsigned short*)alloc((size_t)N_NODES * HID * 2);
  float* pooled = (float*)alloc((size_t)N_B * HID * 4);
  (void)ws_size; (void)in_sizes; (void)n_in; (void)out_size;

  // zero cnt (async memset; pooled is zeroed inside conv1_scatter's transpose block)
  hipMemsetAsync(cnt, 0, (size_t)N_NODES * 4, stream);

  // scatter || conv1 || weight transpose + pooled-zero (one launch)
  conv1_scatter_kernel<<<4113, 256, 0, stream>>>(x, c1w, c1b, ei, cnt, slots, y1, g1w, g2w, w1t, w2t, pooled);

  // conv2 (pre-scales by rsqrt(cnt+1))
  conv2_kernel<<<2048, 256, 0, stream>>>(y1, c2w, c2b, cnt, feats);

  // aggX (in-register) + both GEMMs (MFMA), one kernel
  gemm12_kernel<<<N_NODES / 64, 256, 0, stream>>>(feats, cnt, slots, w1t, g1b, w2t, H);

  // GCN layer 2 aggregation + bias + relu + mean-pool
  agg2_pool_kernel<<<N_NODES / 16, 256, 0, stream>>>(H, cnt, slots, g2b, pooled);

  // classifier
  cls_kernel<<<N_B, 64, 0, stream>>>(pooled, clsw, clsb, outp);
}

// Round 16
// 104.761 us; speedup vs baseline: 2.7091x; 1.0191x over previous
//
#include <hip/hip_runtime.h>
#include <hip/hip_bf16.h>

typedef __hip_bfloat16 bf16;
typedef unsigned short ushort8_v __attribute__((ext_vector_type(8)));
typedef short bf16x8 __attribute__((ext_vector_type(8)));
typedef float f32x4 __attribute__((ext_vector_type(4)));
typedef float f32x2 __attribute__((ext_vector_type(2)));

#define N_B     64
#define C_IN    9
#define T0      4096
#define C1      16
#define T1      2048
#define C2      32
#define T2      1024
#define N_NODES 65536
#define N_EDGES 524288
#define HID     128
#define OUT_C   10
#define SLOT_CAP 32

__device__ __forceinline__ float us2f(unsigned short u) {
  union { unsigned int i; float f; } c; c.i = ((unsigned int)u) << 16; return c.f;
}
__device__ __forceinline__ unsigned short f2us(float f) {
  bf16 h = __float2bfloat16(f);
  unsigned short u;
  __builtin_memcpy(&u, &h, 2);
  return u;
}
// fp8 OCP e4m3 via gfx950 HW cvt
__device__ __forceinline__ unsigned char f2fp8(float f) {
  int p = __builtin_amdgcn_cvt_pk_fp8_f32(f, f, 0, false);
  return (unsigned char)(p & 0xFF);
}
__device__ __forceinline__ void fp8w_to_f32x4(unsigned int w, float* out) {
  f32x2 lo = __builtin_amdgcn_cvt_pk_f32_fp8((int)w, false);
  f32x2 hi = __builtin_amdgcn_cvt_pk_f32_fp8((int)w, true);
  out[0] = lo[0]; out[1] = lo[1]; out[2] = hi[0]; out[3] = hi[1];
}

// ---------------- fused: scatter x4 (0..511) || conv1 (512..2559) || weight transpose + pooled-zero (2560..2576) ----------------
// slots: ushort, 32 per node = exactly one 64B line/node (4 MB total, L2-resident).
// scatter: 4 independent edges/thread -> 4 atomic chains in flight per wave.
__global__ __launch_bounds__(256) void conv1_scatter_kernel(const float* __restrict__ x, const float* __restrict__ w1,
                                                            const float* __restrict__ b1,
                                                            const int* __restrict__ ei, int* __restrict__ cnt,
                                                            unsigned short* __restrict__ slots,
                                                            unsigned short* __restrict__ y1,
                                                            const float* __restrict__ W1, const float* __restrict__ W2,
                                                            unsigned short* __restrict__ W1T,
                                                            unsigned short* __restrict__ W2T,
                                                            float* __restrict__ pooled)
{
  __shared__ float sx[C_IN * 136];
  __shared__ float sw[45 * 17];
  __shared__ float sb[C1];
  int tid = threadIdx.x;
  if (blockIdx.x < 512) {
    int e0 = blockIdx.x * 1024 + tid;
    int dd[4], ss[4];
    #pragma unroll
    for (int q = 0; q < 4; ++q) {
      dd[q] = ei[N_EDGES + e0 + q * 256];
      ss[q] = ei[e0 + q * 256];
    }
    #pragma unroll
    for (int q = 0; q < 4; ++q) {
      int r = atomicAdd(&cnt[dd[q]], 1);
      if (r < SLOT_CAP) slots[((size_t)dd[q] << 5) + r] = (unsigned short)ss[q];
    }
    return;
  }
  if (blockIdx.x >= 2560) {
    int blk = blockIdx.x - 2560;
    if (blk < 16) {                     // W2T[j][k] = bf16(W2[k][j]), 1024 elems/block
      int base = blk * 1024 + tid * 4;
      #pragma unroll
      for (int i = 0; i < 4; ++i) {
        int idx = base + i;
        int j = idx >> 7, k = idx & 127;
        W2T[j * HID + k] = f2us(W2[(size_t)k * HID + j]);
      }
    } else {                            // W1T[j][k] = bf16(W1[k][j]), 4096 elems; + zero pooled
      #pragma unroll
      for (int i = 0; i < 16; ++i) {
        int idx = tid * 16 + i;
        int j = idx >> 5, k = idx & 31;
        W1T[j * 32 + k] = f2us(W1[(size_t)k * HID + j]);
      }
      float4 z4 = make_float4(0.f, 0.f, 0.f, 0.f);
      for (int i = tid; i < N_B * HID / 4; i += 256)
        ((float4*)pooled)[i] = z4;
    }
    return;
  }
  int blk = blockIdx.x - 512;
  int b = blk >> 5;
  int P0 = (blk & 31) << 6;             // pooled tile start
  int t0 = 2 * P0 - 2;                  // x pos of sx[c][0]
  for (int i = tid; i < C_IN * 132; i += 256) {
    int c = i / 132, j = i % 132;
    int t = t0 + j;
    sx[c * 136 + j] = (t >= 0 && t < T0) ? x[(size_t)(b * C_IN + c) * T0 + t] : 0.f;
  }
  for (int i = tid; i < C1 * 45; i += 256) sw[(i % 45) * 17 + i / 45] = w1[i];
  if (tid < C1) sb[tid] = b1[tid];
  __syncthreads();

  int o = tid & 15, pg = tid >> 4;
  float bias = sb[o];
  float a[8];
  #pragma unroll
  for (int i = 0; i < 8; ++i) a[i] = bias;
  #pragma unroll
  for (int c = 0; c < C_IN; ++c) {
    float xv[12];
    #pragma unroll
    for (int q = 0; q < 3; ++q)
      *(float4*)&xv[4 * q] = *(const float4*)&sx[c * 136 + 8 * pg + 4 * q];
    const float* wr = &sw[(c * 5) * 17 + o];
    float w0 = wr[0], w1_ = wr[17], w2_ = wr[34], w3_ = wr[51], w4_ = wr[68];
    #pragma unroll
    for (int m = 0; m < 8; ++m)
      a[m] += xv[m]*w0 + xv[m+1]*w1_ + xv[m+2]*w2_ + xv[m+3]*w3_ + xv[m+4]*w4_;
  }
  ushort4 r;
  r.x = f2us(fmaxf(fmaxf(a[0], a[1]), 0.f));
  r.y = f2us(fmaxf(fmaxf(a[2], a[3]), 0.f));
  r.z = f2us(fmaxf(fmaxf(a[4], a[5]), 0.f));
  r.w = f2us(fmaxf(fmaxf(a[6], a[7]), 0.f));
  *(ushort4*)&y1[(size_t)(b * C1 + o) * T1 + P0 + 4 * pg] = r;
}

// ---------------- conv2 + relu + pool -> PRE-SCALED bf16 feats F~ = F * rsqrt(cnt+1) ----------------
__global__ __launch_bounds__(256) void conv2_kernel(const unsigned short* __restrict__ y1, const float* __restrict__ w2,
                                                    const float* __restrict__ b2, const int* __restrict__ cnt,
                                                    unsigned short* __restrict__ feats)
{
  __shared__ float sy[C1 * 72];
  __shared__ float sw[80 * 33];
  __shared__ float sb[C2];
  int tid = threadIdx.x;
  int b = blockIdx.x >> 5;
  int Q0 = (blockIdx.x & 31) << 5;      // final tile start
  int t0 = 2 * Q0 - 2;                  // y1 pos of sy[c][0]
  for (int i = tid; i < C1 * 68; i += 256) {
    int c = i / 68, j = i % 68;
    int t = t0 + j;
    sy[c * 72 + j] = (t >= 0 && t < T1) ? us2f(y1[(size_t)(b * C1 + c) * T1 + t]) : 0.f;
  }
  for (int i = tid; i < C2 * 80; i += 256) sw[(i % 80) * 33 + i / 80] = w2[i];
  if (tid < C2) sb[tid] = b2[tid];
  __syncthreads();

  int o = tid & 31, pg = tid >> 5;
  float bias = sb[o];
  float a[8];
  #pragma unroll
  for (int i = 0; i < 8; ++i) a[i] = bias;
  #pragma unroll
  for (int c = 0; c < C1; ++c) {
    float yv[12];
    #pragma unroll
    for (int q = 0; q < 3; ++q)
      *(float4*)&yv[4 * q] = *(const float4*)&sy[c * 72 + 8 * pg + 4 * q];
    const float* wr = &sw[(c * 5) * 33 + o];
    float w0 = wr[0], w1_ = wr[33], w2_ = wr[66], w3_ = wr[99], w4_ = wr[132];
    #pragma unroll
    for (int m = 0; m < 8; ++m)
      a[m] += yv[m]*w0 + yv[m+1]*w1_ + yv[m+2]*w2_ + yv[m+3]*w3_ + yv[m+4]*w4_;
  }
  #pragma unroll
  for (int i = 0; i < 4; ++i) {
    int node = (b << 10) + Q0 + 4 * pg + i;
    float dv = rsqrtf((float)cnt[node] + 1.0f);
    feats[(size_t)node * C2 + o] = f2us(fmaxf(fmaxf(a[2*i], a[2*i+1]), 0.f) * dv);
  }
}

// ---------------- gemm12 (gather + all-MFMA): aggX in-register; G=relu(..@W1+b1); H~=(G@W2)*rsqrt -> fp8 ----------------
// grid 1024 = 64 nodes/block; block 256 = 4 waves.
// mfma_f32_16x16x32_bf16 (m89): A row=l&15,k=(l>>4)*8+i ; B col=l&15,same k ; C col=l&15,row=(l>>4)*4+r.
__global__ __launch_bounds__(256) void gemm12_kernel(const unsigned short* __restrict__ F,
                                                     const int* __restrict__ cnt,
                                                     const unsigned short* __restrict__ slots,
                                                     const unsigned short* __restrict__ W1T,
                                                     const float* __restrict__ gb1,
                                                     const unsigned short* __restrict__ W2T,
                                                     unsigned char* __restrict__ Hb)
{
  __shared__ unsigned short sG[64 * 132];   // 16.9 KB
  int tid = threadIdx.x;
  int w = tid >> 6, l = tid & 63;
  int lr = l & 15, lk = l >> 4;
  int n0b = blockIdx.x << 6;
  int jb = w << 5;

  // phase A + GEMM1
  {
    int nb = w << 4;
    int node = n0b + nb + lr;
    int cn = cnt[node];
    float dn = rsqrtf((float)cn + 1.0f);
    int koff = lk << 3;
    float accf[8];
    {
      ushort8_v r = *(const ushort8_v*)(F + (size_t)node * C2 + koff);
      #pragma unroll
      for (int k = 0; k < 8; ++k) accf[k] = us2f(r[k]);
    }
    const unsigned short* sl = slots + ((size_t)node << 5);
    int e1 = min(cn, SLOT_CAP);
    int e = 0;
    for (; e + 4 <= e1; e += 4) {
      int s0 = sl[e], s1 = sl[e + 1], s2 = sl[e + 2], s3 = sl[e + 3];
      ushort8_v r0 = *(const ushort8_v*)(F + (size_t)s0 * C2 + koff);
      ushort8_v r1 = *(const ushort8_v*)(F + (size_t)s1 * C2 + koff);
      ushort8_v r2 = *(const ushort8_v*)(F + (size_t)s2 * C2 + koff);
      ushort8_v r3 = *(const ushort8_v*)(F + (size_t)s3 * C2 + koff);
      #pragma unroll
      for (int k = 0; k < 8; ++k)
        accf[k] += (us2f(r0[k]) + us2f(r1[k])) + (us2f(r2[k]) + us2f(r3[k]));
    }
    for (; e < e1; ++e) {
      int s0 = sl[e];
      ushort8_v r0 = *(const ushort8_v*)(F + (size_t)s0 * C2 + koff);
      #pragma unroll
      for (int k = 0; k < 8; ++k) accf[k] += us2f(r0[k]);
    }
    bf16x8 af;
    #pragma unroll
    for (int k = 0; k < 8; ++k) af[k] = (short)f2us(accf[k] * dn);

    #pragma unroll
    for (int jt = 0; jt < 8; ++jt) {
      bf16x8 bfr = *(const bf16x8*)((const short*)W1T + (jt * 16 + lr) * 32 + lk * 8);
      f32x4 acc = {0.f, 0.f, 0.f, 0.f};
      acc = __builtin_amdgcn_mfma_f32_16x16x32_bf16(af, bfr, acc, 0, 0, 0);
      float bj = gb1[jt * 16 + lr];
      #pragma unroll
      for (int r = 0; r < 4; ++r)
        sG[(nb + lk * 4 + r) * 132 + jt * 16 + lr] = f2us(fmaxf(acc[r] + bj, 0.f));
    }
  }

  // hoist GEMM2 B-frags (global, no sG dependence) above the barrier
  bf16x8 bfr[2][4];
  #pragma unroll
  for (int jtt = 0; jtt < 2; ++jtt)
    #pragma unroll
    for (int ks = 0; ks < 4; ++ks)
      bfr[jtt][ks] = *(const bf16x8*)((const short*)W2T + (size_t)(jb + jtt * 16 + lr) * HID + ks * 32 + lk * 8);

  __syncthreads();

  // GEMM2 -> fp8 H
  {
    #pragma unroll
    for (int nt = 0; nt < 4; ++nt) {
      bf16x8 afr[4];
      #pragma unroll
      for (int ks = 0; ks < 4; ++ks)
        afr[ks] = *(const bf16x8*)((const short*)sG + (nt * 16 + lr) * 132 + ks * 32 + lk * 8);
      int rowb = n0b + nt * 16 + lk * 4;
      int4 c4 = *(const int4*)&cnt[rowb];
      float dvr[4] = { rsqrtf((float)c4.x + 1.f), rsqrtf((float)c4.y + 1.f),
                       rsqrtf((float)c4.z + 1.f), rsqrtf((float)c4.w + 1.f) };
      #pragma unroll
      for (int jtt = 0; jtt < 2; ++jtt) {
        f32x4 acc = {0.f, 0.f, 0.f, 0.f};
        #pragma unroll
        for (int ks = 0; ks < 4; ++ks)
          acc = __builtin_amdgcn_mfma_f32_16x16x32_bf16(afr[ks], bfr[jtt][ks], acc, 0, 0, 0);
        #pragma unroll
        for (int r = 0; r < 4; ++r)
          Hb[(size_t)(rowb + r) * HID + jb + jtt * 16 + lr] = f2fp8(acc[r] * dvr[r]);
      }
    }
  }
}

// ---------------- agg2 + bias + relu + mean-pool: rsqrt(cnt+1)*(H~[n]+sum H~[s]), fp8 H ----------------
// block 256 = 16 nodes x 16 lanes (8 fp8 each -> 8B loads); grid 4096
__global__ __launch_bounds__(256) void agg2_pool_kernel(const unsigned char* __restrict__ Hb, const int* __restrict__ cnt,
                                                        const unsigned short* __restrict__ slots,
                                                        const float* __restrict__ bias, float* __restrict__ pooled)
{
  __shared__ float red[16][HID];           // 8 KB
  int tid = threadIdx.x;
  int g = tid >> 4;                        // local node 0..15
  int jq = (tid & 15) << 3;                // fp8 element (=byte) offset 0..120
  int node = (blockIdx.x << 4) + g;
  int cn = cnt[node];
  float dn = rsqrtf((float)cn + 1.0f);
  float acc[8];
  {
    uint2 v = *(const uint2*)(Hb + (size_t)node * HID + jq);
    fp8w_to_f32x4(v.x, &acc[0]);
    fp8w_to_f32x4(v.y, &acc[4]);
  }
  const unsigned short* sl = slots + ((size_t)node << 5);
  int e1 = min(cn, SLOT_CAP);
  int e = 0;
  for (; e + 4 <= e1; e += 4) {
    uint2 v0 = *(const uint2*)(Hb + (size_t)sl[e]     * HID + jq);
    uint2 v1 = *(const uint2*)(Hb + (size_t)sl[e + 1] * HID + jq);
    uint2 v2 = *(const uint2*)(Hb + (size_t)sl[e + 2] * HID + jq);
    uint2 v3 = *(const uint2*)(Hb + (size_t)sl[e + 3] * HID + jq);
    float t0[8], t1[8], t2[8], t3[8];
    fp8w_to_f32x4(v0.x, &t0[0]); fp8w_to_f32x4(v0.y, &t0[4]);
    fp8w_to_f32x4(v1.x, &t1[0]); fp8w_to_f32x4(v1.y, &t1[4]);
    fp8w_to_f32x4(v2.x, &t2[0]); fp8w_to_f32x4(v2.y, &t2[4]);
    fp8w_to_f32x4(v3.x, &t3[0]); fp8w_to_f32x4(v3.y, &t3[4]);
    #pragma unroll
    for (int k = 0; k < 8; ++k)
      acc[k] += (t0[k] + t1[k]) + (t2[k] + t3[k]);
  }
  for (; e < e1; ++e) {
    uint2 v0 = *(const uint2*)(Hb + (size_t)sl[e] * HID + jq);
    float t0[8];
    fp8w_to_f32x4(v0.x, &t0[0]); fp8w_to_f32x4(v0.y, &t0[4]);
    #pragma unroll
    for (int k = 0; k < 8; ++k) acc[k] += t0[k];
  }
  #pragma unroll
  for (int k = 0; k < 8; ++k)
    red[g][jq + k] = fmaxf(dn * acc[k] + bias[jq + k], 0.f);
  __syncthreads();
  if (tid < HID) {
    float s = 0.f;
    #pragma unroll
    for (int g2 = 0; g2 < 16; ++g2) s += red[g2][tid];
    int b = blockIdx.x >> 6;               // 64 blocks per graph
    atomicAdd(&pooled[b * HID + tid], s * (1.0f / 1024.0f));
  }
}

// ---------------- classifier ----------------

__global__ __launch_bounds__(64) void cls_kernel(const float* __restrict__ pooled, const float* __restrict__ w,
                                                 const float* __restrict__ cb, float* __restrict__ out)
{
  int b = blockIdx.x, o = threadIdx.x;
  if (o < OUT_C) {
    float acc = cb[o];
    for (int i = 0; i < HID; ++i)
      acc += pooled[b * HID + i] * w[i * OUT_C + o];
    out[b * OUT_C + o] = acc;
  }
}

// ---------------- launcher ----------------

extern "C" void kernel_launch(void* const* d_in, const int* in_sizes, int n_in,
                              void* d_out, int out_size, void* d_ws, size_t ws_size,
                              hipStream_t stream)
{
  const float* x    = (const float*)d_in[0];
  const int*   ei   = (const int*)d_in[1];
  const float* c1w  = (const float*)d_in[2];
  const float* c1b  = (const float*)d_in[3];
  const float* c2w  = (const float*)d_in[4];
  const float* c2b  = (const float*)d_in[5];
  const float* g1w  = (const float*)d_in[6];
  const float* g1b  = (const float*)d_in[7];
  const float* g2w  = (const float*)d_in[8];
  const float* g2b  = (const float*)d_in[9];
  const float* clsw = (const float*)d_in[10];
  const float* clsb = (const float*)d_in[11];
  float* outp = (float*)d_out;

  char* ws = (char*)d_ws;
  size_t off_b = 0;
  auto alloc = [&](size_t bytes) { void* p = ws + off_b; off_b = (off_b + bytes + 255) & ~(size_t)255; return p; };
  int*   cnt    = (int*)  alloc((size_t)N_NODES * 4);
  unsigned short* slots = (unsigned short*)alloc((size_t)N_NODES * SLOT_CAP * 2);  // 4 MB
  unsigned short* w1t   = (unsigned short*)alloc((size_t)HID * 32 * 2);
  unsigned short* w2t   = (unsigned short*)alloc((size_t)HID * HID * 2);
  unsigned short* y1    = (unsigned short*)alloc((size_t)N_B * C1 * T1 * 2);
  unsigned short* feats = (unsigned short*)alloc((size_t)N_NODES * C2 * 2);
  unsigned char*  H     = (unsigned char*) alloc((size_t)N_NODES * HID);           // fp8 e4m3, 8 MB
  float* pooled = (float*)alloc((size_t)N_B * HID * 4);
  (void)ws_size; (void)in_sizes; (void)n_in; (void)out_size;

  // zero cnt (async memset; pooled is zeroed inside conv1_scatter's transpose block)
  hipMemsetAsync(cnt, 0, (size_t)N_NODES * 4, stream);

  // scatter(4x-batched) || conv1 || weight transpose + pooled-zero (one launch)
  conv1_scatter_kernel<<<2577, 256, 0, stream>>>(x, c1w, c1b, ei, cnt, slots, y1, g1w, g2w, w1t, w2t, pooled);

  // conv2 (pre-scales by rsqrt(cnt+1))
  conv2_kernel<<<2048, 256, 0, stream>>>(y1, c2w, c2b, cnt, feats);

  // aggX (in-register) + both GEMMs (MFMA), one kernel; H out in fp8
  gemm12_kernel<<<N_NODES / 64, 256, 0, stream>>>(feats, cnt, slots, w1t, g1b, w2t, H);

  // GCN layer 2 aggregation + bias + relu + mean-pool (fp8 gather)
  agg2_pool_kernel<<<N_NODES / 16, 256, 0, stream>>>(H, cnt, slots, g2b, pooled);

  // classifier
  cls_kernel<<<N_B, 64, 0, stream>>>(pooled, clsw, clsb, outp);
}

// Round 17
// 98.347 us; speedup vs baseline: 2.8857x; 1.0652x over previous
//
#include <hip/hip_runtime.h>
#include <hip/hip_bf16.h>

typedef __hip_bfloat16 bf16;
typedef unsigned short ushort8_v __attribute__((ext_vector_type(8)));
typedef short bf16x8 __attribute__((ext_vector_type(8)));
typedef float f32x4 __attribute__((ext_vector_type(4)));
typedef float f32x2 __attribute__((ext_vector_type(2)));

#define N_B     64
#define C_IN    9
#define T0      4096
#define C1      16
#define T1      2048
#define C2      32
#define T2      1024
#define N_NODES 65536
#define N_EDGES 524288
#define HID     128
#define OUT_C   10
#define SLOT_CAP 32

__device__ __forceinline__ float us2f(unsigned short u) {
  union { unsigned int i; float f; } c; c.i = ((unsigned int)u) << 16; return c.f;
}
__device__ __forceinline__ unsigned short f2us(float f) {
  bf16 h = __float2bfloat16(f);
  unsigned short u;
  __builtin_memcpy(&u, &h, 2);
  return u;
}
// fp8 OCP e4m3 via gfx950 HW cvt
__device__ __forceinline__ unsigned char f2fp8(float f) {
  int p = __builtin_amdgcn_cvt_pk_fp8_f32(f, f, 0, false);
  return (unsigned char)(p & 0xFF);
}
__device__ __forceinline__ void fp8w_to_f32x4(unsigned int w, float* out) {
  f32x2 lo = __builtin_amdgcn_cvt_pk_f32_fp8((int)w, false);
  f32x2 hi = __builtin_amdgcn_cvt_pk_f32_fp8((int)w, true);
  out[0] = lo[0]; out[1] = lo[1]; out[2] = hi[0]; out[3] = hi[1];
}

// ---------------- fused: scatter (0..2047) || conv1 (2048..4095) || weight transpose + pooled-zero (4096..4112) ----------------
// slots: ushort, 32 per node = exactly one 64B line/node (4 MB total).
// scatter: 1 edge/thread -> max TLP for the atomic round-trips (R16 lesson: TLP > per-thread MLP here).
__global__ __launch_bounds__(256) void conv1_scatter_kernel(const float* __restrict__ x, const float* __restrict__ w1,
                                                            const float* __restrict__ b1,
                                                            const int* __restrict__ ei, int* __restrict__ cnt,
                                                            unsigned short* __restrict__ slots,
                                                            unsigned short* __restrict__ y1,
                                                            const float* __restrict__ W1, const float* __restrict__ W2,
                                                            unsigned short* __restrict__ W1T,
                                                            unsigned short* __restrict__ W2T,
                                                            float* __restrict__ pooled)
{
  __shared__ float sx[C_IN * 136];
  __shared__ float sw[45 * 17];
  __shared__ float sb[C1];
  int tid = threadIdx.x;
  if (blockIdx.x < 2048) {
    int e = blockIdx.x * 256 + tid;
    int d = ei[N_EDGES + e];
    int s = ei[e];
    int r = atomicAdd(&cnt[d], 1);
    if (r < SLOT_CAP) slots[((size_t)d << 5) + r] = (unsigned short)s;
    return;
  }
  if (blockIdx.x >= 4096) {
    int blk = blockIdx.x - 4096;
    if (blk < 16) {                     // W2T[j][k] = bf16(W2[k][j]), 1024 elems/block
      int base = blk * 1024 + tid * 4;
      #pragma unroll
      for (int i = 0; i < 4; ++i) {
        int idx = base + i;
        int j = idx >> 7, k = idx & 127;
        W2T[j * HID + k] = f2us(W2[(size_t)k * HID + j]);
      }
    } else {                            // W1T[j][k] = bf16(W1[k][j]), 4096 elems; + zero pooled
      #pragma unroll
      for (int i = 0; i < 16; ++i) {
        int idx = tid * 16 + i;
        int j = idx >> 5, k = idx & 31;
        W1T[j * 32 + k] = f2us(W1[(size_t)k * HID + j]);
      }
      float4 z4 = make_float4(0.f, 0.f, 0.f, 0.f);
      for (int i = tid; i < N_B * HID / 4; i += 256)
        ((float4*)pooled)[i] = z4;
    }
    return;
  }
  int blk = blockIdx.x - 2048;
  int b = blk >> 5;
  int P0 = (blk & 31) << 6;             // pooled tile start
  int t0 = 2 * P0 - 2;                  // x pos of sx[c][0]
  for (int i = tid; i < C_IN * 132; i += 256) {
    int c = i / 132, j = i % 132;
    int t = t0 + j;
    sx[c * 136 + j] = (t >= 0 && t < T0) ? x[(size_t)(b * C_IN + c) * T0 + t] : 0.f;
  }
  for (int i = tid; i < C1 * 45; i += 256) sw[(i % 45) * 17 + i / 45] = w1[i];
  if (tid < C1) sb[tid] = b1[tid];
  __syncthreads();

  int o = tid & 15, pg = tid >> 4;
  float bias = sb[o];
  float a[8];
  #pragma unroll
  for (int i = 0; i < 8; ++i) a[i] = bias;
  #pragma unroll
  for (int c = 0; c < C_IN; ++c) {
    float xv[12];
    #pragma unroll
    for (int q = 0; q < 3; ++q)
      *(float4*)&xv[4 * q] = *(const float4*)&sx[c * 136 + 8 * pg + 4 * q];
    const float* wr = &sw[(c * 5) * 17 + o];
    float w0 = wr[0], w1_ = wr[17], w2_ = wr[34], w3_ = wr[51], w4_ = wr[68];
    #pragma unroll
    for (int m = 0; m < 8; ++m)
      a[m] += xv[m]*w0 + xv[m+1]*w1_ + xv[m+2]*w2_ + xv[m+3]*w3_ + xv[m+4]*w4_;
  }
  ushort4 r;
  r.x = f2us(fmaxf(fmaxf(a[0], a[1]), 0.f));
  r.y = f2us(fmaxf(fmaxf(a[2], a[3]), 0.f));
  r.z = f2us(fmaxf(fmaxf(a[4], a[5]), 0.f));
  r.w = f2us(fmaxf(fmaxf(a[6], a[7]), 0.f));
  *(ushort4*)&y1[(size_t)(b * C1 + o) * T1 + P0 + 4 * pg] = r;
}

// ---------------- conv2 + relu + pool -> PRE-SCALED bf16 feats F~ = F * rsqrt(cnt+1) ----------------
__global__ __launch_bounds__(256) void conv2_kernel(const unsigned short* __restrict__ y1, const float* __restrict__ w2,
                                                    const float* __restrict__ b2, const int* __restrict__ cnt,
                                                    unsigned short* __restrict__ feats)
{
  __shared__ float sy[C1 * 72];
  __shared__ float sw[80 * 33];
  __shared__ float sb[C2];
  int tid = threadIdx.x;
  int b = blockIdx.x >> 5;
  int Q0 = (blockIdx.x & 31) << 5;      // final tile start
  int t0 = 2 * Q0 - 2;                  // y1 pos of sy[c][0]
  for (int i = tid; i < C1 * 68; i += 256) {
    int c = i / 68, j = i % 68;
    int t = t0 + j;
    sy[c * 72 + j] = (t >= 0 && t < T1) ? us2f(y1[(size_t)(b * C1 + c) * T1 + t]) : 0.f;
  }
  for (int i = tid; i < C2 * 80; i += 256) sw[(i % 80) * 33 + i / 80] = w2[i];
  if (tid < C2) sb[tid] = b2[tid];
  __syncthreads();

  int o = tid & 31, pg = tid >> 5;
  float bias = sb[o];
  float a[8];
  #pragma unroll
  for (int i = 0; i < 8; ++i) a[i] = bias;
  #pragma unroll
  for (int c = 0; c < C1; ++c) {
    float yv[12];
    #pragma unroll
    for (int q = 0; q < 3; ++q)
      *(float4*)&yv[4 * q] = *(const float4*)&sy[c * 72 + 8 * pg + 4 * q];
    const float* wr = &sw[(c * 5) * 33 + o];
    float w0 = wr[0], w1_ = wr[33], w2_ = wr[66], w3_ = wr[99], w4_ = wr[132];
    #pragma unroll
    for (int m = 0; m < 8; ++m)
      a[m] += yv[m]*w0 + yv[m+1]*w1_ + yv[m+2]*w2_ + yv[m+3]*w3_ + yv[m+4]*w4_;
  }
  #pragma unroll
  for (int i = 0; i < 4; ++i) {
    int node = (b << 10) + Q0 + 4 * pg + i;
    float dv = rsqrtf((float)cnt[node] + 1.0f);
    feats[(size_t)node * C2 + o] = f2us(fmaxf(fmaxf(a[2*i], a[2*i+1]), 0.f) * dv);
  }
}

// ---------------- gemm12 (gather + all-MFMA): aggX in-register; G=relu(..@W1+b1); H~=(G@W2)*rsqrt -> fp8 ----------------
// grid 1024 = 64 nodes/block; block 256 = 4 waves.
// mfma_f32_16x16x32_bf16 (m89): A row=l&15,k=(l>>4)*8+i ; B col=l&15,same k ; C col=l&15,row=(l>>4)*4+r.
__global__ __launch_bounds__(256) void gemm12_kernel(const unsigned short* __restrict__ F,
                                                     const int* __restrict__ cnt,
                                                     const unsigned short* __restrict__ slots,
                                                     const unsigned short* __restrict__ W1T,
                                                     const float* __restrict__ gb1,
                                                     const unsigned short* __restrict__ W2T,
                                                     unsigned char* __restrict__ Hb)
{
  __shared__ unsigned short sG[64 * 132];   // 16.9 KB
  int tid = threadIdx.x;
  int w = tid >> 6, l = tid & 63;
  int lr = l & 15, lk = l >> 4;
  int n0b = blockIdx.x << 6;
  int jb = w << 5;

  // phase A + GEMM1
  {
    int nb = w << 4;
    int node = n0b + nb + lr;
    int cn = cnt[node];
    float dn = rsqrtf((float)cn + 1.0f);
    int koff = lk << 3;
    float accf[8];
    {
      ushort8_v r = *(const ushort8_v*)(F + (size_t)node * C2 + koff);
      #pragma unroll
      for (int k = 0; k < 8; ++k) accf[k] = us2f(r[k]);
    }
    const unsigned short* sl = slots + ((size_t)node << 5);
    int e1 = min(cn, SLOT_CAP);
    int e = 0;
    for (; e + 4 <= e1; e += 4) {
      int s0 = sl[e], s1 = sl[e + 1], s2 = sl[e + 2], s3 = sl[e + 3];
      ushort8_v r0 = *(const ushort8_v*)(F + (size_t)s0 * C2 + koff);
      ushort8_v r1 = *(const ushort8_v*)(F + (size_t)s1 * C2 + koff);
      ushort8_v r2 = *(const ushort8_v*)(F + (size_t)s2 * C2 + koff);
      ushort8_v r3 = *(const ushort8_v*)(F + (size_t)s3 * C2 + koff);
      #pragma unroll
      for (int k = 0; k < 8; ++k)
        accf[k] += (us2f(r0[k]) + us2f(r1[k])) + (us2f(r2[k]) + us2f(r3[k]));
    }
    for (; e < e1; ++e) {
      int s0 = sl[e];
      ushort8_v r0 = *(const ushort8_v*)(F + (size_t)s0 * C2 + koff);
      #pragma unroll
      for (int k = 0; k < 8; ++k) accf[k] += us2f(r0[k]);
    }
    bf16x8 af;
    #pragma unroll
    for (int k = 0; k < 8; ++k) af[k] = (short)f2us(accf[k] * dn);

    #pragma unroll
    for (int jt = 0; jt < 8; ++jt) {
      bf16x8 bfr = *(const bf16x8*)((const short*)W1T + (jt * 16 + lr) * 32 + lk * 8);
      f32x4 acc = {0.f, 0.f, 0.f, 0.f};
      acc = __builtin_amdgcn_mfma_f32_16x16x32_bf16(af, bfr, acc, 0, 0, 0);
      float bj = gb1[jt * 16 + lr];
      #pragma unroll
      for (int r = 0; r < 4; ++r)
        sG[(nb + lk * 4 + r) * 132 + jt * 16 + lr] = f2us(fmaxf(acc[r] + bj, 0.f));
    }
  }

  // hoist GEMM2 B-frags (global, no sG dependence) above the barrier
  bf16x8 bfr[2][4];
  #pragma unroll
  for (int jtt = 0; jtt < 2; ++jtt)
    #pragma unroll
    for (int ks = 0; ks < 4; ++ks)
      bfr[jtt][ks] = *(const bf16x8*)((const short*)W2T + (size_t)(jb + jtt * 16 + lr) * HID + ks * 32 + lk * 8);

  __syncthreads();

  // GEMM2 -> fp8 H
  {
    #pragma unroll
    for (int nt = 0; nt < 4; ++nt) {
      bf16x8 afr[4];
      #pragma unroll
      for (int ks = 0; ks < 4; ++ks)
        afr[ks] = *(const bf16x8*)((const short*)sG + (nt * 16 + lr) * 132 + ks * 32 + lk * 8);
      int rowb = n0b + nt * 16 + lk * 4;
      int4 c4 = *(const int4*)&cnt[rowb];
      float dvr[4] = { rsqrtf((float)c4.x + 1.f), rsqrtf((float)c4.y + 1.f),
                       rsqrtf((float)c4.z + 1.f), rsqrtf((float)c4.w + 1.f) };
      #pragma unroll
      for (int jtt = 0; jtt < 2; ++jtt) {
        f32x4 acc = {0.f, 0.f, 0.f, 0.f};
        #pragma unroll
        for (int ks = 0; ks < 4; ++ks)
          acc = __builtin_amdgcn_mfma_f32_16x16x32_bf16(afr[ks], bfr[jtt][ks], acc, 0, 0, 0);
        #pragma unroll
        for (int r = 0; r < 4; ++r)
          Hb[(size_t)(rowb + r) * HID + jb + jtt * 16 + lr] = f2fp8(acc[r] * dvr[r]);
      }
    }
  }
}

// ---------------- agg2 + bias + relu + mean-pool: rsqrt(cnt+1)*(H~[n]+sum H~[s]), fp8 H ----------------
// block 256 = 16 nodes x 16 lanes (8 fp8 each -> 8B loads); grid 4096
__global__ __launch_bounds__(256) void agg2_pool_kernel(const unsigned char* __restrict__ Hb, const int* __restrict__ cnt,
                                                        const unsigned short* __restrict__ slots,
                                                        const float* __restrict__ bias, float* __restrict__ pooled)
{
  __shared__ float red[16][HID];           // 8 KB
  int tid = threadIdx.x;
  int g = tid >> 4;                        // local node 0..15
  int jq = (tid & 15) << 3;                // fp8 element (=byte) offset 0..120
  int node = (blockIdx.x << 4) + g;
  int cn = cnt[node];
  float dn = rsqrtf((float)cn + 1.0f);
  float acc[8];
  {
    uint2 v = *(const uint2*)(Hb + (size_t)node * HID + jq);
    fp8w_to_f32x4(v.x, &acc[0]);
    fp8w_to_f32x4(v.y, &acc[4]);
  }
  const unsigned short* sl = slots + ((size_t)node << 5);
  int e1 = min(cn, SLOT_CAP);
  int e = 0;
  for (; e + 4 <= e1; e += 4) {
    uint2 v0 = *(const uint2*)(Hb + (size_t)sl[e]     * HID + jq);
    uint2 v1 = *(const uint2*)(Hb + (size_t)sl[e + 1] * HID + jq);
    uint2 v2 = *(const uint2*)(Hb + (size_t)sl[e + 2] * HID + jq);
    uint2 v3 = *(const uint2*)(Hb + (size_t)sl[e + 3] * HID + jq);
    float t0[8], t1[8], t2[8], t3[8];
    fp8w_to_f32x4(v0.x, &t0[0]); fp8w_to_f32x4(v0.y, &t0[4]);
    fp8w_to_f32x4(v1.x, &t1[0]); fp8w_to_f32x4(v1.y, &t1[4]);
    fp8w_to_f32x4(v2.x, &t2[0]); fp8w_to_f32x4(v2.y, &t2[4]);
    fp8w_to_f32x4(v3.x, &t3[0]); fp8w_to_f32x4(v3.y, &t3[4]);
    #pragma unroll
    for (int k = 0; k < 8; ++k)
      acc[k] += (t0[k] + t1[k]) + (t2[k] + t3[k]);
  }
  for (; e < e1; ++e) {
    uint2 v0 = *(const uint2*)(Hb + (size_t)sl[e] * HID + jq);
    float t0[8];
    fp8w_to_f32x4(v0.x, &t0[0]); fp8w_to_f32x4(v0.y, &t0[4]);
    #pragma unroll
    for (int k = 0; k < 8; ++k) acc[k] += t0[k];
  }
  #pragma unroll
  for (int k = 0; k < 8; ++k)
    red[g][jq + k] = fmaxf(dn * acc[k] + bias[jq + k], 0.f);
  __syncthreads();
  if (tid < HID) {
    float s = 0.f;
    #pragma unroll
    for (int g2 = 0; g2 < 16; ++g2) s += red[g2][tid];
    int b = blockIdx.x >> 6;               // 64 blocks per graph
    atomicAdd(&pooled[b * HID + tid], s * (1.0f / 1024.0f));
  }
}

// ---------------- classifier ----------------

__global__ __launch_bounds__(64) void cls_kernel(const float* __restrict__ pooled, const float* __restrict__ w,
                                                 const float* __restrict__ cb, float* __restrict__ out)
{
  int b = blockIdx.x, o = threadIdx.x;
  if (o < OUT_C) {
    float acc = cb[o];
    for (int i = 0; i < HID; ++i)
      acc += pooled[b * HID + i] * w[i * OUT_C + o];
    out[b * OUT_C + o] = acc;
  }
}

// ---------------- launcher ----------------

extern "C" void kernel_launch(void* const* d_in, const int* in_sizes, int n_in,
                              void* d_out, int out_size, void* d_ws, size_t ws_size,
                              hipStream_t stream)
{
  const float* x    = (const float*)d_in[0];
  const int*   ei   = (const int*)d_in[1];
  const float* c1w  = (const float*)d_in[2];
  const float* c1b  = (const float*)d_in[3];
  const float* c2w  = (const float*)d_in[4];
  const float* c2b  = (const float*)d_in[5];
  const float* g1w  = (const float*)d_in[6];
  const float* g1b  = (const float*)d_in[7];
  const float* g2w  = (const float*)d_in[8];
  const float* g2b  = (const float*)d_in[9];
  const float* clsw = (const float*)d_in[10];
  const float* clsb = (const float*)d_in[11];
  float* outp = (float*)d_out;

  char* ws = (char*)d_ws;
  size_t off_b = 0;
  auto alloc = [&](size_t bytes) { void* p = ws + off_b; off_b = (off_b + bytes + 255) & ~(size_t)255; return p; };
  int*   cnt    = (int*)  alloc((size_t)N_NODES * 4);
  unsigned short* slots = (unsigned short*)alloc((size_t)N_NODES * SLOT_CAP * 2);  // 4 MB
  unsigned short* w1t   = (unsigned short*)alloc((size_t)HID * 32 * 2);
  unsigned short* w2t   = (unsigned short*)alloc((size_t)HID * HID * 2);
  unsigned short* y1    = (unsigned short*)alloc((size_t)N_B * C1 * T1 * 2);
  unsigned short* feats = (unsigned short*)alloc((size_t)N_NODES * C2 * 2);
  unsigned char*  H     = (unsigned char*) alloc((size_t)N_NODES * HID);           // fp8 e4m3, 8 MB
  float* pooled = (float*)alloc((size_t)N_B * HID * 4);
  (void)ws_size; (void)in_sizes; (void)n_in; (void)out_size;

  // zero cnt (async memset; pooled is zeroed inside conv1_scatter's transpose block)
  hipMemsetAsync(cnt, 0, (size_t)N_NODES * 4, stream);

  // scatter(1 edge/thread) || conv1 || weight transpose + pooled-zero (one launch)
  conv1_scatter_kernel<<<4113, 256, 0, stream>>>(x, c1w, c1b, ei, cnt, slots, y1, g1w, g2w, w1t, w2t, pooled);

  // conv2 (pre-scales by rsqrt(cnt+1))
  conv2_kernel<<<2048, 256, 0, stream>>>(y1, c2w, c2b, cnt, feats);

  // aggX (in-register) + both GEMMs (MFMA), one kernel; H out in fp8
  gemm12_kernel<<<N_NODES / 64, 256, 0, stream>>>(feats, cnt, slots, w1t, g1b, w2t, H);

  // GCN layer 2 aggregation + bias + relu + mean-pool (fp8 gather)
  agg2_pool_kernel<<<N_NODES / 16, 256, 0, stream>>>(H, cnt, slots, g2b, pooled);

  // classifier
  cls_kernel<<<N_B, 64, 0, stream>>>(pooled, clsw, clsb, outp);
}

// Round 18
// 96.236 us; speedup vs baseline: 2.9490x; 1.0219x over previous
//
#include <hip/hip_runtime.h>
#include <hip/hip_bf16.h>

typedef __hip_bfloat16 bf16;
typedef unsigned short ushort8_v __attribute__((ext_vector_type(8)));
typedef short bf16x8 __attribute__((ext_vector_type(8)));
typedef float f32x4 __attribute__((ext_vector_type(4)));
typedef float f32x2 __attribute__((ext_vector_type(2)));

#define N_B     64
#define C_IN    9
#define T0      4096
#define C1      16
#define T1      2048
#define C2      32
#define T2      1024
#define N_NODES 65536
#define N_EDGES 524288
#define HID     128
#define OUT_C   10
#define SLOT_CAP 32

__device__ __forceinline__ float us2f(unsigned short u) {
  union { unsigned int i; float f; } c; c.i = ((unsigned int)u) << 16; return c.f;
}
__device__ __forceinline__ unsigned short f2us(float f) {
  bf16 h = __float2bfloat16(f);
  unsigned short u;
  __builtin_memcpy(&u, &h, 2);
  return u;
}
// fp8 OCP e4m3 via gfx950 HW cvt
__device__ __forceinline__ unsigned char f2fp8(float f) {
  int p = __builtin_amdgcn_cvt_pk_fp8_f32(f, f, 0, false);
  return (unsigned char)(p & 0xFF);
}
__device__ __forceinline__ void fp8w_to_f32x4(unsigned int w, float* out) {
  f32x2 lo = __builtin_amdgcn_cvt_pk_f32_fp8((int)w, false);
  f32x2 hi = __builtin_amdgcn_cvt_pk_f32_fp8((int)w, true);
  out[0] = lo[0]; out[1] = lo[1]; out[2] = hi[0]; out[3] = hi[1];
}

// ---------------- front: scatter (0..2047) || conv1+conv2 fused (2048..4095) || transpose+zero (4096..4112) ----------------
// scatter: 1 edge/thread (max TLP — R16 lesson). slots: ushort, 32/node = one 64B line/node.
// conv blocks: per 32-final-pos tile, conv1 -> LDS sy[16][72] (conflict-free f4 writes), conv2 -> RAW bf16 feats
// (no dinv pre-scale: removes the scatter->conv dependency so conv work hides fully under the scatter).
__global__ __launch_bounds__(256) void front_kernel(const float* __restrict__ x, const float* __restrict__ w1c,
                                                    const float* __restrict__ b1c, const float* __restrict__ w2c,
                                                    const float* __restrict__ b2c,
                                                    const int* __restrict__ ei, int* __restrict__ cnt,
                                                    unsigned short* __restrict__ slots,
                                                    const float* __restrict__ W1, const float* __restrict__ W2,
                                                    unsigned short* __restrict__ W1T,
                                                    unsigned short* __restrict__ W2T,
                                                    float* __restrict__ pooled,
                                                    unsigned short* __restrict__ feats)
{
  __shared__ float sx[C_IN * 144];    // 5.2 KB  x tile (140 staged, 144 stride)
  __shared__ float sy[C1 * 72];       // 4.6 KB  y1 tile (68 positions)
  __shared__ float sw1[45 * 17];      // 3.1 KB
  __shared__ float sw2[80 * 33];      // 10.6 KB
  __shared__ float sb1[C1];
  __shared__ float sb2[C2];
  int tid = threadIdx.x;

  if (blockIdx.x < 2048) {
    int e = blockIdx.x * 256 + tid;
    int d = ei[N_EDGES + e];
    int s = ei[e];
    int r = atomicAdd(&cnt[d], 1);
    if (r < SLOT_CAP) slots[((size_t)d << 5) + r] = (unsigned short)s;
    return;
  }
  if (blockIdx.x >= 4096) {
    int blk = blockIdx.x - 4096;
    if (blk < 16) {                     // W2T[j][k] = bf16(W2[k][j])
      int base = blk * 1024 + tid * 4;
      #pragma unroll
      for (int i = 0; i < 4; ++i) {
        int idx = base + i;
        int j = idx >> 7, k = idx & 127;
        W2T[j * HID + k] = f2us(W2[(size_t)k * HID + j]);
      }
    } else {                            // W1T[j][k] = bf16(W1[k][j]); zero pooled
      #pragma unroll
      for (int i = 0; i < 16; ++i) {
        int idx = tid * 16 + i;
        int j = idx >> 5, k = idx & 31;
        W1T[j * 32 + k] = f2us(W1[(size_t)k * HID + j]);
      }
      float4 z4 = make_float4(0.f, 0.f, 0.f, 0.f);
      for (int i = tid; i < N_B * HID / 4; i += 256)
        ((float4*)pooled)[i] = z4;
    }
    return;
  }

  int blk = blockIdx.x - 2048;
  int b = blk >> 5;
  int Q0 = (blk & 31) << 5;             // 32 final positions per tile
  int x0 = 4 * Q0 - 6;                  // x pos of sx[c][0]

  for (int i = tid; i < C_IN * 140; i += 256) {
    int c = i / 140, j = i % 140;
    int t = x0 + j;
    sx[c * 144 + j] = (t >= 0 && t < T0) ? x[(size_t)(b * C_IN + c) * T0 + t] : 0.f;
  }
  for (int i = tid; i < C1 * 45; i += 256) sw1[(i % 45) * 17 + i / 45] = w1c[i];
  for (int i = tid; i < C2 * 80; i += 256) sw2[(i % 80) * 33 + i / 80] = w2c[i];
  if (tid < C1) sb1[tid] = b1c[tid];
  else if (tid >= 32 && tid < 64) sb2[tid - 32] = b2c[tid - 32];
  __syncthreads();

  // stage 1: conv1+relu+pool -> sy[o][q], q=0..67 local (y1 pos p = 2*Q0-2+q; 0 outside [0,T1))
  {
    int o = tid & 15, pg = tid >> 4;
    float bias = sb1[o];
    float a[8];
    #pragma unroll
    for (int i = 0; i < 8; ++i) a[i] = bias;
    #pragma unroll
    for (int c = 0; c < C_IN; ++c) {
      float xv[12];
      #pragma unroll
      for (int q = 0; q < 3; ++q)
        *(float4*)&xv[4 * q] = *(const float4*)&sx[c * 144 + 8 * pg + 4 * q];
      const float* wr = &sw1[(c * 5) * 17 + o];
      float w0 = wr[0], w1_ = wr[17], w2_ = wr[34], w3_ = wr[51], w4_ = wr[68];
      #pragma unroll
      for (int m = 0; m < 8; ++m)
        a[m] += xv[m]*w0 + xv[m+1]*w1_ + xv[m+2]*w2_ + xv[m+3]*w3_ + xv[m+4]*w4_;
    }
    float4 r;
    int pb = 2 * Q0 - 2 + 4 * pg;
    r.x = (pb + 0 >= 0 && pb + 0 < T1) ? fmaxf(fmaxf(a[0], a[1]), 0.f) : 0.f;
    r.y = (pb + 1 >= 0 && pb + 1 < T1) ? fmaxf(fmaxf(a[2], a[3]), 0.f) : 0.f;
    r.z = (pb + 2 >= 0 && pb + 2 < T1) ? fmaxf(fmaxf(a[4], a[5]), 0.f) : 0.f;
    r.w = (pb + 3 >= 0 && pb + 3 < T1) ? fmaxf(fmaxf(a[6], a[7]), 0.f) : 0.f;
    *(float4*)&sy[o * 72 + 4 * pg] = r;   // 72 = 4*18: aligned; banks 18o+pg all distinct
    if (pg < 4) {                          // tail q = 64..67
      int q = 64 + pg;
      int p = 2 * Q0 - 2 + q;
      float v = 0.f;
      if (p >= 0 && p < T1) {
        float t0 = bias, t1 = bias;
        #pragma unroll
        for (int c = 0; c < C_IN; ++c) {
          const float* xr = &sx[c * 144 + 2 * q];
          const float* wr = &sw1[(c * 5) * 17 + o];
          float w0 = wr[0], w1_ = wr[17], w2_ = wr[34], w3_ = wr[51], w4_ = wr[68];
          t0 += xr[0]*w0 + xr[1]*w1_ + xr[2]*w2_ + xr[3]*w3_ + xr[4]*w4_;
          t1 += xr[1]*w0 + xr[2]*w1_ + xr[3]*w2_ + xr[4]*w3_ + xr[5]*w4_;
        }
        v = fmaxf(fmaxf(t0, t1), 0.f);
      }
      sy[o * 72 + q] = v;
    }
  }
  __syncthreads();

  // stage 2: conv2+relu+pool -> RAW bf16 feats [node][32]
  {
    int o = tid & 31, ug = tid >> 5;
    float bias = sb2[o];
    float a[8];
    #pragma unroll
    for (int i = 0; i < 8; ++i) a[i] = bias;
    #pragma unroll
    for (int c = 0; c < C1; ++c) {
      float yv[12];
      #pragma unroll
      for (int q = 0; q < 3; ++q)
        *(float4*)&yv[4 * q] = *(const float4*)&sy[c * 72 + 8 * ug + 4 * q];
      const float* wr = &sw2[(c * 5) * 33 + o];
      float w0 = wr[0], w1_ = wr[33], w2_ = wr[66], w3_ = wr[99], w4_ = wr[132];
      #pragma unroll
      for (int m = 0; m < 8; ++m)
        a[m] += yv[m]*w0 + yv[m+1]*w1_ + yv[m+2]*w2_ + yv[m+3]*w3_ + yv[m+4]*w4_;
    }
    #pragma unroll
    for (int i = 0; i < 4; ++i) {
      int node = (b << 10) + Q0 + 4 * ug + i;
      feats[(size_t)node * C2 + o] = f2us(fmaxf(fmaxf(a[2*i], a[2*i+1]), 0.f));
    }
  }
}

// ---------------- gemm12: gather (dinv applied in fp32) + GEMM1 + GEMM2 (MFMA) -> fp8 H~ ----------------
// grid 1024 = 64 nodes/block; block 256 = 4 waves.
// agg = dinv[n]*(F[n]*dinv[n] + sum_s F[s]*dinv[s]); G = relu(agg@W1+b1); H~ = (G@W2)*dinv[row].
// mfma_f32_16x16x32_bf16 (m89): A row=l&15,k=(l>>4)*8+i ; B col=l&15,same k ; C col=l&15,row=(l>>4)*4+r.
__global__ __launch_bounds__(256) void gemm12_kernel(const unsigned short* __restrict__ F,
                                                     const int* __restrict__ cnt,
                                                     const unsigned short* __restrict__ slots,
                                                     const unsigned short* __restrict__ W1T,
                                                     const float* __restrict__ gb1,
                                                     const unsigned short* __restrict__ W2T,
                                                     unsigned char* __restrict__ Hb)
{
  __shared__ unsigned short sG[64 * 132];   // 16.9 KB
  int tid = threadIdx.x;
  int w = tid >> 6, l = tid & 63;
  int lr = l & 15, lk = l >> 4;
  int n0b = blockIdx.x << 6;
  int jb = w << 5;

  // phase A + GEMM1
  {
    int nb = w << 4;
    int node = n0b + nb + lr;
    int cn = cnt[node];
    float dn = rsqrtf((float)cn + 1.0f);
    int koff = lk << 3;
    float accf[8];
    {
      ushort8_v r = *(const ushort8_v*)(F + (size_t)node * C2 + koff);
      #pragma unroll
      for (int k = 0; k < 8; ++k) accf[k] = us2f(r[k]) * dn;   // self term: F[n]*dinv[n]
    }
    const unsigned short* sl = slots + ((size_t)node << 5);
    int e1 = min(cn, SLOT_CAP);
    int e = 0;
    for (; e + 4 <= e1; e += 4) {
      int s0 = sl[e], s1 = sl[e + 1], s2 = sl[e + 2], s3 = sl[e + 3];
      float d0 = rsqrtf((float)cnt[s0] + 1.f), d1 = rsqrtf((float)cnt[s1] + 1.f);
      float d2 = rsqrtf((float)cnt[s2] + 1.f), d3 = rsqrtf((float)cnt[s3] + 1.f);
      ushort8_v r0 = *(const ushort8_v*)(F + (size_t)s0 * C2 + koff);
      ushort8_v r1 = *(const ushort8_v*)(F + (size_t)s1 * C2 + koff);
      ushort8_v r2 = *(const ushort8_v*)(F + (size_t)s2 * C2 + koff);
      ushort8_v r3 = *(const ushort8_v*)(F + (size_t)s3 * C2 + koff);
      #pragma unroll
      for (int k = 0; k < 8; ++k)
        accf[k] += (us2f(r0[k]) * d0 + us2f(r1[k]) * d1) + (us2f(r2[k]) * d2 + us2f(r3[k]) * d3);
    }
    for (; e < e1; ++e) {
      int s0 = sl[e];
      float d0 = rsqrtf((float)cnt[s0] + 1.f);
      ushort8_v r0 = *(const ushort8_v*)(F + (size_t)s0 * C2 + koff);
      #pragma unroll
      for (int k = 0; k < 8; ++k) accf[k] += us2f(r0[k]) * d0;
    }
    bf16x8 af;
    #pragma unroll
    for (int k = 0; k < 8; ++k) af[k] = (short)f2us(accf[k] * dn);

    #pragma unroll
    for (int jt = 0; jt < 8; ++jt) {
      bf16x8 bfr = *(const bf16x8*)((const short*)W1T + (jt * 16 + lr) * 32 + lk * 8);
      f32x4 acc = {0.f, 0.f, 0.f, 0.f};
      acc = __builtin_amdgcn_mfma_f32_16x16x32_bf16(af, bfr, acc, 0, 0, 0);
      float bj = gb1[jt * 16 + lr];
      #pragma unroll
      for (int r = 0; r < 4; ++r)
        sG[(nb + lk * 4 + r) * 132 + jt * 16 + lr] = f2us(fmaxf(acc[r] + bj, 0.f));
    }
  }

  // hoist GEMM2 B-frags above the barrier (latency hides under the drain)
  bf16x8 bfr[2][4];
  #pragma unroll
  for (int jtt = 0; jtt < 2; ++jtt)
    #pragma unroll
    for (int ks = 0; ks < 4; ++ks)
      bfr[jtt][ks] = *(const bf16x8*)((const short*)W2T + (size_t)(jb + jtt * 16 + lr) * HID + ks * 32 + lk * 8);

  __syncthreads();

  // GEMM2 -> fp8 H
  {
    #pragma unroll
    for (int nt = 0; nt < 4; ++nt) {
      bf16x8 afr[4];
      #pragma unroll
      for (int ks = 0; ks < 4; ++ks)
        afr[ks] = *(const bf16x8*)((const short*)sG + (nt * 16 + lr) * 132 + ks * 32 + lk * 8);
      int rowb = n0b + nt * 16 + lk * 4;
      int4 c4 = *(const int4*)&cnt[rowb];
      float dvr[4] = { rsqrtf((float)c4.x + 1.f), rsqrtf((float)c4.y + 1.f),
                       rsqrtf((float)c4.z + 1.f), rsqrtf((float)c4.w + 1.f) };
      #pragma unroll
      for (int jtt = 0; jtt < 2; ++jtt) {
        f32x4 acc = {0.f, 0.f, 0.f, 0.f};
        #pragma unroll
        for (int ks = 0; ks < 4; ++ks)
          acc = __builtin_amdgcn_mfma_f32_16x16x32_bf16(afr[ks], bfr[jtt][ks], acc, 0, 0, 0);
        #pragma unroll
        for (int r = 0; r < 4; ++r)
          Hb[(size_t)(rowb + r) * HID + jb + jtt * 16 + lr] = f2fp8(acc[r] * dvr[r]);
      }
    }
  }
}

// ---------------- agg2 + bias + relu + mean-pool: rsqrt(cnt+1)*(H~[n]+sum H~[s]), fp8 H ----------------
// block 256 = 16 nodes x 16 lanes (8 fp8 each -> 8B loads); grid 4096
__global__ __launch_bounds__(256) void agg2_pool_kernel(const unsigned char* __restrict__ Hb, const int* __restrict__ cnt,
                                                        const unsigned short* __restrict__ slots,
                                                        const float* __restrict__ bias, float* __restrict__ pooled)
{
  __shared__ float red[16][HID];           // 8 KB
  int tid = threadIdx.x;
  int g = tid >> 4;                        // local node 0..15
  int jq = (tid & 15) << 3;                // fp8 element (=byte) offset 0..120
  int node = (blockIdx.x << 4) + g;
  int cn = cnt[node];
  float dn = rsqrtf((float)cn + 1.0f);
  float acc[8];
  {
    uint2 v = *(const uint2*)(Hb + (size_t)node * HID + jq);
    fp8w_to_f32x4(v.x, &acc[0]);
    fp8w_to_f32x4(v.y, &acc[4]);
  }
  const unsigned short* sl = slots + ((size_t)node << 5);
  int e1 = min(cn, SLOT_CAP);
  int e = 0;
  for (; e + 4 <= e1; e += 4) {
    uint2 v0 = *(const uint2*)(Hb + (size_t)sl[e]     * HID + jq);
    uint2 v1 = *(const uint2*)(Hb + (size_t)sl[e + 1] * HID + jq);
    uint2 v2 = *(const uint2*)(Hb + (size_t)sl[e + 2] * HID + jq);
    uint2 v3 = *(const uint2*)(Hb + (size_t)sl[e + 3] * HID + jq);
    float t0[8], t1[8], t2[8], t3[8];
    fp8w_to_f32x4(v0.x, &t0[0]); fp8w_to_f32x4(v0.y, &t0[4]);
    fp8w_to_f32x4(v1.x, &t1[0]); fp8w_to_f32x4(v1.y, &t1[4]);
    fp8w_to_f32x4(v2.x, &t2[0]); fp8w_to_f32x4(v2.y, &t2[4]);
    fp8w_to_f32x4(v3.x, &t3[0]); fp8w_to_f32x4(v3.y, &t3[4]);
    #pragma unroll
    for (int k = 0; k < 8; ++k)
      acc[k] += (t0[k] + t1[k]) + (t2[k] + t3[k]);
  }
  for (; e < e1; ++e) {
    uint2 v0 = *(const uint2*)(Hb + (size_t)sl[e] * HID + jq);
    float t0[8];
    fp8w_to_f32x4(v0.x, &t0[0]); fp8w_to_f32x4(v0.y, &t0[4]);
    #pragma unroll
    for (int k = 0; k < 8; ++k) acc[k] += t0[k];
  }
  #pragma unroll
  for (int k = 0; k < 8; ++k)
    red[g][jq + k] = fmaxf(dn * acc[k] + bias[jq + k], 0.f);
  __syncthreads();
  if (tid < HID) {
    float s = 0.f;
    #pragma unroll
    for (int g2 = 0; g2 < 16; ++g2) s += red[g2][tid];
    int b = blockIdx.x >> 6;               // 64 blocks per graph
    atomicAdd(&pooled[b * HID + tid], s * (1.0f / 1024.0f));
  }
}

// ---------------- classifier ----------------

__global__ __launch_bounds__(64) void cls_kernel(const float* __restrict__ pooled, const float* __restrict__ w,
                                                 const float* __restrict__ cb, float* __restrict__ out)
{
  int b = blockIdx.x, o = threadIdx.x;
  if (o < OUT_C) {
    float acc = cb[o];
    for (int i = 0; i < HID; ++i)
      acc += pooled[b * HID + i] * w[i * OUT_C + o];
    out[b * OUT_C + o] = acc;
  }
}

// ---------------- launcher ----------------

extern "C" void kernel_launch(void* const* d_in, const int* in_sizes, int n_in,
                              void* d_out, int out_size, void* d_ws, size_t ws_size,
                              hipStream_t stream)
{
  const float* x    = (const float*)d_in[0];
  const int*   ei   = (const int*)d_in[1];
  const float* c1w  = (const float*)d_in[2];
  const float* c1b  = (const float*)d_in[3];
  const float* c2w  = (const float*)d_in[4];
  const float* c2b  = (const float*)d_in[5];
  const float* g1w  = (const float*)d_in[6];
  const float* g1b  = (const float*)d_in[7];
  const float* g2w  = (const float*)d_in[8];
  const float* g2b  = (const float*)d_in[9];
  const float* clsw = (const float*)d_in[10];
  const float* clsb = (const float*)d_in[11];
  float* outp = (float*)d_out;

  char* ws = (char*)d_ws;
  size_t off_b = 0;
  auto alloc = [&](size_t bytes) { void* p = ws + off_b; off_b = (off_b + bytes + 255) & ~(size_t)255; return p; };
  int*   cnt    = (int*)  alloc((size_t)N_NODES * 4);
  unsigned short* slots = (unsigned short*)alloc((size_t)N_NODES * SLOT_CAP * 2);  // 4 MB
  unsigned short* w1t   = (unsigned short*)alloc((size_t)HID * 32 * 2);
  unsigned short* w2t   = (unsigned short*)alloc((size_t)HID * HID * 2);
  unsigned short* feats = (unsigned short*)alloc((size_t)N_NODES * C2 * 2);
  unsigned char*  H     = (unsigned char*) alloc((size_t)N_NODES * HID);           // fp8 e4m3, 8 MB
  float* pooled = (float*)alloc((size_t)N_B * HID * 4);
  (void)ws_size; (void)in_sizes; (void)n_in; (void)out_size;

  // zero cnt (async memset; pooled is zeroed inside front_kernel's transpose block)
  hipMemsetAsync(cnt, 0, (size_t)N_NODES * 4, stream);

  // scatter || conv1+conv2 fused || weight transpose + pooled-zero (one launch)
  front_kernel<<<4113, 256, 0, stream>>>(x, c1w, c1b, c2w, c2b, ei, cnt, slots,
                                         g1w, g2w, w1t, w2t, pooled, feats);

  // gather (dinv in-loop) + both GEMMs (MFMA); H out in fp8
  gemm12_kernel<<<N_NODES / 64, 256, 0, stream>>>(feats, cnt, slots, w1t, g1b, w2t, H);

  // GCN layer 2 aggregation + bias + relu + mean-pool (fp8 gather)
  agg2_pool_kernel<<<N_NODES / 16, 256, 0, stream>>>(H, cnt, slots, g2b, pooled);

  // classifier
  cls_kernel<<<N_B, 64, 0, stream>>>(pooled, clsw, clsb, outp);
}